// Round 4
// baseline (427.651 us; speedup 1.0000x reference)
//
#include <hip/hip_runtime.h>
#include <hip/hip_bf16.h>
#include <math.h>

#define BB 16
#define NTOK 1024
#define CDIM 256
#define HEADS 8
#define HD 32

typedef __attribute__((ext_vector_type(8))) __bf16 bf16x8;
typedef __attribute__((ext_vector_type(8))) unsigned short u16x8;
typedef __attribute__((ext_vector_type(4))) unsigned short u16x4;
typedef __attribute__((ext_vector_type(4))) float f32x4;

// Split fp32 into bf16 hi (truncation) + bf16 lo (truncation of residual).
__device__ __forceinline__ void split_bf(float f, unsigned short& hi,
                                         unsigned short& lo) {
  unsigned u = __float_as_uint(f);
  hi = (unsigned short)(u >> 16);
  float fl = f - __uint_as_float(u & 0xFFFF0000u);
  lo = (unsigned short)(__float_as_uint(fl) >> 16);
}

__device__ __forceinline__ bf16x8 ldb8(const unsigned short* p) {
  return *reinterpret_cast<const bf16x8*>(p);
}

// ---------------------------------------------------------------------------
// Split X (16384x256 fp32) into bf16 hi/lo, 8 elems/thread.
// ---------------------------------------------------------------------------
__global__ __launch_bounds__(256) void split_x(const float* __restrict__ X,
                                               unsigned short* __restrict__ xhi,
                                               unsigned short* __restrict__ xlo) {
  size_t base = ((size_t)blockIdx.x * 256 + threadIdx.x) * 8;
  float4 a = *(const float4*)(X + base);
  float4 b = *(const float4*)(X + base + 4);
  float v[8] = {a.x, a.y, a.z, a.w, b.x, b.y, b.z, b.w};
  u16x8 h, l;
#pragma unroll
  for (int j = 0; j < 8; ++j) {
    unsigned short hh, ll;
    split_bf(v[j], hh, ll);
    h[j] = hh; l[j] = ll;
  }
  *(u16x8*)(xhi + base) = h;
  *(u16x8*)(xlo + base) = l;
}

// ---------------------------------------------------------------------------
// Split + transpose weights into (N,K) hi/lo.
// ---------------------------------------------------------------------------
__global__ __launch_bounds__(256) void split_w(
    const float* __restrict__ Wq, const float* __restrict__ Wkv,
    const float* __restrict__ Wp, unsigned short* __restrict__ wthi,
    unsigned short* __restrict__ wtlo, unsigned short* __restrict__ wpthi,
    unsigned short* __restrict__ wptlo) {
  int idx = blockIdx.x * 256 + threadIdx.x;  // 0 .. 262143
  float val; size_t dst; bool isp = false;
  if (idx < 65536) {               // Wq: (k,n)
    int k = idx >> 8, n = idx & 255;
    val = Wq[idx]; dst = (size_t)n * 256 + k;
  } else if (idx < 196608) {       // Wkv: (k,n2) -> cols 256..767
    int i2 = idx - 65536;
    int k = i2 >> 9, n2 = i2 & 511;
    val = Wkv[i2]; dst = (size_t)(256 + n2) * 256 + k;
  } else {                         // Wp
    int i3 = idx - 196608;
    int k = i3 >> 8, n = i3 & 255;
    val = Wp[i3]; dst = (size_t)n * 256 + k; isp = true;
  }
  unsigned short h, l;
  split_bf(val, h, l);
  if (isp) { wpthi[dst] = h; wptlo[dst] = l; }
  else     { wthi[dst] = h; wtlo[dst] = l; }
}

// ---------------------------------------------------------------------------
// Per-query angle bias
// ---------------------------------------------------------------------------
__global__ __launch_bounds__(256) void bias_kernel(
    const float* __restrict__ affine, const float* __restrict__ atab,
    float* __restrict__ bias) {
  int idx = blockIdx.x * 256 + threadIdx.x;
  if (idx >= BB * NTOK) return;
  int b = idx >> 10, n = idx & (NTOK - 1);
  float cx = (float)(n & 31);
  float cy = (float)(n >> 5);
  const float* A = affine + b * 6;
  float egx = fmaf(A[0], 16.f, fmaf(A[1], 16.f, A[2]));
  float egy = fmaf(A[3], 16.f, fmaf(A[4], 16.f, A[5]));
  float ang = atan2f(cy - egy, cx - egx);
  float t = (ang + 3.14159265358979323846f) *
            (1.f / (2.f * 3.14159265358979323846f)) * 4.f;
  int bin = (int)t;
  bin = bin < 0 ? 0 : (bin > 4 ? 4 : bin);
  for (int h = 0; h < HEADS; ++h) {
    float a = atab[bin * HEADS + h];
    float s = 1.f / (1.f + __expf(-a));
    bias[((size_t)b * HEADS + h) * NTOK + n] = 1.f + s;
  }
}

// ---------------------------------------------------------------------------
// QKV projection, split-bf16 MFMA, no LDS. Block = 128 rows x 64 cols;
// wave w owns rows m0+32w..+31 (two 16-row fragments) x 64 cols.
// ---------------------------------------------------------------------------
__global__ __launch_bounds__(256) void gemm_qkv_mfma(
    const unsigned short* __restrict__ xhi, const unsigned short* __restrict__ xlo,
    const unsigned short* __restrict__ wthi, const unsigned short* __restrict__ wtlo,
    const float* __restrict__ bq, const float* __restrict__ bkv,
    const float* __restrict__ bias,
    unsigned short* __restrict__ qhi, unsigned short* __restrict__ qlo,
    unsigned short* __restrict__ khi, unsigned short* __restrict__ klo,
    unsigned short* __restrict__ vthi, unsigned short* __restrict__ vtlo) {
  int tid = threadIdx.x;
  int w = tid >> 6, l = tid & 63;
  int row16 = l & 15, grp = l >> 4;
  int j0 = blockIdx.x * 64;
  int m0 = blockIdx.y * 128;
  const unsigned short* a0h = xhi + ((size_t)(m0 + w * 32 + row16)) * CDIM;
  const unsigned short* a0l = xlo + ((size_t)(m0 + w * 32 + row16)) * CDIM;
  const unsigned short* a1h = a0h + 16 * CDIM;
  const unsigned short* a1l = a0l + 16 * CDIM;
  f32x4 acc[2][4];
#pragma unroll
  for (int i = 0; i < 2; ++i)
#pragma unroll
    for (int c = 0; c < 4; ++c) acc[i][c] = (f32x4){0.f, 0.f, 0.f, 0.f};
#pragma unroll
  for (int k0 = 0; k0 < CDIM; k0 += 32) {
    bf16x8 ah0 = ldb8(a0h + k0 + grp * 8);
    bf16x8 al0 = ldb8(a0l + k0 + grp * 8);
    bf16x8 ah1 = ldb8(a1h + k0 + grp * 8);
    bf16x8 al1 = ldb8(a1l + k0 + grp * 8);
#pragma unroll
    for (int c = 0; c < 4; ++c) {
      size_t boff = ((size_t)(j0 + c * 16 + row16)) * CDIM + k0 + grp * 8;
      bf16x8 bh = ldb8(wthi + boff);
      bf16x8 bl = ldb8(wtlo + boff);
      acc[0][c] = __builtin_amdgcn_mfma_f32_16x16x32_bf16(ah0, bh, acc[0][c], 0, 0, 0);
      acc[0][c] = __builtin_amdgcn_mfma_f32_16x16x32_bf16(al0, bh, acc[0][c], 0, 0, 0);
      acc[0][c] = __builtin_amdgcn_mfma_f32_16x16x32_bf16(ah0, bl, acc[0][c], 0, 0, 0);
      acc[1][c] = __builtin_amdgcn_mfma_f32_16x16x32_bf16(ah1, bh, acc[1][c], 0, 0, 0);
      acc[1][c] = __builtin_amdgcn_mfma_f32_16x16x32_bf16(al1, bh, acc[1][c], 0, 0, 0);
      acc[1][c] = __builtin_amdgcn_mfma_f32_16x16x32_bf16(ah1, bl, acc[1][c], 0, 0, 0);
    }
  }
  const float scale = 0.17677669529663687f;  // 32^-0.5
#pragma unroll
  for (int i = 0; i < 2; ++i) {
    int ng = m0 + w * 32 + i * 16 + grp * 4;
#pragma unroll
    for (int c = 0; c < 4; ++c) {
      int jg = j0 + c * 16 + row16;
#pragma unroll
      for (int r = 0; r < 4; ++r) {
        int m = ng + r;
        int b = m >> 10, n = m & (NTOK - 1);
        float val = acc[i][c][r];
        unsigned short hi, lo;
        if (jg < CDIM) {
          int h = jg >> 5, d = jg & 31;
          size_t idx = (((size_t)b * HEADS + h) * NTOK + n) * HD + d;
          float s = (val + bq[jg]) * scale * bias[((size_t)b * HEADS + h) * NTOK + n];
          split_bf(s, hi, lo);
          qhi[idx] = hi; qlo[idx] = lo;
        } else {
          int c2 = jg - CDIM;
          float vv = val + bkv[c2];
          if (c2 < CDIM) {
            int h = c2 >> 5, d = c2 & 31;
            size_t idx = (((size_t)b * HEADS + h) * NTOK + n) * HD + d;
            split_bf(vv, hi, lo);
            khi[idx] = hi; klo[idx] = lo;
          } else {
            int c3 = c2 - CDIM;
            int h = c3 >> 5, d = c3 & 31;
            size_t idxT = (((size_t)b * HEADS + h) * HD + d) * NTOK + n;
            split_bf(vv, hi, lo);
            vthi[idxT] = hi; vtlo[idxT] = lo;
          }
        }
      }
    }
  }
}

// ---------------------------------------------------------------------------
// MFMA flash attention, no-max softmax, swapped QK^T.
// Block = 64 q x (b,h), 4 waves; wave w owns q0+16w..+15.
// QK^T: mfma(K,Q) -> lane holds P[k-frag][q=l&15]; p=exp(s+mask) in-lane,
// lsum accumulated per-lane (q=l&15), reduced once at the end.
// P split to bf16 hi/lo at LDS-write; PV reads fragments directly.
// ---------------------------------------------------------------------------
__global__ __launch_bounds__(256) void attn_mfma(
    const unsigned short* __restrict__ qhi, const unsigned short* __restrict__ qlo,
    const unsigned short* __restrict__ khi, const unsigned short* __restrict__ klo,
    const unsigned short* __restrict__ vthi, const unsigned short* __restrict__ vtlo,
    const float* __restrict__ mask, unsigned short* __restrict__ aohi,
    unsigned short* __restrict__ aolo) {
  __shared__ __align__(16) unsigned short Psh[64][72];
  __shared__ __align__(16) unsigned short Psl[64][72];
  int tid = threadIdx.x;
  int w = tid >> 6;
  int l = tid & 63;
  int row16 = l & 15;
  int grp = l >> 4;
  // XCD-chunked swizzle: 2048 blocks, 8 XCDs -> each XCD gets 2 batches.
  int bid = blockIdx.x;
  int swz = (bid & 7) * 256 + (bid >> 3);
  int b = swz >> 7, h = (swz >> 4) & 7, qt = swz & 15;
  int q0 = qt * 64;
  int bh = b * HEADS + h;

  size_t qidx = (((size_t)bh * NTOK) + q0 + w * 16 + row16) * HD + grp * 8;
  bf16x8 bqh = ldb8(qhi + qidx);   // Q as B-operand: col=q (l&15), k=d
  bf16x8 bql = ldb8(qlo + qidx);

  const unsigned short* kbh = khi + (size_t)bh * NTOK * HD;
  const unsigned short* kbl = klo + (size_t)bh * NTOK * HD;
  const unsigned short* vbh = vthi + (size_t)bh * HD * NTOK;
  const unsigned short* vbl = vtlo + (size_t)bh * HD * NTOK;
  const float* maskq = mask + (size_t)(b & 3) * NTOK * NTOK +
                       (size_t)(q0 + w * 16 + row16) * NTOK + grp * 4;

  f32x4 accd[2];
  accd[0] = (f32x4){0.f, 0.f, 0.f, 0.f};
  accd[1] = (f32x4){0.f, 0.f, 0.f, 0.f};
  float lsum = 0.f;
  const f32x4 zero4 = (f32x4){0.f, 0.f, 0.f, 0.f};

  for (int kt = 0; kt < 16; ++kt) {
    int k0 = kt * 64;
    // ---- S^T = K Q^T : D row = k-local (4*grp+r), col = q (row16)
    f32x4 s[4];
#pragma unroll
    for (int f = 0; f < 4; ++f) {
      size_t kidx = ((size_t)(k0 + f * 16 + row16)) * HD + grp * 8;
      bf16x8 kh = ldb8(kbh + kidx);
      bf16x8 kl2 = ldb8(kbl + kidx);
      f32x4 t = __builtin_amdgcn_mfma_f32_16x16x32_bf16(kh, bqh, zero4, 0, 0, 0);
      t = __builtin_amdgcn_mfma_f32_16x16x32_bf16(kl2, bqh, t, 0, 0, 0);
      t = __builtin_amdgcn_mfma_f32_16x16x32_bf16(kh, bql, t, 0, 0, 0);
      s[f] = t;
    }
    // ---- p = exp(s + mask); lsum; split -> LDS (no reductions, no branches)
#pragma unroll
    for (int f = 0; f < 4; ++f) {
      float4 mv = *(const float4*)(maskq + k0 + f * 16);
      float p0 = __expf(s[f][0] + mv.x);
      float p1 = __expf(s[f][1] + mv.y);
      float p2 = __expf(s[f][2] + mv.z);
      float p3 = __expf(s[f][3] + mv.w);
      lsum += (p0 + p1) + (p2 + p3);
      unsigned short h0, l0, h1, l1, h2, l2, h3, l3;
      split_bf(p0, h0, l0); split_bf(p1, h1, l1);
      split_bf(p2, h2, l2); split_bf(p3, h3, l3);
      int prow = w * 16 + row16;          // q-local row
      int pcol = f * 16 + grp * 4;        // k-local col
      *(u16x4*)&Psh[prow][pcol] = (u16x4){h0, h1, h2, h3};
      *(u16x4*)&Psl[prow][pcol] = (u16x4){l0, l1, l2, l3};
    }
    // ---- O += P V : A=P (row=q=l&15, k=ks*32+8*grp+j), B=V^T
#pragma unroll
    for (int ks = 0; ks < 2; ++ks) {
      bf16x8 ph = __builtin_bit_cast(bf16x8,
          *(const u16x8*)&Psh[w * 16 + row16][ks * 32 + grp * 8]);
      bf16x8 pl = __builtin_bit_cast(bf16x8,
          *(const u16x8*)&Psl[w * 16 + row16][ks * 32 + grp * 8]);
#pragma unroll
      for (int df = 0; df < 2; ++df) {
        size_t vidx = ((size_t)(df * 16 + row16)) * NTOK + k0 + ks * 32 + grp * 8;
        bf16x8 vh = ldb8(vbh + vidx);
        bf16x8 vl = ldb8(vbl + vidx);
        accd[df] = __builtin_amdgcn_mfma_f32_16x16x32_bf16(ph, vh, accd[df], 0, 0, 0);
        accd[df] = __builtin_amdgcn_mfma_f32_16x16x32_bf16(pl, vh, accd[df], 0, 0, 0);
        accd[df] = __builtin_amdgcn_mfma_f32_16x16x32_bf16(ph, vl, accd[df], 0, 0, 0);
      }
    }
  }
  // ---- single final reduction: sum lsum across the 4 lane-groups
  lsum += __shfl_xor(lsum, 16);
  lsum += __shfl_xor(lsum, 32);
  // accd rows are q-local 4*grp+r; fetch matching row-sum from lane grp*4+r
#pragma unroll
  for (int r = 0; r < 4; ++r) {
    float lr = __shfl(lsum, grp * 4 + r, 16);
    float inv = 1.f / lr;
    int qrow = q0 + w * 16 + grp * 4 + r;
    size_t obase = ((size_t)b * NTOK + qrow) * CDIM + h * HD;
    float v0 = accd[0][r] * inv, v1 = accd[1][r] * inv;
    unsigned short h0, l0, h1, l1;
    split_bf(v0, h0, l0);
    split_bf(v1, h1, l1);
    aohi[obase + row16] = h0; aolo[obase + row16] = l0;
    aohi[obase + 16 + row16] = h1; aolo[obase + 16 + row16] = l1;
  }
}

// ---------------------------------------------------------------------------
// Output projection, split-bf16 MFMA, 128-row blocks, 32-row wave tiles.
// ---------------------------------------------------------------------------
__global__ __launch_bounds__(256) void gemm_out_mfma(
    const unsigned short* __restrict__ ahi, const unsigned short* __restrict__ alo,
    const unsigned short* __restrict__ wpthi, const unsigned short* __restrict__ wptlo,
    const float* __restrict__ bp, float* __restrict__ out) {
  int tid = threadIdx.x;
  int w = tid >> 6, l = tid & 63;
  int row16 = l & 15, grp = l >> 4;
  int j0 = blockIdx.x * 64;
  int m0 = blockIdx.y * 128;
  const unsigned short* a0h = ahi + ((size_t)(m0 + w * 32 + row16)) * CDIM;
  const unsigned short* a0l = alo + ((size_t)(m0 + w * 32 + row16)) * CDIM;
  const unsigned short* a1h = a0h + 16 * CDIM;
  const unsigned short* a1l = a0l + 16 * CDIM;
  f32x4 acc[2][4];
#pragma unroll
  for (int i = 0; i < 2; ++i)
#pragma unroll
    for (int c = 0; c < 4; ++c) acc[i][c] = (f32x4){0.f, 0.f, 0.f, 0.f};
#pragma unroll
  for (int k0 = 0; k0 < CDIM; k0 += 32) {
    bf16x8 ah0 = ldb8(a0h + k0 + grp * 8);
    bf16x8 al0 = ldb8(a0l + k0 + grp * 8);
    bf16x8 ah1 = ldb8(a1h + k0 + grp * 8);
    bf16x8 al1 = ldb8(a1l + k0 + grp * 8);
#pragma unroll
    for (int c = 0; c < 4; ++c) {
      size_t boff = ((size_t)(j0 + c * 16 + row16)) * CDIM + k0 + grp * 8;
      bf16x8 bh = ldb8(wpthi + boff);
      bf16x8 bl = ldb8(wptlo + boff);
      acc[0][c] = __builtin_amdgcn_mfma_f32_16x16x32_bf16(ah0, bh, acc[0][c], 0, 0, 0);
      acc[0][c] = __builtin_amdgcn_mfma_f32_16x16x32_bf16(al0, bh, acc[0][c], 0, 0, 0);
      acc[0][c] = __builtin_amdgcn_mfma_f32_16x16x32_bf16(ah0, bl, acc[0][c], 0, 0, 0);
      acc[1][c] = __builtin_amdgcn_mfma_f32_16x16x32_bf16(ah1, bh, acc[1][c], 0, 0, 0);
      acc[1][c] = __builtin_amdgcn_mfma_f32_16x16x32_bf16(al1, bh, acc[1][c], 0, 0, 0);
      acc[1][c] = __builtin_amdgcn_mfma_f32_16x16x32_bf16(ah1, bl, acc[1][c], 0, 0, 0);
    }
  }
#pragma unroll
  for (int i = 0; i < 2; ++i) {
    int ng = m0 + w * 32 + i * 16 + grp * 4;
#pragma unroll
    for (int c = 0; c < 4; ++c) {
      int jg = j0 + c * 16 + row16;
      float bias = bp[jg];
#pragma unroll
      for (int r = 0; r < 4; ++r) {
        out[(size_t)(ng + r) * CDIM + jg] = acc[i][c][r] + bias;
      }
    }
  }
}

// ---------------------------------------------------------------------------
extern "C" void kernel_launch(void* const* d_in, const int* in_sizes, int n_in,
                              void* d_out, int out_size, void* d_ws,
                              size_t ws_size, hipStream_t stream) {
  const float* x = (const float*)d_in[0];
  const float* mask = (const float*)d_in[1];
  const float* affine = (const float*)d_in[2];
  const float* Wq = (const float*)d_in[3];
  const float* bq = (const float*)d_in[4];
  const float* Wkv = (const float*)d_in[5];
  const float* bkv = (const float*)d_in[6];
  const float* Wp = (const float*)d_in[7];
  const float* bp = (const float*)d_in[8];
  const float* atab = (const float*)d_in[9];
  float* out = (float*)d_out;

  const size_t bhnd = (size_t)BB * HEADS * NTOK * HD;  // 4,194,304
  unsigned short* qhi = (unsigned short*)d_ws;
  unsigned short* qlo = qhi + bhnd;
  unsigned short* khi = qlo + bhnd;
  unsigned short* klo = khi + bhnd;
  unsigned short* vthi = klo + bhnd;
  unsigned short* vtlo = vthi + bhnd;
  unsigned short* xhi = vtlo + bhnd;   // aliased as aout_hi after qkv
  unsigned short* xlo = xhi + bhnd;    // aliased as aout_lo after qkv
  unsigned short* wthi = xlo + bhnd;             // 768*256
  unsigned short* wtlo = wthi + 768 * 256;
  unsigned short* wpthi = wtlo + 768 * 256;      // 256*256
  unsigned short* wptlo = wpthi + 256 * 256;
  float* bias = (float*)(wptlo + 256 * 256);

  split_x<<<2048, 256, 0, stream>>>(x, xhi, xlo);
  split_w<<<1024, 256, 0, stream>>>(Wq, Wkv, Wp, wthi, wtlo, wpthi, wptlo);
  bias_kernel<<<64, 256, 0, stream>>>(affine, atab, bias);
  gemm_qkv_mfma<<<dim3(12, 128), 256, 0, stream>>>(
      xhi, xlo, wthi, wtlo, bq, bkv, bias, qhi, qlo, khi, klo, vthi, vtlo);
  attn_mfma<<<2048, 256, 0, stream>>>(qhi, qlo, khi, klo, vthi, vtlo, mask,
                                      xhi, xlo);
  gemm_out_mfma<<<dim3(4, 128), 256, 0, stream>>>(xhi, xlo, wpthi, wptlo, bp,
                                                  out);
}

// Round 5
// 377.338 us; speedup vs baseline: 1.1333x; 1.1333x over previous
//
#include <hip/hip_runtime.h>
#include <hip/hip_bf16.h>
#include <math.h>

#define BB 16
#define NTOK 1024
#define CDIM 256
#define HEADS 8
#define HD 32

typedef __attribute__((ext_vector_type(8))) __bf16 bf16x8;
typedef __attribute__((ext_vector_type(8))) unsigned short u16x8;
typedef __attribute__((ext_vector_type(4))) unsigned short u16x4;
typedef __attribute__((ext_vector_type(4))) float f32x4;

// Split fp32 into bf16 hi (truncation) + bf16 lo (truncation of residual).
__device__ __forceinline__ void split_bf(float f, unsigned short& hi,
                                         unsigned short& lo) {
  unsigned u = __float_as_uint(f);
  hi = (unsigned short)(u >> 16);
  float fl = f - __uint_as_float(u & 0xFFFF0000u);
  lo = (unsigned short)(__float_as_uint(fl) >> 16);
}

__device__ __forceinline__ bf16x8 ldb8(const unsigned short* p) {
  return *reinterpret_cast<const bf16x8*>(p);
}

// ---------------------------------------------------------------------------
// Split X (16384x256 fp32) into bf16 hi/lo, 8 elems/thread.
// ---------------------------------------------------------------------------
__global__ __launch_bounds__(256) void split_x(const float* __restrict__ X,
                                               unsigned short* __restrict__ xhi,
                                               unsigned short* __restrict__ xlo) {
  size_t base = ((size_t)blockIdx.x * 256 + threadIdx.x) * 8;
  float4 a = *(const float4*)(X + base);
  float4 b = *(const float4*)(X + base + 4);
  float v[8] = {a.x, a.y, a.z, a.w, b.x, b.y, b.z, b.w};
  u16x8 h, l;
#pragma unroll
  for (int j = 0; j < 8; ++j) {
    unsigned short hh, ll;
    split_bf(v[j], hh, ll);
    h[j] = hh; l[j] = ll;
  }
  *(u16x8*)(xhi + base) = h;
  *(u16x8*)(xlo + base) = l;
}

// ---------------------------------------------------------------------------
// Split + transpose weights into (N,K) hi/lo.
// ---------------------------------------------------------------------------
__global__ __launch_bounds__(256) void split_w(
    const float* __restrict__ Wq, const float* __restrict__ Wkv,
    const float* __restrict__ Wp, unsigned short* __restrict__ wthi,
    unsigned short* __restrict__ wtlo, unsigned short* __restrict__ wpthi,
    unsigned short* __restrict__ wptlo) {
  int idx = blockIdx.x * 256 + threadIdx.x;  // 0 .. 262143
  float val; size_t dst; bool isp = false;
  if (idx < 65536) {               // Wq: (k,n)
    int k = idx >> 8, n = idx & 255;
    val = Wq[idx]; dst = (size_t)n * 256 + k;
  } else if (idx < 196608) {       // Wkv: (k,n2) -> cols 256..767
    int i2 = idx - 65536;
    int k = i2 >> 9, n2 = i2 & 511;
    val = Wkv[i2]; dst = (size_t)(256 + n2) * 256 + k;
  } else {                         // Wp
    int i3 = idx - 196608;
    int k = i3 >> 8, n = i3 & 255;
    val = Wp[i3]; dst = (size_t)n * 256 + k; isp = true;
  }
  unsigned short h, l;
  split_bf(val, h, l);
  if (isp) { wpthi[dst] = h; wptlo[dst] = l; }
  else     { wthi[dst] = h; wtlo[dst] = l; }
}

// ---------------------------------------------------------------------------
// Per-query angle bias
// ---------------------------------------------------------------------------
__global__ __launch_bounds__(256) void bias_kernel(
    const float* __restrict__ affine, const float* __restrict__ atab,
    float* __restrict__ bias) {
  int idx = blockIdx.x * 256 + threadIdx.x;
  if (idx >= BB * NTOK) return;
  int b = idx >> 10, n = idx & (NTOK - 1);
  float cx = (float)(n & 31);
  float cy = (float)(n >> 5);
  const float* A = affine + b * 6;
  float egx = fmaf(A[0], 16.f, fmaf(A[1], 16.f, A[2]));
  float egy = fmaf(A[3], 16.f, fmaf(A[4], 16.f, A[5]));
  float ang = atan2f(cy - egy, cx - egx);
  float t = (ang + 3.14159265358979323846f) *
            (1.f / (2.f * 3.14159265358979323846f)) * 4.f;
  int bin = (int)t;
  bin = bin < 0 ? 0 : (bin > 4 ? 4 : bin);
  for (int h = 0; h < HEADS; ++h) {
    float a = atab[bin * HEADS + h];
    float s = 1.f / (1.f + __expf(-a));
    bias[((size_t)b * HEADS + h) * NTOK + n] = 1.f + s;
  }
}

// ---------------------------------------------------------------------------
// QKV projection, split-bf16 MFMA, no LDS. Block = 128 rows x 64 cols;
// wave w owns rows m0+32w..+31 (two 16-row fragments) x 64 cols.
// ---------------------------------------------------------------------------
__global__ __launch_bounds__(256) void gemm_qkv_mfma(
    const unsigned short* __restrict__ xhi, const unsigned short* __restrict__ xlo,
    const unsigned short* __restrict__ wthi, const unsigned short* __restrict__ wtlo,
    const float* __restrict__ bq, const float* __restrict__ bkv,
    const float* __restrict__ bias,
    unsigned short* __restrict__ qhi, unsigned short* __restrict__ qlo,
    unsigned short* __restrict__ khi, unsigned short* __restrict__ klo,
    unsigned short* __restrict__ vthi, unsigned short* __restrict__ vtlo) {
  int tid = threadIdx.x;
  int w = tid >> 6, l = tid & 63;
  int row16 = l & 15, grp = l >> 4;
  int j0 = blockIdx.x * 64;
  int m0 = blockIdx.y * 128;
  const unsigned short* a0h = xhi + ((size_t)(m0 + w * 32 + row16)) * CDIM;
  const unsigned short* a0l = xlo + ((size_t)(m0 + w * 32 + row16)) * CDIM;
  const unsigned short* a1h = a0h + 16 * CDIM;
  const unsigned short* a1l = a0l + 16 * CDIM;
  f32x4 acc[2][4];
#pragma unroll
  for (int i = 0; i < 2; ++i)
#pragma unroll
    for (int c = 0; c < 4; ++c) acc[i][c] = (f32x4){0.f, 0.f, 0.f, 0.f};
#pragma unroll
  for (int k0 = 0; k0 < CDIM; k0 += 32) {
    bf16x8 ah0 = ldb8(a0h + k0 + grp * 8);
    bf16x8 al0 = ldb8(a0l + k0 + grp * 8);
    bf16x8 ah1 = ldb8(a1h + k0 + grp * 8);
    bf16x8 al1 = ldb8(a1l + k0 + grp * 8);
#pragma unroll
    for (int c = 0; c < 4; ++c) {
      size_t boff = ((size_t)(j0 + c * 16 + row16)) * CDIM + k0 + grp * 8;
      bf16x8 bh = ldb8(wthi + boff);
      bf16x8 bl = ldb8(wtlo + boff);
      acc[0][c] = __builtin_amdgcn_mfma_f32_16x16x32_bf16(ah0, bh, acc[0][c], 0, 0, 0);
      acc[0][c] = __builtin_amdgcn_mfma_f32_16x16x32_bf16(al0, bh, acc[0][c], 0, 0, 0);
      acc[0][c] = __builtin_amdgcn_mfma_f32_16x16x32_bf16(ah0, bl, acc[0][c], 0, 0, 0);
      acc[1][c] = __builtin_amdgcn_mfma_f32_16x16x32_bf16(ah1, bh, acc[1][c], 0, 0, 0);
      acc[1][c] = __builtin_amdgcn_mfma_f32_16x16x32_bf16(al1, bh, acc[1][c], 0, 0, 0);
      acc[1][c] = __builtin_amdgcn_mfma_f32_16x16x32_bf16(ah1, bl, acc[1][c], 0, 0, 0);
    }
  }
  const float scale = 0.17677669529663687f;  // 32^-0.5
#pragma unroll
  for (int i = 0; i < 2; ++i) {
    int ng = m0 + w * 32 + i * 16 + grp * 4;
#pragma unroll
    for (int c = 0; c < 4; ++c) {
      int jg = j0 + c * 16 + row16;
#pragma unroll
      for (int r = 0; r < 4; ++r) {
        int m = ng + r;
        int b = m >> 10, n = m & (NTOK - 1);
        float val = acc[i][c][r];
        unsigned short hi, lo;
        if (jg < CDIM) {
          int h = jg >> 5, d = jg & 31;
          size_t idx = (((size_t)b * HEADS + h) * NTOK + n) * HD + d;
          float s = (val + bq[jg]) * scale * bias[((size_t)b * HEADS + h) * NTOK + n];
          split_bf(s, hi, lo);
          qhi[idx] = hi; qlo[idx] = lo;
        } else {
          int c2 = jg - CDIM;
          float vv = val + bkv[c2];
          if (c2 < CDIM) {
            int h = c2 >> 5, d = c2 & 31;
            size_t idx = (((size_t)b * HEADS + h) * NTOK + n) * HD + d;
            split_bf(vv, hi, lo);
            khi[idx] = hi; klo[idx] = lo;
          } else {
            int c3 = c2 - CDIM;
            int h = c3 >> 5, d = c3 & 31;
            size_t idxT = (((size_t)b * HEADS + h) * HD + d) * NTOK + n;
            split_bf(vv, hi, lo);
            vthi[idxT] = hi; vtlo[idxT] = lo;
          }
        }
      }
    }
  }
}

// ---------------------------------------------------------------------------
// MFMA flash attention, no-max softmax, swapped QK^T, register-prefetched.
// Block = 64 q x (b,h), 4 waves; wave w owns q0+16w..+15.
//  - K-frags + mask rows for tile kt+1 issued during tile kt (reg dbuf)
//  - V-frags for tile kt issued at tile start, consumed after QK+softmax
//  - no __syncthreads; P staged in wave-private LDS stripe as bf16 hi/lo
// ---------------------------------------------------------------------------
__global__ __launch_bounds__(256, 2) void attn_mfma(
    const unsigned short* __restrict__ qhi, const unsigned short* __restrict__ qlo,
    const unsigned short* __restrict__ khi, const unsigned short* __restrict__ klo,
    const unsigned short* __restrict__ vthi, const unsigned short* __restrict__ vtlo,
    const float* __restrict__ mask, unsigned short* __restrict__ aohi,
    unsigned short* __restrict__ aolo) {
  __shared__ __align__(16) unsigned short Psh[64][72];
  __shared__ __align__(16) unsigned short Psl[64][72];
  int tid = threadIdx.x;
  int w = tid >> 6;
  int l = tid & 63;
  int row16 = l & 15;
  int grp = l >> 4;
  // XCD-chunked swizzle: 2048 blocks, 8 XCDs -> each XCD gets 2 batches.
  int bid = blockIdx.x;
  int swz = (bid & 7) * 256 + (bid >> 3);
  int b = swz >> 7, h = (swz >> 4) & 7, qt = swz & 15;
  int q0 = qt * 64;
  int bh = b * HEADS + h;

  size_t qidx = (((size_t)bh * NTOK) + q0 + w * 16 + row16) * HD + grp * 8;
  bf16x8 bqh = ldb8(qhi + qidx);   // Q as B-operand: col=q (l&15), k=d
  bf16x8 bql = ldb8(qlo + qidx);

  const unsigned short* kbh = khi + (size_t)bh * NTOK * HD;
  const unsigned short* kbl = klo + (size_t)bh * NTOK * HD;
  const unsigned short* vbh = vthi + (size_t)bh * HD * NTOK;
  const unsigned short* vbl = vtlo + (size_t)bh * HD * NTOK;
  const float* maskq = mask + (size_t)(b & 3) * NTOK * NTOK +
                       (size_t)(q0 + w * 16 + row16) * NTOK + grp * 4;

  f32x4 accd[2];
  accd[0] = (f32x4){0.f, 0.f, 0.f, 0.f};
  accd[1] = (f32x4){0.f, 0.f, 0.f, 0.f};
  float lsum = 0.f;
  const f32x4 zero4 = (f32x4){0.f, 0.f, 0.f, 0.f};

  // ---- prologue: load K-frags + mask for tile 0 into current regs
  bf16x8 kch[4], kcl[4], knh[4], knl[4];
  float4 mc[4], mn[4];
#pragma unroll
  for (int f = 0; f < 4; ++f) {
    size_t kidx = ((size_t)(f * 16 + row16)) * HD + grp * 8;
    kch[f] = ldb8(kbh + kidx);
    kcl[f] = ldb8(kbl + kidx);
    mc[f] = *(const float4*)(maskq + f * 16);
  }

  for (int kt = 0; kt < 16; ++kt) {
    int k0 = kt * 64;
    int k0n = ((kt + 1) & 15) * 64;  // wrap: harmless reload of tile 0 at end
    // ---- issue V loads for THIS tile (consumed after QK+softmax)
    bf16x8 vh_[4], vl_[4];  // index = ks*2+df
#pragma unroll
    for (int ks = 0; ks < 2; ++ks)
#pragma unroll
      for (int df = 0; df < 2; ++df) {
        size_t vidx = ((size_t)(df * 16 + row16)) * NTOK + k0 + ks * 32 + grp * 8;
        vh_[ks * 2 + df] = ldb8(vbh + vidx);
        vl_[ks * 2 + df] = ldb8(vbl + vidx);
      }
    // ---- issue K + mask prefetch for NEXT tile
#pragma unroll
    for (int f = 0; f < 4; ++f) {
      size_t kidx = ((size_t)(k0n + f * 16 + row16)) * HD + grp * 8;
      knh[f] = ldb8(kbh + kidx);
      knl[f] = ldb8(kbl + kidx);
      mn[f] = *(const float4*)(maskq + k0n + f * 16);
    }
    // ---- S^T = K Q^T on current K regs
    f32x4 s[4];
#pragma unroll
    for (int f = 0; f < 4; ++f) {
      f32x4 t = __builtin_amdgcn_mfma_f32_16x16x32_bf16(kch[f], bqh, zero4, 0, 0, 0);
      t = __builtin_amdgcn_mfma_f32_16x16x32_bf16(kcl[f], bqh, t, 0, 0, 0);
      t = __builtin_amdgcn_mfma_f32_16x16x32_bf16(kch[f], bql, t, 0, 0, 0);
      s[f] = t;
    }
    // ---- p = exp(s + mask); lsum; split -> LDS
#pragma unroll
    for (int f = 0; f < 4; ++f) {
      float p0 = __expf(s[f][0] + mc[f].x);
      float p1 = __expf(s[f][1] + mc[f].y);
      float p2 = __expf(s[f][2] + mc[f].z);
      float p3 = __expf(s[f][3] + mc[f].w);
      lsum += (p0 + p1) + (p2 + p3);
      unsigned short h0, l0, h1, l1, h2, l2, h3, l3;
      split_bf(p0, h0, l0); split_bf(p1, h1, l1);
      split_bf(p2, h2, l2); split_bf(p3, h3, l3);
      int prow = w * 16 + row16;
      int pcol = f * 16 + grp * 4;
      *(u16x4*)&Psh[prow][pcol] = (u16x4){h0, h1, h2, h3};
      *(u16x4*)&Psl[prow][pcol] = (u16x4){l0, l1, l2, l3};
    }
    // ---- O += P V
#pragma unroll
    for (int ks = 0; ks < 2; ++ks) {
      bf16x8 ph = __builtin_bit_cast(bf16x8,
          *(const u16x8*)&Psh[w * 16 + row16][ks * 32 + grp * 8]);
      bf16x8 pl = __builtin_bit_cast(bf16x8,
          *(const u16x8*)&Psl[w * 16 + row16][ks * 32 + grp * 8]);
#pragma unroll
      for (int df = 0; df < 2; ++df) {
        bf16x8 vh = vh_[ks * 2 + df];
        bf16x8 vl = vl_[ks * 2 + df];
        accd[df] = __builtin_amdgcn_mfma_f32_16x16x32_bf16(ph, vh, accd[df], 0, 0, 0);
        accd[df] = __builtin_amdgcn_mfma_f32_16x16x32_bf16(pl, vh, accd[df], 0, 0, 0);
        accd[df] = __builtin_amdgcn_mfma_f32_16x16x32_bf16(ph, vl, accd[df], 0, 0, 0);
      }
    }
    // ---- rotate prefetch buffers
#pragma unroll
    for (int f = 0; f < 4; ++f) {
      kch[f] = knh[f]; kcl[f] = knl[f]; mc[f] = mn[f];
    }
  }
  // ---- single final reduction: sum lsum across the 4 lane-groups
  lsum += __shfl_xor(lsum, 16);
  lsum += __shfl_xor(lsum, 32);
#pragma unroll
  for (int r = 0; r < 4; ++r) {
    float lr = __shfl(lsum, grp * 4 + r, 16);
    float inv = 1.f / lr;
    int qrow = q0 + w * 16 + grp * 4 + r;
    size_t obase = ((size_t)b * NTOK + qrow) * CDIM + h * HD;
    float v0 = accd[0][r] * inv, v1 = accd[1][r] * inv;
    unsigned short h0, l0, h1, l1;
    split_bf(v0, h0, l0);
    split_bf(v1, h1, l1);
    aohi[obase + row16] = h0; aolo[obase + row16] = l0;
    aohi[obase + 16 + row16] = h1; aolo[obase + 16 + row16] = l1;
  }
}

// ---------------------------------------------------------------------------
// Output projection, split-bf16 MFMA, 128-row blocks, 32-row wave tiles.
// ---------------------------------------------------------------------------
__global__ __launch_bounds__(256) void gemm_out_mfma(
    const unsigned short* __restrict__ ahi, const unsigned short* __restrict__ alo,
    const unsigned short* __restrict__ wpthi, const unsigned short* __restrict__ wptlo,
    const float* __restrict__ bp, float* __restrict__ out) {
  int tid = threadIdx.x;
  int w = tid >> 6, l = tid & 63;
  int row16 = l & 15, grp = l >> 4;
  int j0 = blockIdx.x * 64;
  int m0 = blockIdx.y * 128;
  const unsigned short* a0h = ahi + ((size_t)(m0 + w * 32 + row16)) * CDIM;
  const unsigned short* a0l = alo + ((size_t)(m0 + w * 32 + row16)) * CDIM;
  const unsigned short* a1h = a0h + 16 * CDIM;
  const unsigned short* a1l = a0l + 16 * CDIM;
  f32x4 acc[2][4];
#pragma unroll
  for (int i = 0; i < 2; ++i)
#pragma unroll
    for (int c = 0; c < 4; ++c) acc[i][c] = (f32x4){0.f, 0.f, 0.f, 0.f};
#pragma unroll
  for (int k0 = 0; k0 < CDIM; k0 += 32) {
    bf16x8 ah0 = ldb8(a0h + k0 + grp * 8);
    bf16x8 al0 = ldb8(a0l + k0 + grp * 8);
    bf16x8 ah1 = ldb8(a1h + k0 + grp * 8);
    bf16x8 al1 = ldb8(a1l + k0 + grp * 8);
#pragma unroll
    for (int c = 0; c < 4; ++c) {
      size_t boff = ((size_t)(j0 + c * 16 + row16)) * CDIM + k0 + grp * 8;
      bf16x8 bh = ldb8(wpthi + boff);
      bf16x8 bl = ldb8(wptlo + boff);
      acc[0][c] = __builtin_amdgcn_mfma_f32_16x16x32_bf16(ah0, bh, acc[0][c], 0, 0, 0);
      acc[0][c] = __builtin_amdgcn_mfma_f32_16x16x32_bf16(al0, bh, acc[0][c], 0, 0, 0);
      acc[0][c] = __builtin_amdgcn_mfma_f32_16x16x32_bf16(ah0, bl, acc[0][c], 0, 0, 0);
      acc[1][c] = __builtin_amdgcn_mfma_f32_16x16x32_bf16(ah1, bh, acc[1][c], 0, 0, 0);
      acc[1][c] = __builtin_amdgcn_mfma_f32_16x16x32_bf16(al1, bh, acc[1][c], 0, 0, 0);
      acc[1][c] = __builtin_amdgcn_mfma_f32_16x16x32_bf16(ah1, bl, acc[1][c], 0, 0, 0);
    }
  }
#pragma unroll
  for (int i = 0; i < 2; ++i) {
    int ng = m0 + w * 32 + i * 16 + grp * 4;
#pragma unroll
    for (int c = 0; c < 4; ++c) {
      int jg = j0 + c * 16 + row16;
      float bias = bp[jg];
#pragma unroll
      for (int r = 0; r < 4; ++r) {
        out[(size_t)(ng + r) * CDIM + jg] = acc[i][c][r] + bias;
      }
    }
  }
}

// ---------------------------------------------------------------------------
extern "C" void kernel_launch(void* const* d_in, const int* in_sizes, int n_in,
                              void* d_out, int out_size, void* d_ws,
                              size_t ws_size, hipStream_t stream) {
  const float* x = (const float*)d_in[0];
  const float* mask = (const float*)d_in[1];
  const float* affine = (const float*)d_in[2];
  const float* Wq = (const float*)d_in[3];
  const float* bq = (const float*)d_in[4];
  const float* Wkv = (const float*)d_in[5];
  const float* bkv = (const float*)d_in[6];
  const float* Wp = (const float*)d_in[7];
  const float* bp = (const float*)d_in[8];
  const float* atab = (const float*)d_in[9];
  float* out = (float*)d_out;

  const size_t bhnd = (size_t)BB * HEADS * NTOK * HD;  // 4,194,304
  unsigned short* qhi = (unsigned short*)d_ws;
  unsigned short* qlo = qhi + bhnd;
  unsigned short* khi = qlo + bhnd;
  unsigned short* klo = khi + bhnd;
  unsigned short* vthi = klo + bhnd;
  unsigned short* vtlo = vthi + bhnd;
  unsigned short* xhi = vtlo + bhnd;   // aliased as aout_hi after qkv
  unsigned short* xlo = xhi + bhnd;    // aliased as aout_lo after qkv
  unsigned short* wthi = xlo + bhnd;             // 768*256
  unsigned short* wtlo = wthi + 768 * 256;
  unsigned short* wpthi = wtlo + 768 * 256;      // 256*256
  unsigned short* wptlo = wpthi + 256 * 256;
  float* bias = (float*)(wptlo + 256 * 256);

  split_x<<<2048, 256, 0, stream>>>(x, xhi, xlo);
  split_w<<<1024, 256, 0, stream>>>(Wq, Wkv, Wp, wthi, wtlo, wpthi, wptlo);
  bias_kernel<<<64, 256, 0, stream>>>(affine, atab, bias);
  gemm_qkv_mfma<<<dim3(12, 128), 256, 0, stream>>>(
      xhi, xlo, wthi, wtlo, bq, bkv, bias, qhi, qlo, khi, klo, vthi, vtlo);
  attn_mfma<<<2048, 256, 0, stream>>>(qhi, qlo, khi, klo, vthi, vtlo, mask,
                                      xhi, xlo);
  gemm_out_mfma<<<dim3(4, 128), 256, 0, stream>>>(xhi, xlo, wpthi, wptlo, bp,
                                                  out);
}

// Round 6
// 215.356 us; speedup vs baseline: 1.9858x; 1.7522x over previous
//
#include <hip/hip_runtime.h>
#include <hip/hip_bf16.h>
#include <math.h>

#define BB 16
#define NTOK 1024
#define CDIM 256
#define HEADS 8
#define HD 32

typedef __attribute__((ext_vector_type(8))) __bf16 bf16x8;
typedef __attribute__((ext_vector_type(8))) unsigned short u16x8;
typedef __attribute__((ext_vector_type(4))) float f32x4;

// Split fp32 into bf16 hi (truncation) + bf16 lo (truncation of residual).
__device__ __forceinline__ void split_bf(float f, unsigned short& hi,
                                         unsigned short& lo) {
  unsigned u = __float_as_uint(f);
  hi = (unsigned short)(u >> 16);
  float fl = f - __uint_as_float(u & 0xFFFF0000u);
  lo = (unsigned short)(__float_as_uint(fl) >> 16);
}

__device__ __forceinline__ bf16x8 ldb8(const unsigned short* p) {
  return *reinterpret_cast<const bf16x8*>(p);
}

// async global->LDS 16B DMA: per-lane global src, wave-uniform LDS base
// (HW adds lane*16 to the dest).
__device__ __forceinline__ void gl_lds16(const unsigned short* g,
                                         unsigned short* l) {
  __builtin_amdgcn_global_load_lds(
      (const __attribute__((address_space(1))) unsigned int*)g,
      (__attribute__((address_space(3))) unsigned int*)l, 16, 0, 0);
}

// ---------------------------------------------------------------------------
// Split X (16384x256 fp32) into bf16 hi/lo, 8 elems/thread.
// ---------------------------------------------------------------------------
__global__ __launch_bounds__(256) void split_x(const float* __restrict__ X,
                                               unsigned short* __restrict__ xhi,
                                               unsigned short* __restrict__ xlo) {
  size_t base = ((size_t)blockIdx.x * 256 + threadIdx.x) * 8;
  float4 a = *(const float4*)(X + base);
  float4 b = *(const float4*)(X + base + 4);
  float v[8] = {a.x, a.y, a.z, a.w, b.x, b.y, b.z, b.w};
  u16x8 h, l;
#pragma unroll
  for (int j = 0; j < 8; ++j) {
    unsigned short hh, ll;
    split_bf(v[j], hh, ll);
    h[j] = hh; l[j] = ll;
  }
  *(u16x8*)(xhi + base) = h;
  *(u16x8*)(xlo + base) = l;
}

// ---------------------------------------------------------------------------
// Split + transpose weights into (N,K) hi/lo.
// ---------------------------------------------------------------------------
__global__ __launch_bounds__(256) void split_w(
    const float* __restrict__ Wq, const float* __restrict__ Wkv,
    const float* __restrict__ Wp, unsigned short* __restrict__ wthi,
    unsigned short* __restrict__ wtlo, unsigned short* __restrict__ wpthi,
    unsigned short* __restrict__ wptlo) {
  int idx = blockIdx.x * 256 + threadIdx.x;  // 0 .. 262143
  float val; size_t dst; bool isp = false;
  if (idx < 65536) {               // Wq: (k,n)
    int k = idx >> 8, n = idx & 255;
    val = Wq[idx]; dst = (size_t)n * 256 + k;
  } else if (idx < 196608) {       // Wkv: (k,n2) -> cols 256..767
    int i2 = idx - 65536;
    int k = i2 >> 9, n2 = i2 & 511;
    val = Wkv[i2]; dst = (size_t)(256 + n2) * 256 + k;
  } else {                         // Wp
    int i3 = idx - 196608;
    int k = i3 >> 8, n = i3 & 255;
    val = Wp[i3]; dst = (size_t)n * 256 + k; isp = true;
  }
  unsigned short h, l;
  split_bf(val, h, l);
  if (isp) { wpthi[dst] = h; wptlo[dst] = l; }
  else     { wthi[dst] = h; wtlo[dst] = l; }
}

// ---------------------------------------------------------------------------
// Per-query angle bias
// ---------------------------------------------------------------------------
__global__ __launch_bounds__(256) void bias_kernel(
    const float* __restrict__ affine, const float* __restrict__ atab,
    float* __restrict__ bias) {
  int idx = blockIdx.x * 256 + threadIdx.x;
  if (idx >= BB * NTOK) return;
  int b = idx >> 10, n = idx & (NTOK - 1);
  float cx = (float)(n & 31);
  float cy = (float)(n >> 5);
  const float* A = affine + b * 6;
  float egx = fmaf(A[0], 16.f, fmaf(A[1], 16.f, A[2]));
  float egy = fmaf(A[3], 16.f, fmaf(A[4], 16.f, A[5]));
  float ang = atan2f(cy - egy, cx - egx);
  float t = (ang + 3.14159265358979323846f) *
            (1.f / (2.f * 3.14159265358979323846f)) * 4.f;
  int bin = (int)t;
  bin = bin < 0 ? 0 : (bin > 4 ? 4 : bin);
  for (int h = 0; h < HEADS; ++h) {
    float a = atab[bin * HEADS + h];
    float s = 1.f / (1.f + __expf(-a));
    bias[((size_t)b * HEADS + h) * NTOK + n] = 1.f + s;
  }
}

// ---------------------------------------------------------------------------
// QKV projection, split-bf16 MFMA, no LDS. Block = 128 rows x 64 cols;
// wave w owns rows m0+32w..+31 (two 16-row fragments) x 64 cols.
// ---------------------------------------------------------------------------
__global__ __launch_bounds__(256) void gemm_qkv_mfma(
    const unsigned short* __restrict__ xhi, const unsigned short* __restrict__ xlo,
    const unsigned short* __restrict__ wthi, const unsigned short* __restrict__ wtlo,
    const float* __restrict__ bq, const float* __restrict__ bkv,
    const float* __restrict__ bias,
    unsigned short* __restrict__ qhi, unsigned short* __restrict__ qlo,
    unsigned short* __restrict__ khi, unsigned short* __restrict__ klo,
    unsigned short* __restrict__ vthi, unsigned short* __restrict__ vtlo) {
  int tid = threadIdx.x;
  int w = tid >> 6, l = tid & 63;
  int row16 = l & 15, grp = l >> 4;
  int j0 = blockIdx.x * 64;
  int m0 = blockIdx.y * 128;
  const unsigned short* a0h = xhi + ((size_t)(m0 + w * 32 + row16)) * CDIM;
  const unsigned short* a0l = xlo + ((size_t)(m0 + w * 32 + row16)) * CDIM;
  const unsigned short* a1h = a0h + 16 * CDIM;
  const unsigned short* a1l = a0l + 16 * CDIM;
  f32x4 acc[2][4];
#pragma unroll
  for (int i = 0; i < 2; ++i)
#pragma unroll
    for (int c = 0; c < 4; ++c) acc[i][c] = (f32x4){0.f, 0.f, 0.f, 0.f};
#pragma unroll
  for (int k0 = 0; k0 < CDIM; k0 += 32) {
    bf16x8 ah0 = ldb8(a0h + k0 + grp * 8);
    bf16x8 al0 = ldb8(a0l + k0 + grp * 8);
    bf16x8 ah1 = ldb8(a1h + k0 + grp * 8);
    bf16x8 al1 = ldb8(a1l + k0 + grp * 8);
#pragma unroll
    for (int c = 0; c < 4; ++c) {
      size_t boff = ((size_t)(j0 + c * 16 + row16)) * CDIM + k0 + grp * 8;
      bf16x8 bh = ldb8(wthi + boff);
      bf16x8 bl = ldb8(wtlo + boff);
      acc[0][c] = __builtin_amdgcn_mfma_f32_16x16x32_bf16(ah0, bh, acc[0][c], 0, 0, 0);
      acc[0][c] = __builtin_amdgcn_mfma_f32_16x16x32_bf16(al0, bh, acc[0][c], 0, 0, 0);
      acc[0][c] = __builtin_amdgcn_mfma_f32_16x16x32_bf16(ah0, bl, acc[0][c], 0, 0, 0);
      acc[1][c] = __builtin_amdgcn_mfma_f32_16x16x32_bf16(ah1, bh, acc[1][c], 0, 0, 0);
      acc[1][c] = __builtin_amdgcn_mfma_f32_16x16x32_bf16(al1, bh, acc[1][c], 0, 0, 0);
      acc[1][c] = __builtin_amdgcn_mfma_f32_16x16x32_bf16(ah1, bl, acc[1][c], 0, 0, 0);
    }
  }
  const float scale = 0.17677669529663687f;  // 32^-0.5
#pragma unroll
  for (int i = 0; i < 2; ++i) {
    int ng = m0 + w * 32 + i * 16 + grp * 4;
#pragma unroll
    for (int c = 0; c < 4; ++c) {
      int jg = j0 + c * 16 + row16;
#pragma unroll
      for (int r = 0; r < 4; ++r) {
        int m = ng + r;
        int b = m >> 10, n = m & (NTOK - 1);
        float val = acc[i][c][r];
        unsigned short hi, lo;
        if (jg < CDIM) {
          int h = jg >> 5, d = jg & 31;
          size_t idx = (((size_t)b * HEADS + h) * NTOK + n) * HD + d;
          float s = (val + bq[jg]) * scale * bias[((size_t)b * HEADS + h) * NTOK + n];
          split_bf(s, hi, lo);
          qhi[idx] = hi; qlo[idx] = lo;
        } else {
          int c2 = jg - CDIM;
          float vv = val + bkv[c2];
          if (c2 < CDIM) {
            int h = c2 >> 5, d = c2 & 31;
            size_t idx = (((size_t)b * HEADS + h) * NTOK + n) * HD + d;
            split_bf(vv, hi, lo);
            khi[idx] = hi; klo[idx] = lo;
          } else {
            int c3 = c2 - CDIM;
            int h = c3 >> 5, d = c3 & 31;
            size_t idxT = (((size_t)b * HEADS + h) * HD + d) * NTOK + n;
            split_bf(vv, hi, lo);
            vthi[idxT] = hi; vtlo[idxT] = lo;
          }
        }
      }
    }
  }
}

// ---------------------------------------------------------------------------
// MFMA flash attention, barriered global_load_lds double-buffer.
// Block = 512 threads (8 waves) = 128 queries x one (b,h). 16 k-tiles of 64.
// K tile [64k][32d] hi/lo, V^T tile [32d][64k] hi/lo staged via async DMA
// with pre-swizzled global source (XOR swizzle on both sides).
// No-max softmax: p = exp(s+mask); in-lane lsum[4]; one butterfly at end.
// P staged f32 in wave-private LDS stripe (round-2 proven scheme).
// ---------------------------------------------------------------------------
__global__ __launch_bounds__(512, 4) void attn_mfma(
    const unsigned short* __restrict__ qhi, const unsigned short* __restrict__ qlo,
    const unsigned short* __restrict__ khi_g, const unsigned short* __restrict__ klo_g,
    const unsigned short* __restrict__ vthi_g, const unsigned short* __restrict__ vtlo_g,
    const float* __restrict__ mask, unsigned short* __restrict__ aohi,
    unsigned short* __restrict__ aolo) {
  __shared__ __align__(16) unsigned short KT[2][2][64 * 32];  // [buf][hi/lo]
  __shared__ __align__(16) unsigned short VT[2][2][32 * 64];  // [buf][hi/lo]
  __shared__ __align__(16) float Pw[8][16][68];               // per-wave P

  int tid = threadIdx.x;
  int w = tid >> 6;        // wave 0..7
  int l = tid & 63;
  int row16 = l & 15;
  int grp = l >> 4;
  // XCD-chunked swizzle: 1024 blocks, 8 XCDs -> XCD x gets 16 (b,h) pairs.
  int bid = blockIdx.x;
  int swz = (bid & 7) * 128 + (bid >> 3);
  int qt = swz & 7, h = (swz >> 3) & 7, b = swz >> 6;
  int q0 = qt * 128;
  int bh = b * HEADS + h;

  // Q A-fragment (row=q=l&15, k=8*grp+j), held for the whole kernel
  size_t qidx = (((size_t)bh * NTOK) + q0 + w * 16 + row16) * HD + grp * 8;
  bf16x8 aqh = ldb8(qhi + qidx);
  bf16x8 aql = ldb8(qlo + qidx);

  const float* maskb = mask + (size_t)(b & 3) * NTOK * NTOK +
                       (size_t)(q0 + w * 16 + grp * 4) * NTOK + row16;

  f32x4 accd[2];
  accd[0] = (f32x4){0.f, 0.f, 0.f, 0.f};
  accd[1] = (f32x4){0.f, 0.f, 0.f, 0.f};
  float lsum[4] = {0.f, 0.f, 0.f, 0.f};
  const f32x4 zero4 = (f32x4){0.f, 0.f, 0.f, 0.f};

  // ---- staging lambda: wave w issues chunks 2w, 2w+1 of 16 x 1KB DMAs
  auto stage = [&](int nbuf, int kt2) {
    int k0n = kt2 * 64;
#pragma unroll
    for (int ci = 0; ci < 2; ++ci) {
      int c = w * 2 + ci;
      int comp = c >> 2;  // 0=Khi 1=Klo 2=Vhi 3=Vlo
      int sub = c & 3;
      if (comp < 2) {
        // K: [64k][32d], row = k (64B). dest linear; src col pre-swizzled.
        int kl = sub * 16 + (l >> 2);
        int cb = (l & 3) * 16;                       // dest byte in row
        int gd = (cb ^ ((kl & 3) << 4)) >> 1;        // global d elem
        const unsigned short* src =
            (comp ? klo_g : khi_g) + (((size_t)bh * NTOK) + k0n + kl) * HD + gd;
        gl_lds16(src, &KT[nbuf][comp][sub * 16 * 32]);
      } else {
        // V^T: [32d][64k], row = d (128B)
        int dl = sub * 8 + (l >> 3);
        int cb = (l & 7) * 16;
        int gk = (cb ^ ((dl & 7) << 4)) >> 1;        // global k elem offset
        const unsigned short* src = (comp == 3 ? vtlo_g : vthi_g) +
                                    ((size_t)bh * HD + dl) * NTOK + k0n + gk;
        gl_lds16(src, &VT[nbuf][comp - 2][sub * 8 * 64]);
      }
    }
  };

  stage(0, 0);
  __syncthreads();  // vmcnt drained -> buf0 ready

  for (int kt = 0; kt < 16; ++kt) {
    int cur = kt & 1;
    int k0 = kt * 64;
    if (kt < 15) stage(cur ^ 1, kt + 1);  // async DMA into other buffer

    // ---- mask loads hoisted into regs (latency covered by QK MFMAs)
    float mreg[4][4];
#pragma unroll
    for (int f = 0; f < 4; ++f)
#pragma unroll
      for (int r = 0; r < 4; ++r)
        mreg[f][r] = maskb[(size_t)r * NTOK + k0 + f * 16];

    // ---- QK^T from K LDS (swizzled read)
    f32x4 s[4];
#pragma unroll
    for (int f = 0; f < 4; ++f) {
      int kl = f * 16 + row16;
      int cb = (grp * 16) ^ ((kl & 3) << 4);
      const unsigned short* kp0 = &KT[cur][0][kl * 32 + (cb >> 1)];
      const unsigned short* kp1 = &KT[cur][1][kl * 32 + (cb >> 1)];
      bf16x8 kh = ldb8(kp0);
      bf16x8 kl2 = ldb8(kp1);
      f32x4 t = __builtin_amdgcn_mfma_f32_16x16x32_bf16(aqh, kh, zero4, 0, 0, 0);
      t = __builtin_amdgcn_mfma_f32_16x16x32_bf16(aql, kh, t, 0, 0, 0);
      t = __builtin_amdgcn_mfma_f32_16x16x32_bf16(aqh, kl2, t, 0, 0, 0);
      s[f] = t;
    }
    // ---- p = exp(s + mask), in-lane lsum, P -> wave-private LDS stripe
#pragma unroll
    for (int f = 0; f < 4; ++f) {
#pragma unroll
      for (int r = 0; r < 4; ++r) {
        float p = __expf(s[f][r] + mreg[f][r]);
        lsum[r] += p;
        Pw[w][grp * 4 + r][f * 16 + row16] = p;
      }
    }
    // ---- PV: P from LDS (split on read), V^T from LDS (swizzled read)
#pragma unroll
    for (int ks = 0; ks < 2; ++ks) {
      const float* prow = &Pw[w][row16][ks * 32 + grp * 8];
      float4 pa = *reinterpret_cast<const float4*>(prow);
      float4 pb = *reinterpret_cast<const float4*>(prow + 4);
      float pv[8] = {pa.x, pa.y, pa.z, pa.w, pb.x, pb.y, pb.z, pb.w};
      u16x8 hu, lu;
#pragma unroll
      for (int j = 0; j < 8; ++j) {
        unsigned short hh, ll;
        split_bf(pv[j], hh, ll);
        hu[j] = hh; lu[j] = ll;
      }
      bf16x8 phi = __builtin_bit_cast(bf16x8, hu);
      bf16x8 plo = __builtin_bit_cast(bf16x8, lu);
#pragma unroll
      for (int df = 0; df < 2; ++df) {
        int dl = df * 16 + row16;
        int cb = (ks * 64 + grp * 16) ^ ((dl & 7) << 4);
        const unsigned short* vp0 = &VT[cur][0][dl * 64 + (cb >> 1)];
        const unsigned short* vp1 = &VT[cur][1][dl * 64 + (cb >> 1)];
        bf16x8 vh = ldb8(vp0);
        bf16x8 vl = ldb8(vp1);
        accd[df] = __builtin_amdgcn_mfma_f32_16x16x32_bf16(phi, vh, accd[df], 0, 0, 0);
        accd[df] = __builtin_amdgcn_mfma_f32_16x16x32_bf16(plo, vh, accd[df], 0, 0, 0);
        accd[df] = __builtin_amdgcn_mfma_f32_16x16x32_bf16(phi, vl, accd[df], 0, 0, 0);
      }
    }
    __syncthreads();  // drains stage DMA + protects buffer swap
  }

  // ---- final row-sum reduction: butterfly over the 16-lane row16 group
#pragma unroll
  for (int r = 0; r < 4; ++r) {
#pragma unroll
    for (int off = 1; off < 16; off <<= 1)
      lsum[r] += __shfl_xor(lsum[r], off, 16);
  }
#pragma unroll
  for (int r = 0; r < 4; ++r) {
    float inv = 1.f / lsum[r];
    int qrow = q0 + w * 16 + grp * 4 + r;
    size_t obase = ((size_t)b * NTOK + qrow) * CDIM + h * HD;
    float v0 = accd[0][r] * inv, v1 = accd[1][r] * inv;
    unsigned short h0, l0, h1, l1;
    split_bf(v0, h0, l0);
    split_bf(v1, h1, l1);
    aohi[obase + row16] = h0; aolo[obase + row16] = l0;
    aohi[obase + 16 + row16] = h1; aolo[obase + 16 + row16] = l1;
  }
}

// ---------------------------------------------------------------------------
// Output projection, split-bf16 MFMA, 128-row blocks, 32-row wave tiles.
// ---------------------------------------------------------------------------
__global__ __launch_bounds__(256) void gemm_out_mfma(
    const unsigned short* __restrict__ ahi, const unsigned short* __restrict__ alo,
    const unsigned short* __restrict__ wpthi, const unsigned short* __restrict__ wptlo,
    const float* __restrict__ bp, float* __restrict__ out) {
  int tid = threadIdx.x;
  int w = tid >> 6, l = tid & 63;
  int row16 = l & 15, grp = l >> 4;
  int j0 = blockIdx.x * 64;
  int m0 = blockIdx.y * 128;
  const unsigned short* a0h = ahi + ((size_t)(m0 + w * 32 + row16)) * CDIM;
  const unsigned short* a0l = alo + ((size_t)(m0 + w * 32 + row16)) * CDIM;
  const unsigned short* a1h = a0h + 16 * CDIM;
  const unsigned short* a1l = a0l + 16 * CDIM;
  f32x4 acc[2][4];
#pragma unroll
  for (int i = 0; i < 2; ++i)
#pragma unroll
    for (int c = 0; c < 4; ++c) acc[i][c] = (f32x4){0.f, 0.f, 0.f, 0.f};
#pragma unroll
  for (int k0 = 0; k0 < CDIM; k0 += 32) {
    bf16x8 ah0 = ldb8(a0h + k0 + grp * 8);
    bf16x8 al0 = ldb8(a0l + k0 + grp * 8);
    bf16x8 ah1 = ldb8(a1h + k0 + grp * 8);
    bf16x8 al1 = ldb8(a1l + k0 + grp * 8);
#pragma unroll
    for (int c = 0; c < 4; ++c) {
      size_t boff = ((size_t)(j0 + c * 16 + row16)) * CDIM + k0 + grp * 8;
      bf16x8 bh = ldb8(wpthi + boff);
      bf16x8 bl = ldb8(wptlo + boff);
      acc[0][c] = __builtin_amdgcn_mfma_f32_16x16x32_bf16(ah0, bh, acc[0][c], 0, 0, 0);
      acc[0][c] = __builtin_amdgcn_mfma_f32_16x16x32_bf16(al0, bh, acc[0][c], 0, 0, 0);
      acc[0][c] = __builtin_amdgcn_mfma_f32_16x16x32_bf16(ah0, bl, acc[0][c], 0, 0, 0);
      acc[1][c] = __builtin_amdgcn_mfma_f32_16x16x32_bf16(ah1, bh, acc[1][c], 0, 0, 0);
      acc[1][c] = __builtin_amdgcn_mfma_f32_16x16x32_bf16(al1, bh, acc[1][c], 0, 0, 0);
      acc[1][c] = __builtin_amdgcn_mfma_f32_16x16x32_bf16(ah1, bl, acc[1][c], 0, 0, 0);
    }
  }
#pragma unroll
  for (int i = 0; i < 2; ++i) {
    int ng = m0 + w * 32 + i * 16 + grp * 4;
#pragma unroll
    for (int c = 0; c < 4; ++c) {
      int jg = j0 + c * 16 + row16;
      float bias = bp[jg];
#pragma unroll
      for (int r = 0; r < 4; ++r) {
        out[(size_t)(ng + r) * CDIM + jg] = acc[i][c][r] + bias;
      }
    }
  }
}

// ---------------------------------------------------------------------------
extern "C" void kernel_launch(void* const* d_in, const int* in_sizes, int n_in,
                              void* d_out, int out_size, void* d_ws,
                              size_t ws_size, hipStream_t stream) {
  const float* x = (const float*)d_in[0];
  const float* mask = (const float*)d_in[1];
  const float* affine = (const float*)d_in[2];
  const float* Wq = (const float*)d_in[3];
  const float* bq = (const float*)d_in[4];
  const float* Wkv = (const float*)d_in[5];
  const float* bkv = (const float*)d_in[6];
  const float* Wp = (const float*)d_in[7];
  const float* bp = (const float*)d_in[8];
  const float* atab = (const float*)d_in[9];
  float* out = (float*)d_out;

  const size_t bhnd = (size_t)BB * HEADS * NTOK * HD;  // 4,194,304
  unsigned short* qhi = (unsigned short*)d_ws;
  unsigned short* qlo = qhi + bhnd;
  unsigned short* khi = qlo + bhnd;
  unsigned short* klo = khi + bhnd;
  unsigned short* vthi = klo + bhnd;
  unsigned short* vtlo = vthi + bhnd;
  unsigned short* xhi = vtlo + bhnd;   // aliased as aout_hi after qkv
  unsigned short* xlo = xhi + bhnd;    // aliased as aout_lo after qkv
  unsigned short* wthi = xlo + bhnd;             // 768*256
  unsigned short* wtlo = wthi + 768 * 256;
  unsigned short* wpthi = wtlo + 768 * 256;      // 256*256
  unsigned short* wptlo = wpthi + 256 * 256;
  float* bias = (float*)(wptlo + 256 * 256);

  split_x<<<2048, 256, 0, stream>>>(x, xhi, xlo);
  split_w<<<1024, 256, 0, stream>>>(Wq, Wkv, Wp, wthi, wtlo, wpthi, wptlo);
  bias_kernel<<<64, 256, 0, stream>>>(affine, atab, bias);
  gemm_qkv_mfma<<<dim3(12, 128), 256, 0, stream>>>(
      xhi, xlo, wthi, wtlo, bq, bkv, bias, qhi, qlo, khi, klo, vthi, vtlo);
  attn_mfma<<<1024, 512, 0, stream>>>(qhi, qlo, khi, klo, vthi, vtlo, mask,
                                      xhi, xlo);
  gemm_out_mfma<<<dim3(4, 128), 256, 0, stream>>>(xhi, xlo, wpthi, wptlo, bp,
                                                  out);
}

// Round 7
// 196.888 us; speedup vs baseline: 2.1721x; 1.0938x over previous
//
#include <hip/hip_runtime.h>
#include <hip/hip_bf16.h>
#include <math.h>

#define BB 16
#define NTOK 1024
#define CDIM 256
#define HEADS 8
#define HD 32

typedef __attribute__((ext_vector_type(8))) __bf16 bf16x8;
typedef __attribute__((ext_vector_type(8))) unsigned short u16x8;
typedef __attribute__((ext_vector_type(4))) float f32x4;

// Split fp32 into bf16 hi (truncation) + bf16 lo (truncation of residual).
__device__ __forceinline__ void split_bf(float f, unsigned short& hi,
                                         unsigned short& lo) {
  unsigned u = __float_as_uint(f);
  hi = (unsigned short)(u >> 16);
  float fl = f - __uint_as_float(u & 0xFFFF0000u);
  lo = (unsigned short)(__float_as_uint(fl) >> 16);
}

__device__ __forceinline__ bf16x8 ldb8(const unsigned short* p) {
  return *reinterpret_cast<const bf16x8*>(p);
}

// async global->LDS 16B DMA: per-lane global src, wave-uniform LDS base
// (HW adds lane*16 to the dest).
__device__ __forceinline__ void gl_lds16(const unsigned short* g,
                                         unsigned short* l) {
  __builtin_amdgcn_global_load_lds(
      (const __attribute__((address_space(1))) unsigned int*)g,
      (__attribute__((address_space(3))) unsigned int*)l, 16, 0, 0);
}

// ---------------------------------------------------------------------------
// Split X (16384x256 fp32) into bf16 hi/lo, 8 elems/thread.
// ---------------------------------------------------------------------------
__global__ __launch_bounds__(256) void split_x(const float* __restrict__ X,
                                               unsigned short* __restrict__ xhi,
                                               unsigned short* __restrict__ xlo) {
  size_t base = ((size_t)blockIdx.x * 256 + threadIdx.x) * 8;
  float4 a = *(const float4*)(X + base);
  float4 b = *(const float4*)(X + base + 4);
  float v[8] = {a.x, a.y, a.z, a.w, b.x, b.y, b.z, b.w};
  u16x8 h, l;
#pragma unroll
  for (int j = 0; j < 8; ++j) {
    unsigned short hh, ll;
    split_bf(v[j], hh, ll);
    h[j] = hh; l[j] = ll;
  }
  *(u16x8*)(xhi + base) = h;
  *(u16x8*)(xlo + base) = l;
}

// ---------------------------------------------------------------------------
// Split + transpose weights into (N,K) hi/lo.
// ---------------------------------------------------------------------------
__global__ __launch_bounds__(256) void split_w(
    const float* __restrict__ Wq, const float* __restrict__ Wkv,
    const float* __restrict__ Wp, unsigned short* __restrict__ wthi,
    unsigned short* __restrict__ wtlo, unsigned short* __restrict__ wpthi,
    unsigned short* __restrict__ wptlo) {
  int idx = blockIdx.x * 256 + threadIdx.x;  // 0 .. 262143
  float val; size_t dst; bool isp = false;
  if (idx < 65536) {               // Wq: (k,n)
    int k = idx >> 8, n = idx & 255;
    val = Wq[idx]; dst = (size_t)n * 256 + k;
  } else if (idx < 196608) {       // Wkv: (k,n2) -> cols 256..767
    int i2 = idx - 65536;
    int k = i2 >> 9, n2 = i2 & 511;
    val = Wkv[i2]; dst = (size_t)(256 + n2) * 256 + k;
  } else {                         // Wp
    int i3 = idx - 196608;
    int k = i3 >> 8, n = i3 & 255;
    val = Wp[i3]; dst = (size_t)n * 256 + k; isp = true;
  }
  unsigned short h, l;
  split_bf(val, h, l);
  if (isp) { wpthi[dst] = h; wptlo[dst] = l; }
  else     { wthi[dst] = h; wtlo[dst] = l; }
}

// ---------------------------------------------------------------------------
// Per-query angle bias
// ---------------------------------------------------------------------------
__global__ __launch_bounds__(256) void bias_kernel(
    const float* __restrict__ affine, const float* __restrict__ atab,
    float* __restrict__ bias) {
  int idx = blockIdx.x * 256 + threadIdx.x;
  if (idx >= BB * NTOK) return;
  int b = idx >> 10, n = idx & (NTOK - 1);
  float cx = (float)(n & 31);
  float cy = (float)(n >> 5);
  const float* A = affine + b * 6;
  float egx = fmaf(A[0], 16.f, fmaf(A[1], 16.f, A[2]));
  float egy = fmaf(A[3], 16.f, fmaf(A[4], 16.f, A[5]));
  float ang = atan2f(cy - egy, cx - egx);
  float t = (ang + 3.14159265358979323846f) *
            (1.f / (2.f * 3.14159265358979323846f)) * 4.f;
  int bin = (int)t;
  bin = bin < 0 ? 0 : (bin > 4 ? 4 : bin);
  for (int h = 0; h < HEADS; ++h) {
    float a = atab[bin * HEADS + h];
    float s = 1.f / (1.f + __expf(-a));
    bias[((size_t)b * HEADS + h) * NTOK + n] = 1.f + s;
  }
}

// ---------------------------------------------------------------------------
// QKV projection, split-bf16 MFMA, LDS-staged (global_load_lds dbuf).
// Block = 256 thr (4 waves) = 128 m-rows x 64 n-cols. W panel [64n][256k]
// hi/lo staged once (XOR-swizzled); X tiles [128m][64k] hi/lo double-buffered.
// Wave w owns rows w*32..+31 (2 A-frags) x 64 cols (4 B-frags).
// ---------------------------------------------------------------------------
__global__ __launch_bounds__(256) void gemm_qkv_mfma(
    const unsigned short* __restrict__ xhi, const unsigned short* __restrict__ xlo,
    const unsigned short* __restrict__ wthi, const unsigned short* __restrict__ wtlo,
    const float* __restrict__ bq, const float* __restrict__ bkv,
    const float* __restrict__ bias,
    unsigned short* __restrict__ qhi, unsigned short* __restrict__ qlo,
    unsigned short* __restrict__ khi, unsigned short* __restrict__ klo,
    unsigned short* __restrict__ vthi, unsigned short* __restrict__ vtlo) {
  __shared__ __align__(16) unsigned short Wl[2][64 * 256];     // 64 KB
  __shared__ __align__(16) unsigned short Xl[2][2][128 * 64];  // 64 KB
  int tid = threadIdx.x;
  int w = tid >> 6, l = tid & 63;
  int row16 = l & 15, grp = l >> 4;
  int j0 = blockIdx.x * 64;
  int m0 = blockIdx.y * 128;

  // ---- stage W panel (once): rows n (512B), src col pre-swizzled by n&7
#pragma unroll
  for (int i = 0; i < 16; ++i) {
    int c = i * 4 + w;             // 0..63 chunks of 1KB
    int comp = c >> 5, cc = c & 31;
    int nl = cc * 2 + (l >> 5);
    int kb = (l & 31) * 16;
    int gkb = kb ^ ((nl & 7) << 4);
    const unsigned short* src =
        (comp ? wtlo : wthi) + (size_t)(j0 + nl) * 256 + (gkb >> 1);
    gl_lds16(src, &Wl[comp][cc * 512]);
  }

  // ---- X tile staging lambda (rows m 128B, src col pre-swizzled by m&7)
  auto stage_x = [&](int nb, int kt) {
    int k0 = kt * 64;
#pragma unroll
    for (int i = 0; i < 8; ++i) {
      int c = i * 4 + w;           // 0..31 chunks of 1KB
      int comp = c >> 4, cc = c & 15;
      int ml = cc * 8 + (l >> 3);
      int kb = (l & 7) * 16;
      int gkb = kb ^ ((ml & 7) << 4);
      const unsigned short* src =
          (comp ? xlo : xhi) + (size_t)(m0 + ml) * 256 + k0 + (gkb >> 1);
      gl_lds16(src, &Xl[nb][comp][cc * 512]);
    }
  };

  stage_x(0, 0);
  __syncthreads();  // vmcnt drained: W panel + X tile 0 ready

  f32x4 acc[2][4];
#pragma unroll
  for (int i = 0; i < 2; ++i)
#pragma unroll
    for (int c = 0; c < 4; ++c) acc[i][c] = (f32x4){0.f, 0.f, 0.f, 0.f};

  for (int kt = 0; kt < 4; ++kt) {
    int cur = kt & 1;
    if (kt < 3) stage_x(cur ^ 1, kt + 1);
#pragma unroll
    for (int kc = 0; kc < 2; ++kc) {
      bf16x8 ah[2], al[2];
#pragma unroll
      for (int rf = 0; rf < 2; ++rf) {
        int ml = w * 32 + rf * 16 + row16;
        int ab = (kc * 64 + grp * 16) ^ ((ml & 7) << 4);
        ah[rf] = ldb8(&Xl[cur][0][ml * 64 + (ab >> 1)]);
        al[rf] = ldb8(&Xl[cur][1][ml * 64 + (ab >> 1)]);
      }
#pragma unroll
      for (int c = 0; c < 4; ++c) {
        int nl = c * 16 + row16;
        int bb = (kt * 128 + kc * 64 + grp * 16) ^ ((nl & 7) << 4);
        bf16x8 bh = ldb8(&Wl[0][nl * 256 + (bb >> 1)]);
        bf16x8 bl = ldb8(&Wl[1][nl * 256 + (bb >> 1)]);
#pragma unroll
        for (int rf = 0; rf < 2; ++rf) {
          acc[rf][c] = __builtin_amdgcn_mfma_f32_16x16x32_bf16(ah[rf], bh, acc[rf][c], 0, 0, 0);
          acc[rf][c] = __builtin_amdgcn_mfma_f32_16x16x32_bf16(al[rf], bh, acc[rf][c], 0, 0, 0);
          acc[rf][c] = __builtin_amdgcn_mfma_f32_16x16x32_bf16(ah[rf], bl, acc[rf][c], 0, 0, 0);
        }
      }
    }
    __syncthreads();  // drains next-tile DMA + protects buffer reuse
  }

  const float scale = 0.17677669529663687f;  // 32^-0.5
#pragma unroll
  for (int i = 0; i < 2; ++i) {
    int ng = m0 + w * 32 + i * 16 + grp * 4;
#pragma unroll
    for (int c = 0; c < 4; ++c) {
      int jg = j0 + c * 16 + row16;
#pragma unroll
      for (int r = 0; r < 4; ++r) {
        int m = ng + r;
        int b = m >> 10, n = m & (NTOK - 1);
        float val = acc[i][c][r];
        unsigned short hi, lo;
        if (jg < CDIM) {
          int h = jg >> 5, d = jg & 31;
          size_t idx = (((size_t)b * HEADS + h) * NTOK + n) * HD + d;
          float s = (val + bq[jg]) * scale * bias[((size_t)b * HEADS + h) * NTOK + n];
          split_bf(s, hi, lo);
          qhi[idx] = hi; qlo[idx] = lo;
        } else {
          int c2 = jg - CDIM;
          float vv = val + bkv[c2];
          if (c2 < CDIM) {
            int h = c2 >> 5, d = c2 & 31;
            size_t idx = (((size_t)b * HEADS + h) * NTOK + n) * HD + d;
            split_bf(vv, hi, lo);
            khi[idx] = hi; klo[idx] = lo;
          } else {
            int c3 = c2 - CDIM;
            int h = c3 >> 5, d = c3 & 31;
            size_t idxT = (((size_t)b * HEADS + h) * HD + d) * NTOK + n;
            split_bf(vv, hi, lo);
            vthi[idxT] = hi; vtlo[idxT] = lo;
          }
        }
      }
    }
  }
}

// ---------------------------------------------------------------------------
// MFMA flash attention, barriered global_load_lds double-buffer (round-6).
// ---------------------------------------------------------------------------
__global__ __launch_bounds__(512, 4) void attn_mfma(
    const unsigned short* __restrict__ qhi, const unsigned short* __restrict__ qlo,
    const unsigned short* __restrict__ khi_g, const unsigned short* __restrict__ klo_g,
    const unsigned short* __restrict__ vthi_g, const unsigned short* __restrict__ vtlo_g,
    const float* __restrict__ mask, unsigned short* __restrict__ aohi,
    unsigned short* __restrict__ aolo) {
  __shared__ __align__(16) unsigned short KT[2][2][64 * 32];  // [buf][hi/lo]
  __shared__ __align__(16) unsigned short VT[2][2][32 * 64];  // [buf][hi/lo]
  __shared__ __align__(16) float Pw[8][16][68];               // per-wave P

  int tid = threadIdx.x;
  int w = tid >> 6;        // wave 0..7
  int l = tid & 63;
  int row16 = l & 15;
  int grp = l >> 4;
  int bid = blockIdx.x;
  int swz = (bid & 7) * 128 + (bid >> 3);
  int qt = swz & 7, h = (swz >> 3) & 7, b = swz >> 6;
  int q0 = qt * 128;
  int bh = b * HEADS + h;

  size_t qidx = (((size_t)bh * NTOK) + q0 + w * 16 + row16) * HD + grp * 8;
  bf16x8 aqh = ldb8(qhi + qidx);
  bf16x8 aql = ldb8(qlo + qidx);

  const float* maskb = mask + (size_t)(b & 3) * NTOK * NTOK +
                       (size_t)(q0 + w * 16 + grp * 4) * NTOK + row16;

  f32x4 accd[2];
  accd[0] = (f32x4){0.f, 0.f, 0.f, 0.f};
  accd[1] = (f32x4){0.f, 0.f, 0.f, 0.f};
  float lsum[4] = {0.f, 0.f, 0.f, 0.f};
  const f32x4 zero4 = (f32x4){0.f, 0.f, 0.f, 0.f};

  auto stage = [&](int nbuf, int kt2) {
    int k0n = kt2 * 64;
#pragma unroll
    for (int ci = 0; ci < 2; ++ci) {
      int c = w * 2 + ci;
      int comp = c >> 2;  // 0=Khi 1=Klo 2=Vhi 3=Vlo
      int sub = c & 3;
      if (comp < 2) {
        int kl = sub * 16 + (l >> 2);
        int cb = (l & 3) * 16;
        int gd = (cb ^ ((kl & 3) << 4)) >> 1;
        const unsigned short* src =
            (comp ? klo_g : khi_g) + (((size_t)bh * NTOK) + k0n + kl) * HD + gd;
        gl_lds16(src, &KT[nbuf][comp][sub * 16 * 32]);
      } else {
        int dl = sub * 8 + (l >> 3);
        int cb = (l & 7) * 16;
        int gk = (cb ^ ((dl & 7) << 4)) >> 1;
        const unsigned short* src = (comp == 3 ? vtlo_g : vthi_g) +
                                    ((size_t)bh * HD + dl) * NTOK + k0n + gk;
        gl_lds16(src, &VT[nbuf][comp - 2][sub * 8 * 64]);
      }
    }
  };

  stage(0, 0);
  __syncthreads();

  for (int kt = 0; kt < 16; ++kt) {
    int cur = kt & 1;
    int k0 = kt * 64;
    if (kt < 15) stage(cur ^ 1, kt + 1);

    float mreg[4][4];
#pragma unroll
    for (int f = 0; f < 4; ++f)
#pragma unroll
      for (int r = 0; r < 4; ++r)
        mreg[f][r] = maskb[(size_t)r * NTOK + k0 + f * 16];

    f32x4 s[4];
#pragma unroll
    for (int f = 0; f < 4; ++f) {
      int kl = f * 16 + row16;
      int cb = (grp * 16) ^ ((kl & 3) << 4);
      const unsigned short* kp0 = &KT[cur][0][kl * 32 + (cb >> 1)];
      const unsigned short* kp1 = &KT[cur][1][kl * 32 + (cb >> 1)];
      bf16x8 kh = ldb8(kp0);
      bf16x8 kl2 = ldb8(kp1);
      f32x4 t = __builtin_amdgcn_mfma_f32_16x16x32_bf16(aqh, kh, zero4, 0, 0, 0);
      t = __builtin_amdgcn_mfma_f32_16x16x32_bf16(aql, kh, t, 0, 0, 0);
      t = __builtin_amdgcn_mfma_f32_16x16x32_bf16(aqh, kl2, t, 0, 0, 0);
      s[f] = t;
    }
#pragma unroll
    for (int f = 0; f < 4; ++f) {
#pragma unroll
      for (int r = 0; r < 4; ++r) {
        float p = __expf(s[f][r] + mreg[f][r]);
        lsum[r] += p;
        Pw[w][grp * 4 + r][f * 16 + row16] = p;
      }
    }
#pragma unroll
    for (int ks = 0; ks < 2; ++ks) {
      const float* prow = &Pw[w][row16][ks * 32 + grp * 8];
      float4 pa = *reinterpret_cast<const float4*>(prow);
      float4 pb = *reinterpret_cast<const float4*>(prow + 4);
      float pv[8] = {pa.x, pa.y, pa.z, pa.w, pb.x, pb.y, pb.z, pb.w};
      u16x8 hu, lu;
#pragma unroll
      for (int j = 0; j < 8; ++j) {
        unsigned short hh, ll;
        split_bf(pv[j], hh, ll);
        hu[j] = hh; lu[j] = ll;
      }
      bf16x8 phi = __builtin_bit_cast(bf16x8, hu);
      bf16x8 plo = __builtin_bit_cast(bf16x8, lu);
#pragma unroll
      for (int df = 0; df < 2; ++df) {
        int dl = df * 16 + row16;
        int cb = (ks * 64 + grp * 16) ^ ((dl & 7) << 4);
        const unsigned short* vp0 = &VT[cur][0][dl * 64 + (cb >> 1)];
        const unsigned short* vp1 = &VT[cur][1][dl * 64 + (cb >> 1)];
        bf16x8 vh = ldb8(vp0);
        bf16x8 vl = ldb8(vp1);
        accd[df] = __builtin_amdgcn_mfma_f32_16x16x32_bf16(phi, vh, accd[df], 0, 0, 0);
        accd[df] = __builtin_amdgcn_mfma_f32_16x16x32_bf16(plo, vh, accd[df], 0, 0, 0);
        accd[df] = __builtin_amdgcn_mfma_f32_16x16x32_bf16(phi, vl, accd[df], 0, 0, 0);
      }
    }
    __syncthreads();
  }

#pragma unroll
  for (int r = 0; r < 4; ++r) {
#pragma unroll
    for (int off = 1; off < 16; off <<= 1)
      lsum[r] += __shfl_xor(lsum[r], off, 16);
  }
#pragma unroll
  for (int r = 0; r < 4; ++r) {
    float inv = 1.f / lsum[r];
    int qrow = q0 + w * 16 + grp * 4 + r;
    size_t obase = ((size_t)b * NTOK + qrow) * CDIM + h * HD;
    float v0 = accd[0][r] * inv, v1 = accd[1][r] * inv;
    unsigned short h0, l0, h1, l1;
    split_bf(v0, h0, l0);
    split_bf(v1, h1, l1);
    aohi[obase + row16] = h0; aolo[obase + row16] = l0;
    aohi[obase + 16 + row16] = h1; aolo[obase + 16 + row16] = l1;
  }
}

// ---------------------------------------------------------------------------
// Output projection, split-bf16 MFMA, LDS-staged like gemm_qkv_mfma.
// ---------------------------------------------------------------------------
__global__ __launch_bounds__(256) void gemm_out_mfma(
    const unsigned short* __restrict__ ahi, const unsigned short* __restrict__ alo,
    const unsigned short* __restrict__ wpthi, const unsigned short* __restrict__ wptlo,
    const float* __restrict__ bp, float* __restrict__ out) {
  __shared__ __align__(16) unsigned short Wl[2][64 * 256];     // 64 KB
  __shared__ __align__(16) unsigned short Xl[2][2][128 * 64];  // 64 KB
  int tid = threadIdx.x;
  int w = tid >> 6, l = tid & 63;
  int row16 = l & 15, grp = l >> 4;
  int j0 = blockIdx.x * 64;
  int m0 = blockIdx.y * 128;

#pragma unroll
  for (int i = 0; i < 16; ++i) {
    int c = i * 4 + w;
    int comp = c >> 5, cc = c & 31;
    int nl = cc * 2 + (l >> 5);
    int kb = (l & 31) * 16;
    int gkb = kb ^ ((nl & 7) << 4);
    const unsigned short* src =
        (comp ? wptlo : wpthi) + (size_t)(j0 + nl) * 256 + (gkb >> 1);
    gl_lds16(src, &Wl[comp][cc * 512]);
  }

  auto stage_x = [&](int nb, int kt) {
    int k0 = kt * 64;
#pragma unroll
    for (int i = 0; i < 8; ++i) {
      int c = i * 4 + w;
      int comp = c >> 4, cc = c & 15;
      int ml = cc * 8 + (l >> 3);
      int kb = (l & 7) * 16;
      int gkb = kb ^ ((ml & 7) << 4);
      const unsigned short* src =
          (comp ? alo : ahi) + (size_t)(m0 + ml) * 256 + k0 + (gkb >> 1);
      gl_lds16(src, &Xl[nb][comp][cc * 512]);
    }
  };

  stage_x(0, 0);
  __syncthreads();

  f32x4 acc[2][4];
#pragma unroll
  for (int i = 0; i < 2; ++i)
#pragma unroll
    for (int c = 0; c < 4; ++c) acc[i][c] = (f32x4){0.f, 0.f, 0.f, 0.f};

  for (int kt = 0; kt < 4; ++kt) {
    int cur = kt & 1;
    if (kt < 3) stage_x(cur ^ 1, kt + 1);
#pragma unroll
    for (int kc = 0; kc < 2; ++kc) {
      bf16x8 ah[2], al[2];
#pragma unroll
      for (int rf = 0; rf < 2; ++rf) {
        int ml = w * 32 + rf * 16 + row16;
        int ab = (kc * 64 + grp * 16) ^ ((ml & 7) << 4);
        ah[rf] = ldb8(&Xl[cur][0][ml * 64 + (ab >> 1)]);
        al[rf] = ldb8(&Xl[cur][1][ml * 64 + (ab >> 1)]);
      }
#pragma unroll
      for (int c = 0; c < 4; ++c) {
        int nl = c * 16 + row16;
        int bb = (kt * 128 + kc * 64 + grp * 16) ^ ((nl & 7) << 4);
        bf16x8 bh = ldb8(&Wl[0][nl * 256 + (bb >> 1)]);
        bf16x8 bl = ldb8(&Wl[1][nl * 256 + (bb >> 1)]);
#pragma unroll
        for (int rf = 0; rf < 2; ++rf) {
          acc[rf][c] = __builtin_amdgcn_mfma_f32_16x16x32_bf16(ah[rf], bh, acc[rf][c], 0, 0, 0);
          acc[rf][c] = __builtin_amdgcn_mfma_f32_16x16x32_bf16(al[rf], bh, acc[rf][c], 0, 0, 0);
          acc[rf][c] = __builtin_amdgcn_mfma_f32_16x16x32_bf16(ah[rf], bl, acc[rf][c], 0, 0, 0);
        }
      }
    }
    __syncthreads();
  }

#pragma unroll
  for (int i = 0; i < 2; ++i) {
    int ng = m0 + w * 32 + i * 16 + grp * 4;
#pragma unroll
    for (int c = 0; c < 4; ++c) {
      int jg = j0 + c * 16 + row16;
      float bias = bp[jg];
#pragma unroll
      for (int r = 0; r < 4; ++r) {
        out[(size_t)(ng + r) * CDIM + jg] = acc[i][c][r] + bias;
      }
    }
  }
}

// ---------------------------------------------------------------------------
extern "C" void kernel_launch(void* const* d_in, const int* in_sizes, int n_in,
                              void* d_out, int out_size, void* d_ws,
                              size_t ws_size, hipStream_t stream) {
  const float* x = (const float*)d_in[0];
  const float* mask = (const float*)d_in[1];
  const float* affine = (const float*)d_in[2];
  const float* Wq = (const float*)d_in[3];
  const float* bq = (const float*)d_in[4];
  const float* Wkv = (const float*)d_in[5];
  const float* bkv = (const float*)d_in[6];
  const float* Wp = (const float*)d_in[7];
  const float* bp = (const float*)d_in[8];
  const float* atab = (const float*)d_in[9];
  float* out = (float*)d_out;

  const size_t bhnd = (size_t)BB * HEADS * NTOK * HD;  // 4,194,304
  unsigned short* qhi = (unsigned short*)d_ws;
  unsigned short* qlo = qhi + bhnd;
  unsigned short* khi = qlo + bhnd;
  unsigned short* klo = khi + bhnd;
  unsigned short* vthi = klo + bhnd;
  unsigned short* vtlo = vthi + bhnd;
  unsigned short* xhi = vtlo + bhnd;   // aliased as aout_hi after qkv
  unsigned short* xlo = xhi + bhnd;    // aliased as aout_lo after qkv
  unsigned short* wthi = xlo + bhnd;             // 768*256
  unsigned short* wtlo = wthi + 768 * 256;
  unsigned short* wpthi = wtlo + 768 * 256;      // 256*256
  unsigned short* wptlo = wpthi + 256 * 256;
  float* bias = (float*)(wptlo + 256 * 256);

  split_x<<<2048, 256, 0, stream>>>(x, xhi, xlo);
  split_w<<<1024, 256, 0, stream>>>(Wq, Wkv, Wp, wthi, wtlo, wpthi, wptlo);
  bias_kernel<<<64, 256, 0, stream>>>(affine, atab, bias);
  gemm_qkv_mfma<<<dim3(12, 128), 256, 0, stream>>>(
      xhi, xlo, wthi, wtlo, bq, bkv, bias, qhi, qlo, khi, klo, vthi, vtlo);
  attn_mfma<<<1024, 512, 0, stream>>>(qhi, qlo, khi, klo, vthi, vtlo, mask,
                                      xhi, xlo);
  gemm_out_mfma<<<dim3(4, 128), 256, 0, stream>>>(xhi, xlo, wpthi, wptlo, bp,
                                                  out);
}

// Round 8
// 168.081 us; speedup vs baseline: 2.5443x; 1.1714x over previous
//
#include <hip/hip_runtime.h>
#include <hip/hip_bf16.h>
#include <math.h>

#define BB 16
#define NTOK 1024
#define CDIM 256
#define HEADS 8
#define HD 32

typedef __attribute__((ext_vector_type(8))) __bf16 bf16x8;
typedef __attribute__((ext_vector_type(8))) unsigned short u16x8;
typedef __attribute__((ext_vector_type(4))) float f32x4;

// Split fp32 into bf16 hi (truncation) + bf16 lo (truncation of residual).
__device__ __forceinline__ void split_bf(float f, unsigned short& hi,
                                         unsigned short& lo) {
  unsigned u = __float_as_uint(f);
  hi = (unsigned short)(u >> 16);
  float fl = f - __uint_as_float(u & 0xFFFF0000u);
  lo = (unsigned short)(__float_as_uint(fl) >> 16);
}

__device__ __forceinline__ bf16x8 ldb8(const unsigned short* p) {
  return *reinterpret_cast<const bf16x8*>(p);
}

// async global->LDS 16B DMA: per-lane global src, wave-uniform LDS base
// (HW adds lane*16 to the dest).
__device__ __forceinline__ void gl_lds16(const unsigned short* g,
                                         unsigned short* l) {
  __builtin_amdgcn_global_load_lds(
      (const __attribute__((address_space(1))) unsigned int*)g,
      (__attribute__((address_space(3))) unsigned int*)l, 16, 0, 0);
}

// ---------------------------------------------------------------------------
// Split X (16384x256 fp32) into bf16 hi/lo, 8 elems/thread.
// ---------------------------------------------------------------------------
__global__ __launch_bounds__(256) void split_x(const float* __restrict__ X,
                                               unsigned short* __restrict__ xhi,
                                               unsigned short* __restrict__ xlo) {
  size_t base = ((size_t)blockIdx.x * 256 + threadIdx.x) * 8;
  float4 a = *(const float4*)(X + base);
  float4 b = *(const float4*)(X + base + 4);
  float v[8] = {a.x, a.y, a.z, a.w, b.x, b.y, b.z, b.w};
  u16x8 h, l;
#pragma unroll
  for (int j = 0; j < 8; ++j) {
    unsigned short hh, ll;
    split_bf(v[j], hh, ll);
    h[j] = hh; l[j] = ll;
  }
  *(u16x8*)(xhi + base) = h;
  *(u16x8*)(xlo + base) = l;
}

// ---------------------------------------------------------------------------
// Split + transpose weights into (N,K) hi/lo.
// ---------------------------------------------------------------------------
__global__ __launch_bounds__(256) void split_w(
    const float* __restrict__ Wq, const float* __restrict__ Wkv,
    const float* __restrict__ Wp, unsigned short* __restrict__ wthi,
    unsigned short* __restrict__ wtlo, unsigned short* __restrict__ wpthi,
    unsigned short* __restrict__ wptlo) {
  int idx = blockIdx.x * 256 + threadIdx.x;  // 0 .. 262143
  float val; size_t dst; bool isp = false;
  if (idx < 65536) {               // Wq: (k,n)
    int k = idx >> 8, n = idx & 255;
    val = Wq[idx]; dst = (size_t)n * 256 + k;
  } else if (idx < 196608) {       // Wkv: (k,n2) -> cols 256..767
    int i2 = idx - 65536;
    int k = i2 >> 9, n2 = i2 & 511;
    val = Wkv[i2]; dst = (size_t)(256 + n2) * 256 + k;
  } else {                         // Wp
    int i3 = idx - 196608;
    int k = i3 >> 8, n = i3 & 255;
    val = Wp[i3]; dst = (size_t)n * 256 + k; isp = true;
  }
  unsigned short h, l;
  split_bf(val, h, l);
  if (isp) { wpthi[dst] = h; wptlo[dst] = l; }
  else     { wthi[dst] = h; wtlo[dst] = l; }
}

// ---------------------------------------------------------------------------
// Per-query angle bias
// ---------------------------------------------------------------------------
__global__ __launch_bounds__(256) void bias_kernel(
    const float* __restrict__ affine, const float* __restrict__ atab,
    float* __restrict__ bias) {
  int idx = blockIdx.x * 256 + threadIdx.x;
  if (idx >= BB * NTOK) return;
  int b = idx >> 10, n = idx & (NTOK - 1);
  float cx = (float)(n & 31);
  float cy = (float)(n >> 5);
  const float* A = affine + b * 6;
  float egx = fmaf(A[0], 16.f, fmaf(A[1], 16.f, A[2]));
  float egy = fmaf(A[3], 16.f, fmaf(A[4], 16.f, A[5]));
  float ang = atan2f(cy - egy, cx - egx);
  float t = (ang + 3.14159265358979323846f) *
            (1.f / (2.f * 3.14159265358979323846f)) * 4.f;
  int bin = (int)t;
  bin = bin < 0 ? 0 : (bin > 4 ? 4 : bin);
  for (int h = 0; h < HEADS; ++h) {
    float a = atab[bin * HEADS + h];
    float s = 1.f / (1.f + __expf(-a));
    bias[((size_t)b * HEADS + h) * NTOK + n] = 1.f + s;
  }
}

// ===========================================================================
// Shared GEMM core pieces: 512 thr (8 waves, 4m x 2n), tile 128m x 128n,
// BK=32 double-buffered for BOTH operands. LDS 64 KB -> 2 blocks/CU.
// Superrow swizzle: linear DMA dest; 16B slot s of 128B superrow R holds
// logical slot s^(R&7); reads apply the same XOR.
// ===========================================================================
// Staging: each wave stages chunk w (rows w*16..+15) of each component.
#define GEMM_STAGE(nb, kt, AHI, ALO, BHI, BLO, Xs, Ws)                        \
  {                                                                           \
    int k0s = (kt) * 32;                                                      \
    int sl = (l & 7) ^ (l >> 3);                                              \
    int row = w * 16 + 2 * (l >> 3) + (sl >> 2);                              \
    int ke = (sl & 3) * 8;                                                    \
    gl_lds16(AHI + (size_t)(m0 + row) * 256 + k0s + ke, &Xs[nb][0][w * 512]); \
    gl_lds16(ALO + (size_t)(m0 + row) * 256 + k0s + ke, &Xs[nb][1][w * 512]); \
    gl_lds16(BHI + (size_t)(j0 + row) * 256 + k0s + ke, &Ws[nb][0][w * 512]); \
    gl_lds16(BLO + (size_t)(j0 + row) * 256 + k0s + ke, &Ws[nb][1][w * 512]); \
  }

// swizzled LDS read offset (u16 elems) for logical (row, grp)
__device__ __forceinline__ int swz_off(int row, int grp) {
  int R = row >> 1;
  int phys = (((row & 1) << 2) | grp) ^ (R & 7);
  return R * 64 + phys * 8;
}

// ---------------------------------------------------------------------------
// QKV projection. Grid 768 = 8 XCD x (6 j x 16 m); each XCD owns a 2048-row
// m-slice across all j (X slice 2MB -> L2-resident).
// ---------------------------------------------------------------------------
__global__ __launch_bounds__(512, 4) void gemm_qkv_mfma(
    const unsigned short* __restrict__ xhi, const unsigned short* __restrict__ xlo,
    const unsigned short* __restrict__ wthi, const unsigned short* __restrict__ wtlo,
    const float* __restrict__ bq, const float* __restrict__ bkv,
    const float* __restrict__ bias,
    unsigned short* __restrict__ qhi, unsigned short* __restrict__ qlo,
    unsigned short* __restrict__ khi, unsigned short* __restrict__ klo,
    unsigned short* __restrict__ vthi, unsigned short* __restrict__ vtlo) {
  __shared__ __align__(16) unsigned short Xs[2][2][4096];  // 32 KB
  __shared__ __align__(16) unsigned short Ws[2][2][4096];  // 32 KB
  int tid = threadIdx.x;
  int w = tid >> 6, l = tid & 63;
  int row16 = l & 15, grp = l >> 4;
  int bid = blockIdx.x;
  int xcd = bid & 7, local = bid >> 3;       // local 0..95
  int jb = local % 6, mb = xcd * 16 + local / 6;
  int j0 = jb * 128, m0 = mb * 128;
  int wm = w >> 1, wn = w & 1;

  GEMM_STAGE(0, 0, xhi, xlo, wthi, wtlo, Xs, Ws);
  __syncthreads();

  f32x4 acc[2][4];
#pragma unroll
  for (int i = 0; i < 2; ++i)
#pragma unroll
    for (int c = 0; c < 4; ++c) acc[i][c] = (f32x4){0.f, 0.f, 0.f, 0.f};

  for (int kt = 0; kt < 8; ++kt) {
    int cur = kt & 1;
    if (kt < 7) GEMM_STAGE(cur ^ 1, kt + 1, xhi, xlo, wthi, wtlo, Xs, Ws);
    bf16x8 ah[2], al[2];
#pragma unroll
    for (int rf = 0; rf < 2; ++rf) {
      int off = swz_off(wm * 32 + rf * 16 + row16, grp);
      ah[rf] = ldb8(&Xs[cur][0][off]);
      al[rf] = ldb8(&Xs[cur][1][off]);
    }
#pragma unroll
    for (int c = 0; c < 4; ++c) {
      int off = swz_off(wn * 64 + c * 16 + row16, grp);
      bf16x8 bh = ldb8(&Ws[cur][0][off]);
      bf16x8 bl = ldb8(&Ws[cur][1][off]);
#pragma unroll
      for (int rf = 0; rf < 2; ++rf) {
        acc[rf][c] = __builtin_amdgcn_mfma_f32_16x16x32_bf16(ah[rf], bh, acc[rf][c], 0, 0, 0);
        acc[rf][c] = __builtin_amdgcn_mfma_f32_16x16x32_bf16(al[rf], bh, acc[rf][c], 0, 0, 0);
        acc[rf][c] = __builtin_amdgcn_mfma_f32_16x16x32_bf16(ah[rf], bl, acc[rf][c], 0, 0, 0);
      }
    }
    __syncthreads();
  }

  const float scale = 0.17677669529663687f;  // 32^-0.5
#pragma unroll
  for (int i = 0; i < 2; ++i) {
    int ng = m0 + wm * 32 + i * 16 + grp * 4;
#pragma unroll
    for (int c = 0; c < 4; ++c) {
      int jg = j0 + wn * 64 + c * 16 + row16;
#pragma unroll
      for (int r = 0; r < 4; ++r) {
        int m = ng + r;
        int b = m >> 10, n = m & (NTOK - 1);
        float val = acc[i][c][r];
        unsigned short hi, lo;
        if (jg < CDIM) {
          int h = jg >> 5, d = jg & 31;
          size_t idx = (((size_t)b * HEADS + h) * NTOK + n) * HD + d;
          float s = (val + bq[jg]) * scale * bias[((size_t)b * HEADS + h) * NTOK + n];
          split_bf(s, hi, lo);
          qhi[idx] = hi; qlo[idx] = lo;
        } else {
          int c2 = jg - CDIM;
          float vv = val + bkv[c2];
          if (c2 < CDIM) {
            int h = c2 >> 5, d = c2 & 31;
            size_t idx = (((size_t)b * HEADS + h) * NTOK + n) * HD + d;
            split_bf(vv, hi, lo);
            khi[idx] = hi; klo[idx] = lo;
          } else {
            int c3 = c2 - CDIM;
            int h = c3 >> 5, d = c3 & 31;
            size_t idxT = (((size_t)b * HEADS + h) * HD + d) * NTOK + n;
            split_bf(vv, hi, lo);
            vthi[idxT] = hi; vtlo[idxT] = lo;
          }
        }
      }
    }
  }
}

// ---------------------------------------------------------------------------
// MFMA flash attention, barriered global_load_lds double-buffer (round-6).
// ---------------------------------------------------------------------------
__global__ __launch_bounds__(512, 4) void attn_mfma(
    const unsigned short* __restrict__ qhi, const unsigned short* __restrict__ qlo,
    const unsigned short* __restrict__ khi_g, const unsigned short* __restrict__ klo_g,
    const unsigned short* __restrict__ vthi_g, const unsigned short* __restrict__ vtlo_g,
    const float* __restrict__ mask, unsigned short* __restrict__ aohi,
    unsigned short* __restrict__ aolo) {
  __shared__ __align__(16) unsigned short KT[2][2][64 * 32];  // [buf][hi/lo]
  __shared__ __align__(16) unsigned short VT[2][2][32 * 64];  // [buf][hi/lo]
  __shared__ __align__(16) float Pw[8][16][68];               // per-wave P

  int tid = threadIdx.x;
  int w = tid >> 6;        // wave 0..7
  int l = tid & 63;
  int row16 = l & 15;
  int grp = l >> 4;
  int bid = blockIdx.x;
  int swz = (bid & 7) * 128 + (bid >> 3);
  int qt = swz & 7, h = (swz >> 3) & 7, b = swz >> 6;
  int q0 = qt * 128;
  int bh = b * HEADS + h;

  size_t qidx = (((size_t)bh * NTOK) + q0 + w * 16 + row16) * HD + grp * 8;
  bf16x8 aqh = ldb8(qhi + qidx);
  bf16x8 aql = ldb8(qlo + qidx);

  const float* maskb = mask + (size_t)(b & 3) * NTOK * NTOK +
                       (size_t)(q0 + w * 16 + grp * 4) * NTOK + row16;

  f32x4 accd[2];
  accd[0] = (f32x4){0.f, 0.f, 0.f, 0.f};
  accd[1] = (f32x4){0.f, 0.f, 0.f, 0.f};
  float lsum[4] = {0.f, 0.f, 0.f, 0.f};
  const f32x4 zero4 = (f32x4){0.f, 0.f, 0.f, 0.f};

  auto stage = [&](int nbuf, int kt2) {
    int k0n = kt2 * 64;
#pragma unroll
    for (int ci = 0; ci < 2; ++ci) {
      int c = w * 2 + ci;
      int comp = c >> 2;  // 0=Khi 1=Klo 2=Vhi 3=Vlo
      int sub = c & 3;
      if (comp < 2) {
        int kl = sub * 16 + (l >> 2);
        int cb = (l & 3) * 16;
        int gd = (cb ^ ((kl & 3) << 4)) >> 1;
        const unsigned short* src =
            (comp ? klo_g : khi_g) + (((size_t)bh * NTOK) + k0n + kl) * HD + gd;
        gl_lds16(src, &KT[nbuf][comp][sub * 16 * 32]);
      } else {
        int dl = sub * 8 + (l >> 3);
        int cb = (l & 7) * 16;
        int gk = (cb ^ ((dl & 7) << 4)) >> 1;
        const unsigned short* src = (comp == 3 ? vtlo_g : vthi_g) +
                                    ((size_t)bh * HD + dl) * NTOK + k0n + gk;
        gl_lds16(src, &VT[nbuf][comp - 2][sub * 8 * 64]);
      }
    }
  };

  stage(0, 0);
  __syncthreads();

  for (int kt = 0; kt < 16; ++kt) {
    int cur = kt & 1;
    int k0 = kt * 64;
    if (kt < 15) stage(cur ^ 1, kt + 1);

    float mreg[4][4];
#pragma unroll
    for (int f = 0; f < 4; ++f)
#pragma unroll
      for (int r = 0; r < 4; ++r)
        mreg[f][r] = maskb[(size_t)r * NTOK + k0 + f * 16];

    f32x4 s[4];
#pragma unroll
    for (int f = 0; f < 4; ++f) {
      int kl = f * 16 + row16;
      int cb = (grp * 16) ^ ((kl & 3) << 4);
      const unsigned short* kp0 = &KT[cur][0][kl * 32 + (cb >> 1)];
      const unsigned short* kp1 = &KT[cur][1][kl * 32 + (cb >> 1)];
      bf16x8 kh = ldb8(kp0);
      bf16x8 kl2 = ldb8(kp1);
      f32x4 t = __builtin_amdgcn_mfma_f32_16x16x32_bf16(aqh, kh, zero4, 0, 0, 0);
      t = __builtin_amdgcn_mfma_f32_16x16x32_bf16(aql, kh, t, 0, 0, 0);
      t = __builtin_amdgcn_mfma_f32_16x16x32_bf16(aqh, kl2, t, 0, 0, 0);
      s[f] = t;
    }
#pragma unroll
    for (int f = 0; f < 4; ++f) {
#pragma unroll
      for (int r = 0; r < 4; ++r) {
        float p = __expf(s[f][r] + mreg[f][r]);
        lsum[r] += p;
        Pw[w][grp * 4 + r][f * 16 + row16] = p;
      }
    }
#pragma unroll
    for (int ks = 0; ks < 2; ++ks) {
      const float* prow = &Pw[w][row16][ks * 32 + grp * 8];
      float4 pa = *reinterpret_cast<const float4*>(prow);
      float4 pb = *reinterpret_cast<const float4*>(prow + 4);
      float pv[8] = {pa.x, pa.y, pa.z, pa.w, pb.x, pb.y, pb.z, pb.w};
      u16x8 hu, lu;
#pragma unroll
      for (int j = 0; j < 8; ++j) {
        unsigned short hh, ll;
        split_bf(pv[j], hh, ll);
        hu[j] = hh; lu[j] = ll;
      }
      bf16x8 phi = __builtin_bit_cast(bf16x8, hu);
      bf16x8 plo = __builtin_bit_cast(bf16x8, lu);
#pragma unroll
      for (int df = 0; df < 2; ++df) {
        int dl = df * 16 + row16;
        int cb = (ks * 64 + grp * 16) ^ ((dl & 7) << 4);
        const unsigned short* vp0 = &VT[cur][0][dl * 64 + (cb >> 1)];
        const unsigned short* vp1 = &VT[cur][1][dl * 64 + (cb >> 1)];
        bf16x8 vh = ldb8(vp0);
        bf16x8 vl = ldb8(vp1);
        accd[df] = __builtin_amdgcn_mfma_f32_16x16x32_bf16(phi, vh, accd[df], 0, 0, 0);
        accd[df] = __builtin_amdgcn_mfma_f32_16x16x32_bf16(plo, vh, accd[df], 0, 0, 0);
        accd[df] = __builtin_amdgcn_mfma_f32_16x16x32_bf16(phi, vl, accd[df], 0, 0, 0);
      }
    }
    __syncthreads();
  }

#pragma unroll
  for (int r = 0; r < 4; ++r) {
#pragma unroll
    for (int off = 1; off < 16; off <<= 1)
      lsum[r] += __shfl_xor(lsum[r], off, 16);
  }
#pragma unroll
  for (int r = 0; r < 4; ++r) {
    float inv = 1.f / lsum[r];
    int qrow = q0 + w * 16 + grp * 4 + r;
    size_t obase = ((size_t)b * NTOK + qrow) * CDIM + h * HD;
    float v0 = accd[0][r] * inv, v1 = accd[1][r] * inv;
    unsigned short h0, l0, h1, l1;
    split_bf(v0, h0, l0);
    split_bf(v1, h1, l1);
    aohi[obase + row16] = h0; aolo[obase + row16] = l0;
    aohi[obase + 16 + row16] = h1; aolo[obase + 16 + row16] = l1;
  }
}

// ---------------------------------------------------------------------------
// Output projection, same 128x128/BK=32 dbuf structure. Grid 256 =
// 8 XCD x (2 j x 16 m).
// ---------------------------------------------------------------------------
__global__ __launch_bounds__(512, 4) void gemm_out_mfma(
    const unsigned short* __restrict__ ahi, const unsigned short* __restrict__ alo,
    const unsigned short* __restrict__ wpthi, const unsigned short* __restrict__ wptlo,
    const float* __restrict__ bp, float* __restrict__ out) {
  __shared__ __align__(16) unsigned short Xs[2][2][4096];
  __shared__ __align__(16) unsigned short Ws[2][2][4096];
  int tid = threadIdx.x;
  int w = tid >> 6, l = tid & 63;
  int row16 = l & 15, grp = l >> 4;
  int bid = blockIdx.x;
  int xcd = bid & 7, local = bid >> 3;       // local 0..31
  int jb = local & 1, mb = xcd * 16 + (local >> 1);
  int j0 = jb * 128, m0 = mb * 128;
  int wm = w >> 1, wn = w & 1;

  GEMM_STAGE(0, 0, ahi, alo, wpthi, wptlo, Xs, Ws);
  __syncthreads();

  f32x4 acc[2][4];
#pragma unroll
  for (int i = 0; i < 2; ++i)
#pragma unroll
    for (int c = 0; c < 4; ++c) acc[i][c] = (f32x4){0.f, 0.f, 0.f, 0.f};

  for (int kt = 0; kt < 8; ++kt) {
    int cur = kt & 1;
    if (kt < 7) GEMM_STAGE(cur ^ 1, kt + 1, ahi, alo, wpthi, wptlo, Xs, Ws);
    bf16x8 ah[2], al[2];
#pragma unroll
    for (int rf = 0; rf < 2; ++rf) {
      int off = swz_off(wm * 32 + rf * 16 + row16, grp);
      ah[rf] = ldb8(&Xs[cur][0][off]);
      al[rf] = ldb8(&Xs[cur][1][off]);
    }
#pragma unroll
    for (int c = 0; c < 4; ++c) {
      int off = swz_off(wn * 64 + c * 16 + row16, grp);
      bf16x8 bh = ldb8(&Ws[cur][0][off]);
      bf16x8 bl = ldb8(&Ws[cur][1][off]);
#pragma unroll
      for (int rf = 0; rf < 2; ++rf) {
        acc[rf][c] = __builtin_amdgcn_mfma_f32_16x16x32_bf16(ah[rf], bh, acc[rf][c], 0, 0, 0);
        acc[rf][c] = __builtin_amdgcn_mfma_f32_16x16x32_bf16(al[rf], bh, acc[rf][c], 0, 0, 0);
        acc[rf][c] = __builtin_amdgcn_mfma_f32_16x16x32_bf16(ah[rf], bl, acc[rf][c], 0, 0, 0);
      }
    }
    __syncthreads();
  }

#pragma unroll
  for (int i = 0; i < 2; ++i) {
    int ng = m0 + wm * 32 + i * 16 + grp * 4;
#pragma unroll
    for (int c = 0; c < 4; ++c) {
      int jg = j0 + wn * 64 + c * 16 + row16;
      float bias = bp[jg];
#pragma unroll
      for (int r = 0; r < 4; ++r) {
        out[(size_t)(ng + r) * CDIM + jg] = acc[i][c][r] + bias;
      }
    }
  }
}

// ---------------------------------------------------------------------------
extern "C" void kernel_launch(void* const* d_in, const int* in_sizes, int n_in,
                              void* d_out, int out_size, void* d_ws,
                              size_t ws_size, hipStream_t stream) {
  const float* x = (const float*)d_in[0];
  const float* mask = (const float*)d_in[1];
  const float* affine = (const float*)d_in[2];
  const float* Wq = (const float*)d_in[3];
  const float* bq = (const float*)d_in[4];
  const float* Wkv = (const float*)d_in[5];
  const float* bkv = (const float*)d_in[6];
  const float* Wp = (const float*)d_in[7];
  const float* bp = (const float*)d_in[8];
  const float* atab = (const float*)d_in[9];
  float* out = (float*)d_out;

  const size_t bhnd = (size_t)BB * HEADS * NTOK * HD;  // 4,194,304
  unsigned short* qhi = (unsigned short*)d_ws;
  unsigned short* qlo = qhi + bhnd;
  unsigned short* khi = qlo + bhnd;
  unsigned short* klo = khi + bhnd;
  unsigned short* vthi = klo + bhnd;
  unsigned short* vtlo = vthi + bhnd;
  unsigned short* xhi = vtlo + bhnd;   // aliased as aout_hi after qkv
  unsigned short* xlo = xhi + bhnd;    // aliased as aout_lo after qkv
  unsigned short* wthi = xlo + bhnd;             // 768*256
  unsigned short* wtlo = wthi + 768 * 256;
  unsigned short* wpthi = wtlo + 768 * 256;      // 256*256
  unsigned short* wptlo = wpthi + 256 * 256;
  float* bias = (float*)(wptlo + 256 * 256);

  split_x<<<2048, 256, 0, stream>>>(x, xhi, xlo);
  split_w<<<1024, 256, 0, stream>>>(Wq, Wkv, Wp, wthi, wtlo, wpthi, wptlo);
  bias_kernel<<<64, 256, 0, stream>>>(affine, atab, bias);
  gemm_qkv_mfma<<<768, 512, 0, stream>>>(
      xhi, xlo, wthi, wtlo, bq, bkv, bias, qhi, qlo, khi, klo, vthi, vtlo);
  attn_mfma<<<1024, 512, 0, stream>>>(qhi, qlo, khi, klo, vthi, vtlo, mask,
                                      xhi, xlo);
  gemm_out_mfma<<<256, 512, 0, stream>>>(xhi, xlo, wpthi, wptlo, bp, out);
}

// Round 9
// 163.924 us; speedup vs baseline: 2.6088x; 1.0254x over previous
//
#include <hip/hip_runtime.h>
#include <hip/hip_bf16.h>
#include <math.h>

#define BB 16
#define NTOK 1024
#define CDIM 256
#define HEADS 8
#define HD 32
#define LOG2E 1.4426950408889634f

typedef __attribute__((ext_vector_type(8))) __bf16 bf16x8;
typedef __attribute__((ext_vector_type(8))) unsigned short u16x8;
typedef __attribute__((ext_vector_type(4))) unsigned int u32x4;
typedef __attribute__((ext_vector_type(4))) float f32x4;

// Split fp32 into bf16 hi (truncation) + bf16 lo (truncation of residual).
__device__ __forceinline__ void split_bf(float f, unsigned short& hi,
                                         unsigned short& lo) {
  unsigned u = __float_as_uint(f);
  hi = (unsigned short)(u >> 16);
  float fl = f - __uint_as_float(u & 0xFFFF0000u);
  lo = (unsigned short)(__float_as_uint(fl) >> 16);
}

__device__ __forceinline__ bf16x8 ldb8(const unsigned short* p) {
  return *reinterpret_cast<const bf16x8*>(p);
}

// async global->LDS 16B DMA: per-lane global src, wave-uniform LDS base
// (HW adds lane*16 to the dest).
__device__ __forceinline__ void gl_lds16(const unsigned short* g,
                                         unsigned short* l) {
  __builtin_amdgcn_global_load_lds(
      (const __attribute__((address_space(1))) unsigned int*)g,
      (__attribute__((address_space(3))) unsigned int*)l, 16, 0, 0);
}

// ---------------------------------------------------------------------------
// Split X (16384x256 fp32) into bf16 hi/lo, 8 elems/thread.
// ---------------------------------------------------------------------------
__global__ __launch_bounds__(256) void split_x(const float* __restrict__ X,
                                               unsigned short* __restrict__ xhi,
                                               unsigned short* __restrict__ xlo) {
  size_t base = ((size_t)blockIdx.x * 256 + threadIdx.x) * 8;
  float4 a = *(const float4*)(X + base);
  float4 b = *(const float4*)(X + base + 4);
  float v[8] = {a.x, a.y, a.z, a.w, b.x, b.y, b.z, b.w};
  u16x8 h, l;
#pragma unroll
  for (int j = 0; j < 8; ++j) {
    unsigned short hh, ll;
    split_bf(v[j], hh, ll);
    h[j] = hh; l[j] = ll;
  }
  *(u16x8*)(xhi + base) = h;
  *(u16x8*)(xlo + base) = l;
}

// ---------------------------------------------------------------------------
// Split + transpose weights into (N,K) hi/lo.
// ---------------------------------------------------------------------------
__global__ __launch_bounds__(256) void split_w(
    const float* __restrict__ Wq, const float* __restrict__ Wkv,
    const float* __restrict__ Wp, unsigned short* __restrict__ wthi,
    unsigned short* __restrict__ wtlo, unsigned short* __restrict__ wpthi,
    unsigned short* __restrict__ wptlo) {
  int idx = blockIdx.x * 256 + threadIdx.x;  // 0 .. 262143
  float val; size_t dst; bool isp = false;
  if (idx < 65536) {               // Wq: (k,n)
    int k = idx >> 8, n = idx & 255;
    val = Wq[idx]; dst = (size_t)n * 256 + k;
  } else if (idx < 196608) {       // Wkv: (k,n2) -> cols 256..767
    int i2 = idx - 65536;
    int k = i2 >> 9, n2 = i2 & 511;
    val = Wkv[i2]; dst = (size_t)(256 + n2) * 256 + k;
  } else {                         // Wp
    int i3 = idx - 196608;
    int k = i3 >> 8, n = i3 & 255;
    val = Wp[i3]; dst = (size_t)n * 256 + k; isp = true;
  }
  unsigned short h, l;
  split_bf(val, h, l);
  if (isp) { wpthi[dst] = h; wptlo[dst] = l; }
  else     { wthi[dst] = h; wtlo[dst] = l; }
}

// ---------------------------------------------------------------------------
// Per-query angle bias
// ---------------------------------------------------------------------------
__global__ __launch_bounds__(256) void bias_kernel(
    const float* __restrict__ affine, const float* __restrict__ atab,
    float* __restrict__ bias) {
  int idx = blockIdx.x * 256 + threadIdx.x;
  if (idx >= BB * NTOK) return;
  int b = idx >> 10, n = idx & (NTOK - 1);
  float cx = (float)(n & 31);
  float cy = (float)(n >> 5);
  const float* A = affine + b * 6;
  float egx = fmaf(A[0], 16.f, fmaf(A[1], 16.f, A[2]));
  float egy = fmaf(A[3], 16.f, fmaf(A[4], 16.f, A[5]));
  float ang = atan2f(cy - egy, cx - egx);
  float t = (ang + 3.14159265358979323846f) *
            (1.f / (2.f * 3.14159265358979323846f)) * 4.f;
  int bin = (int)t;
  bin = bin < 0 ? 0 : (bin > 4 ? 4 : bin);
  for (int h = 0; h < HEADS; ++h) {
    float a = atab[bin * HEADS + h];
    float s = 1.f / (1.f + __expf(-a));
    bias[((size_t)b * HEADS + h) * NTOK + n] = 1.f + s;
  }
}

// ---------------------------------------------------------------------------
// mask2 = mask * log2(e)  (for exp2-domain softmax)
// ---------------------------------------------------------------------------
__global__ __launch_bounds__(256) void mask_prep(const float* __restrict__ m,
                                                 float* __restrict__ m2) {
  size_t i = ((size_t)blockIdx.x * 256 + threadIdx.x) * 4;
  float4 v = *(const float4*)(m + i);
  v.x *= LOG2E; v.y *= LOG2E; v.z *= LOG2E; v.w *= LOG2E;
  *(float4*)(m2 + i) = v;
}

// ---------------------------------------------------------------------------
// QKV projection, split-bf16 MFMA, LDS dbuf (128m x 128n, BK=32), with a
// coalescing LDS-bounce epilogue: outputs written as packed (hi|lo) u32 to
// the freed staging LDS in two 64-row halves, then re-read and stored as
// 16B u16x8 runs (V^T transposed through LDS columns).
// Q is premultiplied by scale*bias*LOG2E (exp2-domain attention).
// ---------------------------------------------------------------------------
__global__ __launch_bounds__(512, 4) void gemm_qkv_mfma(
    const unsigned short* __restrict__ xhi, const unsigned short* __restrict__ xlo,
    const unsigned short* __restrict__ wthi, const unsigned short* __restrict__ wtlo,
    const float* __restrict__ bq, const float* __restrict__ bkv,
    const float* __restrict__ bias,
    unsigned short* __restrict__ qhi, unsigned short* __restrict__ qlo,
    unsigned short* __restrict__ khi, unsigned short* __restrict__ klo,
    unsigned short* __restrict__ vthi, unsigned short* __restrict__ vtlo) {
  __shared__ __align__(16) unsigned int SMu[16384];  // 64 KB, multi-purpose
  unsigned short* SMs = (unsigned short*)SMu;
  int tid = threadIdx.x;
  int w = tid >> 6, l = tid & 63;
  int row16 = l & 15, grp = l >> 4;
  int bid = blockIdx.x;
  int xcd = bid & 7, local = bid >> 3;       // local 0..95
  int jb = local % 6, mb = xcd * 16 + local / 6;
  int j0 = jb * 128, m0 = mb * 128;
  int wm = w >> 1, wn = w & 1;

  // staging: superrow swizzle, linear DMA dest (verified R8 scheme)
  auto stg = [&](int nb, int kt) {
    int k0s = kt * 32;
    int sl = (l & 7) ^ (l >> 3);
    int row = w * 16 + 2 * (l >> 3) + (sl >> 2);
    int ke = (sl & 3) * 8;
    gl_lds16(xhi + (size_t)(m0 + row) * 256 + k0s + ke,
             SMs + nb * 8192 + w * 512);
    gl_lds16(xlo + (size_t)(m0 + row) * 256 + k0s + ke,
             SMs + nb * 8192 + 4096 + w * 512);
    gl_lds16(wthi + (size_t)(j0 + row) * 256 + k0s + ke,
             SMs + 16384 + nb * 8192 + w * 512);
    gl_lds16(wtlo + (size_t)(j0 + row) * 256 + k0s + ke,
             SMs + 16384 + nb * 8192 + 4096 + w * 512);
  };
  // swizzled LDS read offset (u16 elems) for logical (row, grp)
  auto swz_off = [&](int row, int g) {
    int R = row >> 1;
    int phys = (((row & 1) << 2) | g) ^ (R & 7);
    return R * 64 + phys * 8;
  };

  stg(0, 0);
  __syncthreads();

  f32x4 acc[2][4];
#pragma unroll
  for (int i = 0; i < 2; ++i)
#pragma unroll
    for (int c = 0; c < 4; ++c) acc[i][c] = (f32x4){0.f, 0.f, 0.f, 0.f};

  for (int kt = 0; kt < 8; ++kt) {
    int cur = kt & 1;
    if (kt < 7) stg(cur ^ 1, kt + 1);
    bf16x8 ah[2], al[2];
#pragma unroll
    for (int rf = 0; rf < 2; ++rf) {
      int off = swz_off(wm * 32 + rf * 16 + row16, grp);
      ah[rf] = ldb8(SMs + cur * 8192 + off);
      al[rf] = ldb8(SMs + cur * 8192 + 4096 + off);
    }
#pragma unroll
    for (int c = 0; c < 4; ++c) {
      int off = swz_off(wn * 64 + c * 16 + row16, grp);
      bf16x8 bh = ldb8(SMs + 16384 + cur * 8192 + off);
      bf16x8 bl = ldb8(SMs + 16384 + cur * 8192 + 4096 + off);
#pragma unroll
      for (int rf = 0; rf < 2; ++rf) {
        acc[rf][c] = __builtin_amdgcn_mfma_f32_16x16x32_bf16(ah[rf], bh, acc[rf][c], 0, 0, 0);
        acc[rf][c] = __builtin_amdgcn_mfma_f32_16x16x32_bf16(al[rf], bh, acc[rf][c], 0, 0, 0);
        acc[rf][c] = __builtin_amdgcn_mfma_f32_16x16x32_bf16(ah[rf], bl, acc[rf][c], 0, 0, 0);
      }
    }
    __syncthreads();
  }

  // ---- coalescing epilogue: two 64-row halves through SMu [64][132] u32
  const float scaleq = 0.17677669529663687f * LOG2E;  // 32^-0.5 * log2e
  int half_mine = wm >> 1;
  for (int half = 0; half < 2; ++half) {
    if (half_mine == half) {  // Phase A: pack + scatter into LDS
#pragma unroll
      for (int i = 0; i < 2; ++i) {
#pragma unroll
        for (int c = 0; c < 4; ++c) {
          int col = wn * 64 + c * 16 + row16;
          int jg = j0 + col;
#pragma unroll
          for (int r = 0; r < 4; ++r) {
            int rowl = (wm & 1) * 32 + i * 16 + grp * 4 + r;  // 0..63
            int m = m0 + half * 64 + rowl;
            int b = m >> 10, n = m & (NTOK - 1);
            float val = acc[i][c][r];
            float f;
            if (jb < 2) {
              int h = jg >> 5;
              f = (val + bq[jg]) * scaleq *
                  bias[((size_t)b * HEADS + h) * NTOK + n];
            } else {
              f = val + bkv[jg - CDIM];
            }
            unsigned short hi, lo;
            split_bf(f, hi, lo);
            SMu[rowl * 132 + col] = ((unsigned)hi << 16) | lo;
          }
        }
      }
    }
    __syncthreads();
    // Phase B: coalesced 16B stores
    if (jb < 4) {
#pragma unroll
      for (int it = 0; it < 2; ++it) {
        int lin = it * 512 + tid;          // 0..1023
        int rowb = lin >> 4, oct = lin & 15;
        const unsigned* pp = &SMu[rowb * 132 + oct * 8];
        u32x4 a0 = *(const u32x4*)pp;
        u32x4 a1 = *(const u32x4*)(pp + 4);
        u16x8 vh, vl;
#pragma unroll
        for (int e = 0; e < 4; ++e) {
          vh[e] = (unsigned short)(a0[e] >> 16);
          vl[e] = (unsigned short)(a0[e] & 0xffff);
          vh[e + 4] = (unsigned short)(a1[e] >> 16);
          vl[e + 4] = (unsigned short)(a1[e] & 0xffff);
        }
        int m = m0 + half * 64 + rowb;
        int b = m >> 10, n = m & (NTOK - 1);
        int jg = j0 + oct * 8;
        unsigned short *dh, *dl;
        int h, d;
        if (jb < 2) { h = jg >> 5; d = jg & 31; dh = qhi; dl = qlo; }
        else { int c2 = jg - CDIM; h = c2 >> 5; d = c2 & 31; dh = khi; dl = klo; }
        size_t idx = (((size_t)b * HEADS + h) * NTOK + n) * HD + d;
        *(u16x8*)(dh + idx) = vh;
        *(u16x8*)(dl + idx) = vl;
      }
    } else {  // V^T: read LDS columns (lane-per-jl, conflict-free)
#pragma unroll
      for (int it = 0; it < 2; ++it) {
        int lin = it * 512 + tid;
        int noct = lin >> 7, jl = lin & 127;  // noct 0..7
        unsigned pv[8];
#pragma unroll
        for (int e = 0; e < 8; ++e) pv[e] = SMu[(noct * 8 + e) * 132 + jl];
        u16x8 vh, vl;
#pragma unroll
        for (int e = 0; e < 8; ++e) {
          vh[e] = (unsigned short)(pv[e] >> 16);
          vl[e] = (unsigned short)(pv[e] & 0xffff);
        }
        int c3 = j0 + jl - 2 * CDIM;
        int h = c3 >> 5, d = c3 & 31;
        int n0 = m0 + half * 64 + noct * 8;
        int b = n0 >> 10, nn = n0 & (NTOK - 1);
        size_t idx = (((size_t)b * HEADS + h) * HD + d) * NTOK + nn;
        *(u16x8*)(vthi + idx) = vh;
        *(u16x8*)(vtlo + idx) = vl;
      }
    }
    __syncthreads();
  }
}

// ---------------------------------------------------------------------------
// MFMA flash attention, barriered global_load_lds double-buffer.
// exp2-domain softmax (Q carries log2e; mask2 pre-scaled). P staged as
// packed (hi|lo) u32 in wave-private LDS stripe.
// ---------------------------------------------------------------------------
__global__ __launch_bounds__(512, 4) void attn_mfma(
    const unsigned short* __restrict__ qhi, const unsigned short* __restrict__ qlo,
    const unsigned short* __restrict__ khi_g, const unsigned short* __restrict__ klo_g,
    const unsigned short* __restrict__ vthi_g, const unsigned short* __restrict__ vtlo_g,
    const float* __restrict__ mask2, unsigned short* __restrict__ aohi,
    unsigned short* __restrict__ aolo) {
  __shared__ __align__(16) unsigned short KT[2][2][64 * 32];  // [buf][hi/lo]
  __shared__ __align__(16) unsigned short VT[2][2][32 * 64];  // [buf][hi/lo]
  __shared__ __align__(16) unsigned int Pw[8][16][68];        // packed hi|lo

  int tid = threadIdx.x;
  int w = tid >> 6;        // wave 0..7
  int l = tid & 63;
  int row16 = l & 15;
  int grp = l >> 4;
  int bid = blockIdx.x;
  int swz = (bid & 7) * 128 + (bid >> 3);
  int qt = swz & 7, h = (swz >> 3) & 7, b = swz >> 6;
  int q0 = qt * 128;
  int bh = b * HEADS + h;

  size_t qidx = (((size_t)bh * NTOK) + q0 + w * 16 + row16) * HD + grp * 8;
  bf16x8 aqh = ldb8(qhi + qidx);
  bf16x8 aql = ldb8(qlo + qidx);

  const float* maskb = mask2 + (size_t)(b & 3) * NTOK * NTOK +
                       (size_t)(q0 + w * 16 + grp * 4) * NTOK + row16;

  f32x4 accd[2];
  accd[0] = (f32x4){0.f, 0.f, 0.f, 0.f};
  accd[1] = (f32x4){0.f, 0.f, 0.f, 0.f};
  float lsum[4] = {0.f, 0.f, 0.f, 0.f};
  const f32x4 zero4 = (f32x4){0.f, 0.f, 0.f, 0.f};

  auto stage = [&](int nbuf, int kt2) {
    int k0n = kt2 * 64;
#pragma unroll
    for (int ci = 0; ci < 2; ++ci) {
      int c = w * 2 + ci;
      int comp = c >> 2;  // 0=Khi 1=Klo 2=Vhi 3=Vlo
      int sub = c & 3;
      if (comp < 2) {
        int kl = sub * 16 + (l >> 2);
        int cb = (l & 3) * 16;
        int gd = (cb ^ ((kl & 3) << 4)) >> 1;
        const unsigned short* src =
            (comp ? klo_g : khi_g) + (((size_t)bh * NTOK) + k0n + kl) * HD + gd;
        gl_lds16(src, &KT[nbuf][comp][sub * 16 * 32]);
      } else {
        int dl = sub * 8 + (l >> 3);
        int cb = (l & 7) * 16;
        int gk = (cb ^ ((dl & 7) << 4)) >> 1;
        const unsigned short* src = (comp == 3 ? vtlo_g : vthi_g) +
                                    ((size_t)bh * HD + dl) * NTOK + k0n + gk;
        gl_lds16(src, &VT[nbuf][comp - 2][sub * 8 * 64]);
      }
    }
  };

  stage(0, 0);
  __syncthreads();

  for (int kt = 0; kt < 16; ++kt) {
    int cur = kt & 1;
    int k0 = kt * 64;
    if (kt < 15) stage(cur ^ 1, kt + 1);

    float mreg[4][4];
#pragma unroll
    for (int f = 0; f < 4; ++f)
#pragma unroll
      for (int r = 0; r < 4; ++r)
        mreg[f][r] = maskb[(size_t)r * NTOK + k0 + f * 16];

    f32x4 s[4];
#pragma unroll
    for (int f = 0; f < 4; ++f) {
      int kl = f * 16 + row16;
      int cb = (grp * 16) ^ ((kl & 3) << 4);
      const unsigned short* kp0 = &KT[cur][0][kl * 32 + (cb >> 1)];
      const unsigned short* kp1 = &KT[cur][1][kl * 32 + (cb >> 1)];
      bf16x8 kh = ldb8(kp0);
      bf16x8 kl2 = ldb8(kp1);
      f32x4 t = __builtin_amdgcn_mfma_f32_16x16x32_bf16(aqh, kh, zero4, 0, 0, 0);
      t = __builtin_amdgcn_mfma_f32_16x16x32_bf16(aql, kh, t, 0, 0, 0);
      t = __builtin_amdgcn_mfma_f32_16x16x32_bf16(aqh, kl2, t, 0, 0, 0);
      s[f] = t;
    }
#pragma unroll
    for (int f = 0; f < 4; ++f) {
#pragma unroll
      for (int r = 0; r < 4; ++r) {
        float p = __builtin_amdgcn_exp2f(s[f][r] + mreg[f][r]);
        lsum[r] += p;
        unsigned short ph_, pl_;
        split_bf(p, ph_, pl_);
        Pw[w][grp * 4 + r][f * 16 + row16] = ((unsigned)ph_ << 16) | pl_;
      }
    }
#pragma unroll
    for (int ks = 0; ks < 2; ++ks) {
      const unsigned* prow = &Pw[w][row16][ks * 32 + grp * 8];
      u32x4 a0 = *(const u32x4*)prow;
      u32x4 a1 = *(const u32x4*)(prow + 4);
      u16x8 hu, lu;
#pragma unroll
      for (int e = 0; e < 4; ++e) {
        hu[e] = (unsigned short)(a0[e] >> 16);
        lu[e] = (unsigned short)(a0[e] & 0xffff);
        hu[e + 4] = (unsigned short)(a1[e] >> 16);
        lu[e + 4] = (unsigned short)(a1[e] & 0xffff);
      }
      bf16x8 phi = __builtin_bit_cast(bf16x8, hu);
      bf16x8 plo = __builtin_bit_cast(bf16x8, lu);
#pragma unroll
      for (int df = 0; df < 2; ++df) {
        int dl = df * 16 + row16;
        int cb = (ks * 64 + grp * 16) ^ ((dl & 7) << 4);
        const unsigned short* vp0 = &VT[cur][0][dl * 64 + (cb >> 1)];
        const unsigned short* vp1 = &VT[cur][1][dl * 64 + (cb >> 1)];
        bf16x8 vh = ldb8(vp0);
        bf16x8 vl = ldb8(vp1);
        accd[df] = __builtin_amdgcn_mfma_f32_16x16x32_bf16(phi, vh, accd[df], 0, 0, 0);
        accd[df] = __builtin_amdgcn_mfma_f32_16x16x32_bf16(plo, vh, accd[df], 0, 0, 0);
        accd[df] = __builtin_amdgcn_mfma_f32_16x16x32_bf16(phi, vl, accd[df], 0, 0, 0);
      }
    }
    __syncthreads();
  }

#pragma unroll
  for (int r = 0; r < 4; ++r) {
#pragma unroll
    for (int off = 1; off < 16; off <<= 1)
      lsum[r] += __shfl_xor(lsum[r], off, 16);
  }
#pragma unroll
  for (int r = 0; r < 4; ++r) {
    float inv = 1.f / lsum[r];
    int qrow = q0 + w * 16 + grp * 4 + r;
    size_t obase = ((size_t)b * NTOK + qrow) * CDIM + h * HD;
    float v0 = accd[0][r] * inv, v1 = accd[1][r] * inv;
    unsigned short h0, l0, h1, l1;
    split_bf(v0, h0, l0);
    split_bf(v1, h1, l1);
    aohi[obase + row16] = h0; aolo[obase + row16] = l0;
    aohi[obase + 16 + row16] = h1; aolo[obase + 16 + row16] = l1;
  }
}

// ---------------------------------------------------------------------------
// Output projection, 128x128/BK=32 dbuf structure (unchanged from R8).
// ---------------------------------------------------------------------------
__global__ __launch_bounds__(512, 4) void gemm_out_mfma(
    const unsigned short* __restrict__ ahi, const unsigned short* __restrict__ alo,
    const unsigned short* __restrict__ wpthi, const unsigned short* __restrict__ wptlo,
    const float* __restrict__ bp, float* __restrict__ out) {
  __shared__ __align__(16) unsigned short Xs[2][2][4096];
  __shared__ __align__(16) unsigned short Ws[2][2][4096];
  int tid = threadIdx.x;
  int w = tid >> 6, l = tid & 63;
  int row16 = l & 15, grp = l >> 4;
  int bid = blockIdx.x;
  int xcd = bid & 7, local = bid >> 3;       // local 0..31
  int jb = local & 1, mb = xcd * 16 + (local >> 1);
  int j0 = jb * 128, m0 = mb * 128;
  int wm = w >> 1, wn = w & 1;

  auto stg = [&](int nb, int kt) {
    int k0s = kt * 32;
    int sl = (l & 7) ^ (l >> 3);
    int row = w * 16 + 2 * (l >> 3) + (sl >> 2);
    int ke = (sl & 3) * 8;
    gl_lds16(ahi + (size_t)(m0 + row) * 256 + k0s + ke, &Xs[nb][0][w * 512]);
    gl_lds16(alo + (size_t)(m0 + row) * 256 + k0s + ke, &Xs[nb][1][w * 512]);
    gl_lds16(wpthi + (size_t)(j0 + row) * 256 + k0s + ke, &Ws[nb][0][w * 512]);
    gl_lds16(wptlo + (size_t)(j0 + row) * 256 + k0s + ke, &Ws[nb][1][w * 512]);
  };
  auto swz_off = [&](int row, int g) {
    int R = row >> 1;
    int phys = (((row & 1) << 2) | g) ^ (R & 7);
    return R * 64 + phys * 8;
  };

  stg(0, 0);
  __syncthreads();

  f32x4 acc[2][4];
#pragma unroll
  for (int i = 0; i < 2; ++i)
#pragma unroll
    for (int c = 0; c < 4; ++c) acc[i][c] = (f32x4){0.f, 0.f, 0.f, 0.f};

  for (int kt = 0; kt < 8; ++kt) {
    int cur = kt & 1;
    if (kt < 7) stg(cur ^ 1, kt + 1);
    bf16x8 ah[2], al[2];
#pragma unroll
    for (int rf = 0; rf < 2; ++rf) {
      int off = swz_off(wm * 32 + rf * 16 + row16, grp);
      ah[rf] = ldb8(&Xs[cur][0][off]);
      al[rf] = ldb8(&Xs[cur][1][off]);
    }
#pragma unroll
    for (int c = 0; c < 4; ++c) {
      int off = swz_off(wn * 64 + c * 16 + row16, grp);
      bf16x8 bh = ldb8(&Ws[cur][0][off]);
      bf16x8 bl = ldb8(&Ws[cur][1][off]);
#pragma unroll
      for (int rf = 0; rf < 2; ++rf) {
        acc[rf][c] = __builtin_amdgcn_mfma_f32_16x16x32_bf16(ah[rf], bh, acc[rf][c], 0, 0, 0);
        acc[rf][c] = __builtin_amdgcn_mfma_f32_16x16x32_bf16(al[rf], bh, acc[rf][c], 0, 0, 0);
        acc[rf][c] = __builtin_amdgcn_mfma_f32_16x16x32_bf16(ah[rf], bl, acc[rf][c], 0, 0, 0);
      }
    }
    __syncthreads();
  }

#pragma unroll
  for (int i = 0; i < 2; ++i) {
    int ng = m0 + wm * 32 + i * 16 + grp * 4;
#pragma unroll
    for (int c = 0; c < 4; ++c) {
      int jg = j0 + wn * 64 + c * 16 + row16;
      float bias = bp[jg];
#pragma unroll
      for (int r = 0; r < 4; ++r) {
        out[(size_t)(ng + r) * CDIM + jg] = acc[i][c][r] + bias;
      }
    }
  }
}

// ---------------------------------------------------------------------------
extern "C" void kernel_launch(void* const* d_in, const int* in_sizes, int n_in,
                              void* d_out, int out_size, void* d_ws,
                              size_t ws_size, hipStream_t stream) {
  const float* x = (const float*)d_in[0];
  const float* mask = (const float*)d_in[1];
  const float* affine = (const float*)d_in[2];
  const float* Wq = (const float*)d_in[3];
  const float* bq = (const float*)d_in[4];
  const float* Wkv = (const float*)d_in[5];
  const float* bkv = (const float*)d_in[6];
  const float* Wp = (const float*)d_in[7];
  const float* bp = (const float*)d_in[8];
  const float* atab = (const float*)d_in[9];
  float* out = (float*)d_out;

  const size_t bhnd = (size_t)BB * HEADS * NTOK * HD;  // 4,194,304
  unsigned short* qhi = (unsigned short*)d_ws;
  unsigned short* qlo = qhi + bhnd;
  unsigned short* khi = qlo + bhnd;
  unsigned short* klo = khi + bhnd;
  unsigned short* vthi = klo + bhnd;
  unsigned short* vtlo = vthi + bhnd;
  unsigned short* xhi = vtlo + bhnd;   // aliased as aout_hi after qkv
  unsigned short* xlo = xhi + bhnd;    // aliased as aout_lo after qkv
  unsigned short* wthi = xlo + bhnd;             // 768*256
  unsigned short* wtlo = wthi + 768 * 256;
  unsigned short* wpthi = wtlo + 768 * 256;      // 256*256
  unsigned short* wptlo = wpthi + 256 * 256;
  float* bias = (float*)(wptlo + 256 * 256);
  float* mask2 = bias + (size_t)BB * HEADS * NTOK;  // 4M floats

  split_x<<<2048, 256, 0, stream>>>(x, xhi, xlo);
  split_w<<<1024, 256, 0, stream>>>(Wq, Wkv, Wp, wthi, wtlo, wpthi, wptlo);
  bias_kernel<<<64, 256, 0, stream>>>(affine, atab, bias);
  mask_prep<<<4096, 256, 0, stream>>>(mask, mask2);
  gemm_qkv_mfma<<<768, 512, 0, stream>>>(
      xhi, xlo, wthi, wtlo, bq, bkv, bias, qhi, qlo, khi, klo, vthi, vtlo);
  attn_mfma<<<1024, 512, 0, stream>>>(qhi, qlo, khi, klo, vthi, vtlo, mask2,
                                      xhi, xlo);
  gemm_out_mfma<<<256, 512, 0, stream>>>(xhi, xlo, wpthi, wptlo, bp, out);
}

// Round 10
// 117.474 us; speedup vs baseline: 3.6404x; 1.3954x over previous
//
#include <hip/hip_runtime.h>
#include <hip/hip_bf16.h>
#include <math.h>

#define BB 16
#define NTOK 1024
#define CDIM 256
#define HEADS 8
#define HD 32
#define LOG2E 1.4426950408889634f

typedef __attribute__((ext_vector_type(8))) _Float16 half8;
typedef __attribute__((ext_vector_type(8))) __bf16 bf16x8;
typedef __attribute__((ext_vector_type(8))) unsigned short u16x8;
typedef __attribute__((ext_vector_type(4))) unsigned int u32x4;
typedef __attribute__((ext_vector_type(2))) unsigned int u32x2;
typedef __attribute__((ext_vector_type(4))) float f32x4;

__device__ __forceinline__ unsigned short f2h(float f) {
  _Float16 h = (_Float16)f;
  return __builtin_bit_cast(unsigned short, h);
}
__device__ __forceinline__ unsigned short f2b_rne(float f) {
  unsigned u = __float_as_uint(f);
  return (unsigned short)((u + 0x7FFF + ((u >> 16) & 1)) >> 16);
}
// truncation split: f = hi + lo to ~2^-17 rel (for P only)
__device__ __forceinline__ void split_bf(float f, unsigned short& hi,
                                         unsigned short& lo) {
  unsigned u = __float_as_uint(f);
  hi = (unsigned short)(u >> 16);
  float fl = f - __uint_as_float(u & 0xFFFF0000u);
  lo = (unsigned short)(__float_as_uint(fl) >> 16);
}
__device__ __forceinline__ half8 ldh8(const unsigned short* p) {
  return *reinterpret_cast<const half8*>(p);
}
__device__ __forceinline__ bf16x8 ldb8(const unsigned short* p) {
  return *reinterpret_cast<const bf16x8*>(p);
}
__device__ __forceinline__ void gl_lds16(const unsigned short* g,
                                         unsigned short* l) {
  __builtin_amdgcn_global_load_lds(
      (const __attribute__((address_space(1))) unsigned int*)g,
      (__attribute__((address_space(3))) unsigned int*)l, 16, 0, 0);
}

// ---------------------------------------------------------------------------
__global__ __launch_bounds__(256) void cvt_x(const float* __restrict__ X,
                                             unsigned short* __restrict__ x16) {
  size_t base = ((size_t)blockIdx.x * 256 + threadIdx.x) * 8;
  float4 a = *(const float4*)(X + base);
  float4 b = *(const float4*)(X + base + 4);
  u16x8 o = {f2h(a.x), f2h(a.y), f2h(a.z), f2h(a.w),
             f2h(b.x), f2h(b.y), f2h(b.z), f2h(b.w)};
  *(u16x8*)(x16 + base) = o;
}

// Transpose weights into (N,K) fp16.
__global__ __launch_bounds__(256) void cvt_w(
    const float* __restrict__ Wq, const float* __restrict__ Wkv,
    const float* __restrict__ Wp, unsigned short* __restrict__ wt16,
    unsigned short* __restrict__ wp16) {
  int idx = blockIdx.x * 256 + threadIdx.x;  // 0 .. 262143
  float val; size_t dst; bool isp = false;
  if (idx < 65536) {
    int k = idx >> 8, n = idx & 255;
    val = Wq[idx]; dst = (size_t)n * 256 + k;
  } else if (idx < 196608) {
    int i2 = idx - 65536;
    int k = i2 >> 9, n2 = i2 & 511;
    val = Wkv[i2]; dst = (size_t)(256 + n2) * 256 + k;
  } else {
    int i3 = idx - 196608;
    int k = i3 >> 8, n = i3 & 255;
    val = Wp[i3]; dst = (size_t)n * 256 + k; isp = true;
  }
  unsigned short h = f2h(val);
  if (isp) wp16[dst] = h; else wt16[dst] = h;
}

// ---------------------------------------------------------------------------
__global__ __launch_bounds__(256) void bias_kernel(
    const float* __restrict__ affine, const float* __restrict__ atab,
    float* __restrict__ bias) {
  int idx = blockIdx.x * 256 + threadIdx.x;
  if (idx >= BB * NTOK) return;
  int b = idx >> 10, n = idx & (NTOK - 1);
  float cx = (float)(n & 31);
  float cy = (float)(n >> 5);
  const float* A = affine + b * 6;
  float egx = fmaf(A[0], 16.f, fmaf(A[1], 16.f, A[2]));
  float egy = fmaf(A[3], 16.f, fmaf(A[4], 16.f, A[5]));
  float ang = atan2f(cy - egy, cx - egx);
  float t = (ang + 3.14159265358979323846f) *
            (1.f / (2.f * 3.14159265358979323846f)) * 4.f;
  int bin = (int)t;
  bin = bin < 0 ? 0 : (bin > 4 ? 4 : bin);
  for (int h = 0; h < HEADS; ++h) {
    float a = atab[bin * HEADS + h];
    float s = 1.f / (1.f + __expf(-a));
    bias[((size_t)b * HEADS + h) * NTOK + n] = 1.f + s;
  }
}

// ---------------------------------------------------------------------------
// mask2T[b][k][q] = mask[b][q][k] * log2e  (transposed for swapped-QK attn)
// ---------------------------------------------------------------------------
__global__ __launch_bounds__(256) void mask_prepT(const float* __restrict__ m,
                                                  float* __restrict__ mT) {
  __shared__ float t[64][65];
  int bid = blockIdx.x;            // 4 * 16 * 16
  int bb = bid >> 8, bk = (bid >> 4) & 15, bq = bid & 15;
  int ty = threadIdx.x >> 4, tx = threadIdx.x & 15;
  const float* src = m + ((size_t)bb * NTOK + bq * 64) * NTOK + bk * 64;
#pragma unroll
  for (int i = 0; i < 4; ++i) {
    int row = ty + i * 16;
    float4 v = *(const float4*)(src + (size_t)row * NTOK + tx * 4);
    t[row][tx * 4 + 0] = v.x * LOG2E; t[row][tx * 4 + 1] = v.y * LOG2E;
    t[row][tx * 4 + 2] = v.z * LOG2E; t[row][tx * 4 + 3] = v.w * LOG2E;
  }
  __syncthreads();
  float* dst = mT + ((size_t)bb * NTOK + bk * 64) * NTOK + bq * 64;
#pragma unroll
  for (int i = 0; i < 4; ++i) {
    int row = ty + i * 16;  // k-local
    float4 v = {t[tx * 4 + 0][row], t[tx * 4 + 1][row],
                t[tx * 4 + 2][row], t[tx * 4 + 3][row]};
    *(float4*)(dst + (size_t)row * NTOK + tx * 4) = v;
  }
}

// ---------------------------------------------------------------------------
// QKV projection, single-fp16 MFMA, 128x128/BK=32 dbuf, u16 LDS-bounce
// epilogue. q carries scale*bias*log2e; k fp16; v RNE-bf16 transposed.
// ---------------------------------------------------------------------------
__global__ __launch_bounds__(512, 4) void gemm_qkv16(
    const unsigned short* __restrict__ x16, const unsigned short* __restrict__ wt16,
    const float* __restrict__ bq, const float* __restrict__ bkv,
    const float* __restrict__ bias, unsigned short* __restrict__ q16,
    unsigned short* __restrict__ k16, unsigned short* __restrict__ vt16) {
  __shared__ __align__(16) unsigned short SM[16384];  // 32 KB multi-use
  unsigned short* Xs = SM;            // [2][4096]
  unsigned short* Ws = SM + 8192;     // [2][4096]
  int tid = threadIdx.x;
  int w = tid >> 6, l = tid & 63;
  int row16 = l & 15, grp = l >> 4;
  int bid = blockIdx.x;
  int xcd = bid & 7, local = bid >> 3;        // 0..95
  int jb = local % 6, mb = xcd * 16 + local / 6;
  int j0 = jb * 128, m0 = mb * 128;
  int wm = w >> 1, wn = w & 1;

  auto stg = [&](int nb, int kt) {  // 1KB chunk per operand per wave
    int k0s = kt * 32;
    int row = w * 16 + (l >> 2);
    int ge = (((l & 3) * 16) ^ ((row & 3) << 4)) >> 1;
    gl_lds16(x16 + (size_t)(m0 + row) * 256 + k0s + ge, Xs + nb * 4096 + w * 512);
    gl_lds16(wt16 + (size_t)(j0 + row) * 256 + k0s + ge, Ws + nb * 4096 + w * 512);
  };
  auto off16 = [&](int row, int g) {
    return row * 32 + ((((g * 16) ^ ((row & 3) << 4))) >> 1);
  };

  stg(0, 0);
  __syncthreads();

  f32x4 acc[2][4];
#pragma unroll
  for (int i = 0; i < 2; ++i)
#pragma unroll
    for (int c = 0; c < 4; ++c) acc[i][c] = (f32x4){0.f, 0.f, 0.f, 0.f};

  for (int kt = 0; kt < 8; ++kt) {
    int cur = kt & 1;
    if (kt < 7) stg(cur ^ 1, kt + 1);
    half8 a0 = ldh8(Xs + cur * 4096 + off16(wm * 32 + row16, grp));
    half8 a1 = ldh8(Xs + cur * 4096 + off16(wm * 32 + 16 + row16, grp));
#pragma unroll
    for (int c = 0; c < 4; ++c) {
      half8 bh = ldh8(Ws + cur * 4096 + off16(wn * 64 + c * 16 + row16, grp));
      acc[0][c] = __builtin_amdgcn_mfma_f32_16x16x32_f16(a0, bh, acc[0][c], 0, 0, 0);
      acc[1][c] = __builtin_amdgcn_mfma_f32_16x16x32_f16(a1, bh, acc[1][c], 0, 0, 0);
    }
    __syncthreads();
  }

  // epilogue: bounce through SM as u16 [64][136], two 64-row halves
  const float scaleq = 0.17677669529663687f * LOG2E;
  int half_mine = wm >> 1;
  for (int half = 0; half < 2; ++half) {
    if (half_mine == half) {
#pragma unroll
      for (int i = 0; i < 2; ++i) {
#pragma unroll
        for (int c = 0; c < 4; ++c) {
          int col = wn * 64 + c * 16 + row16;
          int jg = j0 + col;
#pragma unroll
          for (int r = 0; r < 4; ++r) {
            int rowl = (wm & 1) * 32 + i * 16 + grp * 4 + r;
            int m = m0 + half * 64 + rowl;
            int b = m >> 10, n = m & (NTOK - 1);
            float val = acc[i][c][r];
            unsigned short o;
            if (jb < 2)
              o = f2h((val + bq[jg]) * scaleq *
                      bias[((size_t)b * HEADS + (jg >> 5)) * NTOK + n]);
            else if (jb < 4)
              o = f2h(val + bkv[jg - CDIM]);
            else
              o = f2b_rne(val + bkv[jg - CDIM]);
            SM[rowl * 136 + col] = o;
          }
        }
      }
    }
    __syncthreads();
    if (jb < 4) {
#pragma unroll
      for (int it = 0; it < 2; ++it) {
        int lin = it * 512 + tid;
        int rowb = lin >> 4, oct = lin & 15;
        u16x8 v = *(const u16x8*)&SM[rowb * 136 + oct * 8];
        int m = m0 + half * 64 + rowb;
        int b = m >> 10, n = m & (NTOK - 1);
        int jg = j0 + oct * 8;
        unsigned short* dst; int h, d;
        if (jb < 2) { h = jg >> 5; d = jg & 31; dst = q16; }
        else { int c2 = jg - CDIM; h = c2 >> 5; d = c2 & 31; dst = k16; }
        *(u16x8*)(dst + (((size_t)b * HEADS + h) * NTOK + n) * HD + d) = v;
      }
    } else {
#pragma unroll
      for (int it = 0; it < 2; ++it) {
        int lin = it * 512 + tid;
        int noct = lin >> 7, jl = lin & 127;
        u16x8 v;
#pragma unroll
        for (int e = 0; e < 8; ++e) v[e] = SM[(noct * 8 + e) * 136 + jl];
        int c3 = j0 + jl - 2 * CDIM;
        int h = c3 >> 5, d = c3 & 31;
        int n0 = m0 + half * 64 + noct * 8;
        int b = n0 >> 10, nn = n0 & (NTOK - 1);
        *(u16x8*)(vt16 + (((size_t)b * HEADS + h) * HD + d) * NTOK + nn) = v;
      }
    }
    __syncthreads();
  }
}

// ---------------------------------------------------------------------------
// Flash attention: fp16 Q/K (1-term QK), bf16 V + split-bf16 P (2-term PV),
// swapped QK^T (lane owns its q-row), packed-pair P bounce in per-wave
// XOR-block-swizzled LDS. gl_lds dbuf staging, 32 KB LDS total.
// ---------------------------------------------------------------------------
__global__ __launch_bounds__(512, 8) void attn16(
    const unsigned short* __restrict__ q16, const unsigned short* __restrict__ k16,
    const unsigned short* __restrict__ vt16, const float* __restrict__ mask2T,
    unsigned short* __restrict__ ao16) {
  __shared__ __align__(16) unsigned short KT[2][64 * 32];  // fp16
  __shared__ __align__(16) unsigned short VT[2][32 * 64];  // bf16
  __shared__ __align__(16) unsigned Pph[8][16][16];
  __shared__ __align__(16) unsigned Ppl[8][16][16];

  int tid = threadIdx.x;
  int w = tid >> 6, l = tid & 63;
  int row16 = l & 15, grp = l >> 4;
  int bid = blockIdx.x;
  int swz = (bid & 7) * 128 + (bid >> 3);
  int qt = swz & 7, h = (swz >> 3) & 7, b = swz >> 6;
  int q0 = qt * 128;
  int bh = b * HEADS + h;

  // Q as B-operand: col=q=row16, k-dim=d
  size_t qidx = (((size_t)bh * NTOK) + q0 + w * 16 + row16) * HD + grp * 8;
  half8 bq16 = ldh8(q16 + qidx);

  const float* maskT = mask2T + (size_t)(b & 3) * NTOK * NTOK +
                       (q0 + w * 16 + row16);

  f32x4 accd[2];
  accd[0] = (f32x4){0.f, 0.f, 0.f, 0.f};
  accd[1] = (f32x4){0.f, 0.f, 0.f, 0.f};
  float lsum = 0.f;
  const f32x4 zero4 = (f32x4){0.f, 0.f, 0.f, 0.f};

  auto stage = [&](int nbuf, int kt2) {  // 8 x 1KB chunks, 1 per wave
    int k0n = kt2 * 64;
    if (w < 4) {  // K: [64k][32d] fp16
      int kl = w * 16 + (l >> 2);
      int gd = (((l & 3) * 16) ^ ((kl & 3) << 4)) >> 1;
      gl_lds16(k16 + (((size_t)bh * NTOK) + k0n + kl) * HD + gd,
               &KT[nbuf][w * 16 * 32]);
    } else {      // V^T: [32d][64k] bf16
      int sub = w - 4;
      int dl = sub * 8 + (l >> 3);
      int gk = (((l & 7) * 16) ^ ((dl & 7) << 4)) >> 1;
      gl_lds16(vt16 + ((size_t)bh * HD + dl) * NTOK + k0n + gk,
               &VT[nbuf][sub * 8 * 64]);
    }
  };

  stage(0, 0);
  __syncthreads();

  for (int kt = 0; kt < 16; ++kt) {
    int cur = kt & 1;
    int k0 = kt * 64;
    if (kt < 15) stage(cur ^ 1, kt + 1);

#pragma unroll
    for (int hf = 0; hf < 2; ++hf) {
      f32x4 s[2];
      float mk[2][4];
#pragma unroll
      for (int fp = 0; fp < 2; ++fp) {
        int f = hf * 2 + fp;
#pragma unroll
        for (int r = 0; r < 4; ++r)
          mk[fp][r] = maskT[(size_t)(k0 + f * 16 + grp * 4 + r) * NTOK];
        int kl = f * 16 + row16;
        int cb = (grp * 16) ^ ((kl & 3) << 4);
        half8 kf = ldh8(&KT[cur][kl * 32 + (cb >> 1)]);
        // swapped: S^T[k][q]; lane -> S[q=row16][k0+16f+4grp+r]
        s[fp] = __builtin_amdgcn_mfma_f32_16x16x32_f16(kf, bq16, zero4, 0, 0, 0);
      }
#pragma unroll
      for (int fp = 0; fp < 2; ++fp) {
        float p0 = __builtin_amdgcn_exp2f(s[fp][0] + mk[fp][0]);
        float p1 = __builtin_amdgcn_exp2f(s[fp][1] + mk[fp][1]);
        float p2 = __builtin_amdgcn_exp2f(s[fp][2] + mk[fp][2]);
        float p3 = __builtin_amdgcn_exp2f(s[fp][3] + mk[fp][3]);
        lsum += (p0 + p1) + (p2 + p3);
        unsigned short h0, l0, h1, l1, h2, l2, h3, l3;
        split_bf(p0, h0, l0); split_bf(p1, h1, l1);
        split_bf(p2, h2, l2); split_bf(p3, h3, l3);
        unsigned h01 = h0 | ((unsigned)h1 << 16);
        unsigned h23 = h2 | ((unsigned)h3 << 16);
        unsigned l01 = l0 | ((unsigned)l1 << 16);
        unsigned l23 = l2 | ((unsigned)l3 << 16);
        // logical pair-cols {8fp+2grp, +1} -> block 2fp+(grp>>1), XOR row16&3
        int pc = ((2 * fp + (grp >> 1)) ^ (row16 & 3)) * 4 + 2 * (grp & 1);
        *(u32x2*)&Pph[w][row16][pc] = (u32x2){h01, h23};
        *(u32x2*)&Ppl[w][row16][pc] = (u32x2){l01, l23};
      }
      // read own q-row's A-frag: logical block grp, same XOR
      int rblk = (grp ^ (row16 & 3)) * 4;
      bf16x8 ph = __builtin_bit_cast(bf16x8, *(const u32x4*)&Pph[w][row16][rblk]);
      bf16x8 pl = __builtin_bit_cast(bf16x8, *(const u32x4*)&Ppl[w][row16][rblk]);
#pragma unroll
      for (int df = 0; df < 2; ++df) {
        int dl = df * 16 + row16;
        int cb = (hf * 64 + grp * 16) ^ ((dl & 7) << 4);
        bf16x8 v = ldb8(&VT[cur][dl * 64 + (cb >> 1)]);
        accd[df] = __builtin_amdgcn_mfma_f32_16x16x32_bf16(ph, v, accd[df], 0, 0, 0);
        accd[df] = __builtin_amdgcn_mfma_f32_16x16x32_bf16(pl, v, accd[df], 0, 0, 0);
      }
    }
    __syncthreads();
  }

  // row-sum: lane's partial covers its grp slice; reduce across grp
  lsum += __shfl_xor(lsum, 16);
  lsum += __shfl_xor(lsum, 32);
#pragma unroll
  for (int r = 0; r < 4; ++r) {
    float lr = __shfl(lsum, grp * 4 + r, 16);
    float inv = 1.f / lr;
    int qrow = q0 + w * 16 + grp * 4 + r;
    size_t obase = ((size_t)b * NTOK + qrow) * CDIM + h * HD;
    ao16[obase + row16] = f2h(accd[0][r] * inv);
    ao16[obase + 16 + row16] = f2h(accd[1][r] * inv);
  }
}

// ---------------------------------------------------------------------------
// Output projection, single-fp16 MFMA, 128x128/BK=32 dbuf.
// ---------------------------------------------------------------------------
__global__ __launch_bounds__(512, 4) void gemm_out16(
    const unsigned short* __restrict__ a16, const unsigned short* __restrict__ wp16,
    const float* __restrict__ bp, float* __restrict__ out) {
  __shared__ __align__(16) unsigned short SM[16384];
  unsigned short* Xs = SM;
  unsigned short* Ws = SM + 8192;
  int tid = threadIdx.x;
  int w = tid >> 6, l = tid & 63;
  int row16 = l & 15, grp = l >> 4;
  int bid = blockIdx.x;
  int xcd = bid & 7, local = bid >> 3;
  int jb = local & 1, mb = xcd * 16 + (local >> 1);
  int j0 = jb * 128, m0 = mb * 128;
  int wm = w >> 1, wn = w & 1;

  auto stg = [&](int nb, int kt) {
    int k0s = kt * 32;
    int row = w * 16 + (l >> 2);
    int ge = (((l & 3) * 16) ^ ((row & 3) << 4)) >> 1;
    gl_lds16(a16 + (size_t)(m0 + row) * 256 + k0s + ge, Xs + nb * 4096 + w * 512);
    gl_lds16(wp16 + (size_t)(j0 + row) * 256 + k0s + ge, Ws + nb * 4096 + w * 512);
  };
  auto off16 = [&](int row, int g) {
    return row * 32 + ((((g * 16) ^ ((row & 3) << 4))) >> 1);
  };

  stg(0, 0);
  __syncthreads();

  f32x4 acc[2][4];
#pragma unroll
  for (int i = 0; i < 2; ++i)
#pragma unroll
    for (int c = 0; c < 4; ++c) acc[i][c] = (f32x4){0.f, 0.f, 0.f, 0.f};

  for (int kt = 0; kt < 8; ++kt) {
    int cur = kt & 1;
    if (kt < 7) stg(cur ^ 1, kt + 1);
    half8 a0 = ldh8(Xs + cur * 4096 + off16(wm * 32 + row16, grp));
    half8 a1 = ldh8(Xs + cur * 4096 + off16(wm * 32 + 16 + row16, grp));
#pragma unroll
    for (int c = 0; c < 4; ++c) {
      half8 bh = ldh8(Ws + cur * 4096 + off16(wn * 64 + c * 16 + row16, grp));
      acc[0][c] = __builtin_amdgcn_mfma_f32_16x16x32_f16(a0, bh, acc[0][c], 0, 0, 0);
      acc[1][c] = __builtin_amdgcn_mfma_f32_16x16x32_f16(a1, bh, acc[1][c], 0, 0, 0);
    }
    __syncthreads();
  }

#pragma unroll
  for (int i = 0; i < 2; ++i) {
    int ng = m0 + wm * 32 + i * 16 + grp * 4;
#pragma unroll
    for (int c = 0; c < 4; ++c) {
      int jg = j0 + wn * 64 + c * 16 + row16;
      float bias = bp[jg];
#pragma unroll
      for (int r = 0; r < 4; ++r) {
        out[(size_t)(ng + r) * CDIM + jg] = acc[i][c][r] + bias;
      }
    }
  }
}

// ---------------------------------------------------------------------------
extern "C" void kernel_launch(void* const* d_in, const int* in_sizes, int n_in,
                              void* d_out, int out_size, void* d_ws,
                              size_t ws_size, hipStream_t stream) {
  const float* x = (const float*)d_in[0];
  const float* mask = (const float*)d_in[1];
  const float* affine = (const float*)d_in[2];
  const float* Wq = (const float*)d_in[3];
  const float* bq = (const float*)d_in[4];
  const float* Wkv = (const float*)d_in[5];
  const float* bkv = (const float*)d_in[6];
  const float* Wp = (const float*)d_in[7];
  const float* bp = (const float*)d_in[8];
  const float* atab = (const float*)d_in[9];
  float* out = (float*)d_out;

  const size_t bhnd = (size_t)BB * HEADS * NTOK * HD;  // 4,194,304
  unsigned short* q16 = (unsigned short*)d_ws;
  unsigned short* k16 = q16 + bhnd;
  unsigned short* vt16 = k16 + bhnd;
  unsigned short* x16 = vt16 + bhnd;     // aliased as ao16 after qkv
  unsigned short* wt16 = x16 + bhnd;     // 768*256
  unsigned short* wp16 = wt16 + 768 * 256;
  float* bias = (float*)(wp16 + 256 * 256);
  float* mask2T = bias + (size_t)BB * HEADS * NTOK;

  cvt_x<<<2048, 256, 0, stream>>>(x, x16);
  cvt_w<<<1024, 256, 0, stream>>>(Wq, Wkv, Wp, wt16, wp16);
  bias_kernel<<<64, 256, 0, stream>>>(affine, atab, bias);
  mask_prepT<<<1024, 256, 0, stream>>>(mask, mask2T);
  gemm_qkv16<<<768, 512, 0, stream>>>(x16, wt16, bq, bkv, bias, q16, k16, vt16);
  attn16<<<1024, 512, 0, stream>>>(q16, k16, vt16, mask2T, x16);
  gemm_out16<<<256, 512, 0, stream>>>(x16, wp16, bp, out);
}

// Round 11
// 111.164 us; speedup vs baseline: 3.8470x; 1.0568x over previous
//
#include <hip/hip_runtime.h>
#include <hip/hip_bf16.h>
#include <math.h>

#define BB 16
#define NTOK 1024
#define CDIM 256
#define HEADS 8
#define HD 32
#define LOG2E 1.4426950408889634f
#define PSHIFT 18.0f

typedef __attribute__((ext_vector_type(8))) _Float16 half8;
typedef __attribute__((ext_vector_type(2))) _Float16 half2v;
typedef __attribute__((ext_vector_type(8))) unsigned short u16x8;
typedef __attribute__((ext_vector_type(4))) unsigned int u32x4;
typedef __attribute__((ext_vector_type(2))) unsigned int u32x2;
typedef __attribute__((ext_vector_type(4))) float f32x4;

__device__ __forceinline__ unsigned short f2h(float f) {
  _Float16 h = (_Float16)f;
  return __builtin_bit_cast(unsigned short, h);
}
__device__ __forceinline__ half8 ldh8(const unsigned short* p) {
  return *reinterpret_cast<const half8*>(p);
}
__device__ __forceinline__ void gl_lds16(const unsigned short* g,
                                         unsigned short* l) {
  __builtin_amdgcn_global_load_lds(
      (const __attribute__((address_space(1))) unsigned int*)g,
      (__attribute__((address_space(3))) unsigned int*)l, 16, 0, 0);
}

// ---------------------------------------------------------------------------
__global__ __launch_bounds__(256) void cvt_x(const float* __restrict__ X,
                                             unsigned short* __restrict__ x16) {
  size_t base = ((size_t)blockIdx.x * 256 + threadIdx.x) * 8;
  float4 a = *(const float4*)(X + base);
  float4 b = *(const float4*)(X + base + 4);
  u16x8 o = {f2h(a.x), f2h(a.y), f2h(a.z), f2h(a.w),
             f2h(b.x), f2h(b.y), f2h(b.z), f2h(b.w)};
  *(u16x8*)(x16 + base) = o;
}

// Transpose weights into (N,K) fp16.
__global__ __launch_bounds__(256) void cvt_w(
    const float* __restrict__ Wq, const float* __restrict__ Wkv,
    const float* __restrict__ Wp, unsigned short* __restrict__ wt16,
    unsigned short* __restrict__ wp16) {
  int idx = blockIdx.x * 256 + threadIdx.x;  // 0 .. 262143
  float val; size_t dst; bool isp = false;
  if (idx < 65536) {
    int k = idx >> 8, n = idx & 255;
    val = Wq[idx]; dst = (size_t)n * 256 + k;
  } else if (idx < 196608) {
    int i2 = idx - 65536;
    int k = i2 >> 9, n2 = i2 & 511;
    val = Wkv[i2]; dst = (size_t)(256 + n2) * 256 + k;
  } else {
    int i3 = idx - 196608;
    int k = i3 >> 8, n = i3 & 255;
    val = Wp[i3]; dst = (size_t)n * 256 + k; isp = true;
  }
  unsigned short h = f2h(val);
  if (isp) wp16[dst] = h; else wt16[dst] = h;
}

// ---------------------------------------------------------------------------
__global__ __launch_bounds__(256) void bias_kernel(
    const float* __restrict__ affine, const float* __restrict__ atab,
    float* __restrict__ bias) {
  int idx = blockIdx.x * 256 + threadIdx.x;
  if (idx >= BB * NTOK) return;
  int b = idx >> 10, n = idx & (NTOK - 1);
  float cx = (float)(n & 31);
  float cy = (float)(n >> 5);
  const float* A = affine + b * 6;
  float egx = fmaf(A[0], 16.f, fmaf(A[1], 16.f, A[2]));
  float egy = fmaf(A[3], 16.f, fmaf(A[4], 16.f, A[5]));
  float ang = atan2f(cy - egy, cx - egx);
  float t = (ang + 3.14159265358979323846f) *
            (1.f / (2.f * 3.14159265358979323846f)) * 4.f;
  int bin = (int)t;
  bin = bin < 0 ? 0 : (bin > 4 ? 4 : bin);
  for (int h = 0; h < HEADS; ++h) {
    float a = atab[bin * HEADS + h];
    float s = 1.f / (1.f + __expf(-a));
    bias[((size_t)b * HEADS + h) * NTOK + n] = 1.f + s;
  }
}

// ---------------------------------------------------------------------------
// mask2T[b][k][q] = mask[b][q][k] * log2e - PSHIFT (exp2 domain, fp16-P shift)
// ---------------------------------------------------------------------------
__global__ __launch_bounds__(256) void mask_prepT(const float* __restrict__ m,
                                                  float* __restrict__ mT) {
  __shared__ float t[64][65];
  int bid = blockIdx.x;            // 4 * 16 * 16
  int bb = bid >> 8, bk = (bid >> 4) & 15, bq = bid & 15;
  int ty = threadIdx.x >> 4, tx = threadIdx.x & 15;
  const float* src = m + ((size_t)bb * NTOK + bq * 64) * NTOK + bk * 64;
#pragma unroll
  for (int i = 0; i < 4; ++i) {
    int row = ty + i * 16;
    float4 v = *(const float4*)(src + (size_t)row * NTOK + tx * 4);
    t[row][tx * 4 + 0] = fmaf(v.x, LOG2E, -PSHIFT);
    t[row][tx * 4 + 1] = fmaf(v.y, LOG2E, -PSHIFT);
    t[row][tx * 4 + 2] = fmaf(v.z, LOG2E, -PSHIFT);
    t[row][tx * 4 + 3] = fmaf(v.w, LOG2E, -PSHIFT);
  }
  __syncthreads();
  float* dst = mT + ((size_t)bb * NTOK + bk * 64) * NTOK + bq * 64;
#pragma unroll
  for (int i = 0; i < 4; ++i) {
    int row = ty + i * 16;  // k-local
    float4 v = {t[tx * 4 + 0][row], t[tx * 4 + 1][row],
                t[tx * 4 + 2][row], t[tx * 4 + 3][row]};
    *(float4*)(dst + (size_t)row * NTOK + tx * 4) = v;
  }
}

// ---------------------------------------------------------------------------
// QKV projection, single-fp16 MFMA, 128x128/BK=32 dbuf, u16 LDS-bounce
// epilogue. q carries scale*bias*log2e; k fp16; v fp16 transposed.
// ---------------------------------------------------------------------------
__global__ __launch_bounds__(512, 4) void gemm_qkv16(
    const unsigned short* __restrict__ x16, const unsigned short* __restrict__ wt16,
    const float* __restrict__ bq, const float* __restrict__ bkv,
    const float* __restrict__ bias, unsigned short* __restrict__ q16,
    unsigned short* __restrict__ k16, unsigned short* __restrict__ vt16) {
  __shared__ __align__(16) unsigned short SM[16384];  // 32 KB multi-use
  unsigned short* Xs = SM;            // [2][4096]
  unsigned short* Ws = SM + 8192;     // [2][4096]
  int tid = threadIdx.x;
  int w = tid >> 6, l = tid & 63;
  int row16 = l & 15, grp = l >> 4;
  int bid = blockIdx.x;
  int xcd = bid & 7, local = bid >> 3;        // 0..95
  int jb = local % 6, mb = xcd * 16 + local / 6;
  int j0 = jb * 128, m0 = mb * 128;
  int wm = w >> 1, wn = w & 1;

  auto stg = [&](int nb, int kt) {  // 1KB chunk per operand per wave
    int k0s = kt * 32;
    int row = w * 16 + (l >> 2);
    int ge = (((l & 3) * 16) ^ ((row & 3) << 4)) >> 1;
    gl_lds16(x16 + (size_t)(m0 + row) * 256 + k0s + ge, Xs + nb * 4096 + w * 512);
    gl_lds16(wt16 + (size_t)(j0 + row) * 256 + k0s + ge, Ws + nb * 4096 + w * 512);
  };
  auto off16 = [&](int row, int g) {
    return row * 32 + ((((g * 16) ^ ((row & 3) << 4))) >> 1);
  };

  stg(0, 0);
  __syncthreads();

  f32x4 acc[2][4];
#pragma unroll
  for (int i = 0; i < 2; ++i)
#pragma unroll
    for (int c = 0; c < 4; ++c) acc[i][c] = (f32x4){0.f, 0.f, 0.f, 0.f};

  for (int kt = 0; kt < 8; ++kt) {
    int cur = kt & 1;
    if (kt < 7) stg(cur ^ 1, kt + 1);
    half8 a0 = ldh8(Xs + cur * 4096 + off16(wm * 32 + row16, grp));
    half8 a1 = ldh8(Xs + cur * 4096 + off16(wm * 32 + 16 + row16, grp));
#pragma unroll
    for (int c = 0; c < 4; ++c) {
      half8 bh = ldh8(Ws + cur * 4096 + off16(wn * 64 + c * 16 + row16, grp));
      acc[0][c] = __builtin_amdgcn_mfma_f32_16x16x32_f16(a0, bh, acc[0][c], 0, 0, 0);
      acc[1][c] = __builtin_amdgcn_mfma_f32_16x16x32_f16(a1, bh, acc[1][c], 0, 0, 0);
    }
    __syncthreads();
  }

  // epilogue: bounce through SM as u16 [64][136], two 64-row halves
  const float scaleq = 0.17677669529663687f * LOG2E;
  int half_mine = wm >> 1;
  for (int half = 0; half < 2; ++half) {
    if (half_mine == half) {
#pragma unroll
      for (int i = 0; i < 2; ++i) {
#pragma unroll
        for (int c = 0; c < 4; ++c) {
          int col = wn * 64 + c * 16 + row16;
          int jg = j0 + col;
#pragma unroll
          for (int r = 0; r < 4; ++r) {
            int rowl = (wm & 1) * 32 + i * 16 + grp * 4 + r;
            int m = m0 + half * 64 + rowl;
            int b = m >> 10, n = m & (NTOK - 1);
            float val = acc[i][c][r];
            unsigned short o;
            if (jb < 2)
              o = f2h((val + bq[jg]) * scaleq *
                      bias[((size_t)b * HEADS + (jg >> 5)) * NTOK + n]);
            else
              o = f2h(val + bkv[jg - CDIM]);
            SM[rowl * 136 + col] = o;
          }
        }
      }
    }
    __syncthreads();
    if (jb < 4) {
#pragma unroll
      for (int it = 0; it < 2; ++it) {
        int lin = it * 512 + tid;
        int rowb = lin >> 4, oct = lin & 15;
        u16x8 v = *(const u16x8*)&SM[rowb * 136 + oct * 8];
        int m = m0 + half * 64 + rowb;
        int b = m >> 10, n = m & (NTOK - 1);
        int jg = j0 + oct * 8;
        unsigned short* dst; int h, d;
        if (jb < 2) { h = jg >> 5; d = jg & 31; dst = q16; }
        else { int c2 = jg - CDIM; h = c2 >> 5; d = c2 & 31; dst = k16; }
        *(u16x8*)(dst + (((size_t)b * HEADS + h) * NTOK + n) * HD + d) = v;
      }
    } else {
#pragma unroll
      for (int it = 0; it < 2; ++it) {
        int lin = it * 512 + tid;
        int noct = lin >> 7, jl = lin & 127;
        u16x8 v;
#pragma unroll
        for (int e = 0; e < 8; ++e) v[e] = SM[(noct * 8 + e) * 136 + jl];
        int c3 = j0 + jl - 2 * CDIM;
        int h = c3 >> 5, d = c3 & 31;
        int n0 = m0 + half * 64 + noct * 8;
        int b = n0 >> 10, nn = n0 & (NTOK - 1);
        *(u16x8*)(vt16 + (((size_t)b * HEADS + h) * HD + d) * NTOK + nn) = v;
      }
    }
    __syncthreads();
  }
}

// ---------------------------------------------------------------------------
// Flash attention: fp16 throughout (Q/K/V/P). Swapped QK^T; p' = 2^(s+m-18)
// fits fp16 (shift cancels in normalization). P packed via cvt_pkrtz into a
// pad-20 per-wave LDS row (conflict-free b64 writes / b128 reads).
// Mask registers prefetched one tile ahead. 8 MFMA/tile.
// ---------------------------------------------------------------------------
__global__ __launch_bounds__(512, 8) void attn16(
    const unsigned short* __restrict__ q16, const unsigned short* __restrict__ k16,
    const unsigned short* __restrict__ vt16, const float* __restrict__ mask2T,
    unsigned short* __restrict__ ao16) {
  __shared__ __align__(16) unsigned short KT[2][64 * 32];  // fp16
  __shared__ __align__(16) unsigned short VT[2][32 * 64];  // fp16
  __shared__ __align__(16) unsigned Pp[8][16][20];         // pad-20 rows

  int tid = threadIdx.x;
  int w = tid >> 6, l = tid & 63;
  int row16 = l & 15, grp = l >> 4;
  int bid = blockIdx.x;
  int swz = (bid & 7) * 128 + (bid >> 3);
  int qt = swz & 7, h = (swz >> 3) & 7, b = swz >> 6;
  int q0 = qt * 128;
  int bh = b * HEADS + h;

  // Q as B-operand: col=q=row16, k-dim=d
  size_t qidx = (((size_t)bh * NTOK) + q0 + w * 16 + row16) * HD + grp * 8;
  half8 bq16 = ldh8(q16 + qidx);

  const float* maskT = mask2T + (size_t)(b & 3) * NTOK * NTOK +
                       (q0 + w * 16 + row16);

  f32x4 accd[2];
  accd[0] = (f32x4){0.f, 0.f, 0.f, 0.f};
  accd[1] = (f32x4){0.f, 0.f, 0.f, 0.f};
  float lsum = 0.f;
  const f32x4 zero4 = (f32x4){0.f, 0.f, 0.f, 0.f};

  auto stage = [&](int nbuf, int kt2) {  // 8 x 1KB chunks, 1 per wave
    int k0n = kt2 * 64;
    if (w < 4) {  // K: [64k][32d] fp16
      int kl = w * 16 + (l >> 2);
      int gd = (((l & 3) * 16) ^ ((kl & 3) << 4)) >> 1;
      gl_lds16(k16 + (((size_t)bh * NTOK) + k0n + kl) * HD + gd,
               &KT[nbuf][w * 16 * 32]);
    } else {      // V^T: [32d][64k] fp16
      int sub = w - 4;
      int dl = sub * 8 + (l >> 3);
      int gk = (((l & 7) * 16) ^ ((dl & 7) << 4)) >> 1;
      gl_lds16(vt16 + ((size_t)bh * HD + dl) * NTOK + k0n + gk,
               &VT[nbuf][sub * 8 * 64]);
    }
  };

  // prologue: mask regs for tile 0
  float mcur[16], mnxt[16];
#pragma unroll
  for (int i = 0; i < 16; ++i) {
    int f = i >> 2, r = i & 3;
    mcur[i] = maskT[(size_t)(f * 16 + grp * 4 + r) * NTOK];
  }
  stage(0, 0);
  __syncthreads();

  for (int kt = 0; kt < 16; ++kt) {
    int cur = kt & 1;
    if (kt < 15) stage(cur ^ 1, kt + 1);
    // prefetch next tile's mask into regs (wrap harmless)
    int k0n = ((kt + 1) & 15) * 64;
#pragma unroll
    for (int i = 0; i < 16; ++i) {
      int f = i >> 2, r = i & 3;
      mnxt[i] = maskT[(size_t)(k0n + f * 16 + grp * 4 + r) * NTOK];
    }

#pragma unroll
    for (int hf = 0; hf < 2; ++hf) {
      f32x4 s[2];
#pragma unroll
      for (int fp = 0; fp < 2; ++fp) {
        int f = hf * 2 + fp;
        int kl = f * 16 + row16;
        int cb = (grp * 16) ^ ((kl & 3) << 4);
        half8 kf = ldh8(&KT[cur][kl * 32 + (cb >> 1)]);
        s[fp] = __builtin_amdgcn_mfma_f32_16x16x32_f16(kf, bq16, zero4, 0, 0, 0);
      }
#pragma unroll
      for (int fp = 0; fp < 2; ++fp) {
        int mi = hf * 8 + fp * 4;
        float p0 = __builtin_amdgcn_exp2f(s[fp][0] + mcur[mi + 0]);
        float p1 = __builtin_amdgcn_exp2f(s[fp][1] + mcur[mi + 1]);
        float p2 = __builtin_amdgcn_exp2f(s[fp][2] + mcur[mi + 2]);
        float p3 = __builtin_amdgcn_exp2f(s[fp][3] + mcur[mi + 3]);
        lsum += (p0 + p1) + (p2 + p3);
        unsigned pk01 =
            __builtin_bit_cast(unsigned, __builtin_amdgcn_cvt_pkrtz(p0, p1));
        unsigned pk23 =
            __builtin_bit_cast(unsigned, __builtin_amdgcn_cvt_pkrtz(p2, p3));
        *(u32x2*)&Pp[w][row16][fp * 8 + grp * 2] = (u32x2){pk01, pk23};
      }
      // read own q-row's A-frag: cols grp*4..+3 hold k = grp*8..grp*8+7
      half8 pa =
          __builtin_bit_cast(half8, *(const u32x4*)&Pp[w][row16][grp * 4]);
#pragma unroll
      for (int df = 0; df < 2; ++df) {
        int dl = df * 16 + row16;
        int cb = (hf * 64 + grp * 16) ^ ((dl & 7) << 4);
        half8 v = ldh8(&VT[cur][dl * 64 + (cb >> 1)]);
        accd[df] = __builtin_amdgcn_mfma_f32_16x16x32_f16(pa, v, accd[df], 0, 0, 0);
      }
    }
    __syncthreads();
#pragma unroll
    for (int i = 0; i < 16; ++i) mcur[i] = mnxt[i];
  }

  // row-sum: reduce across the 4 grp slices for fixed row16
  lsum += __shfl_xor(lsum, 16);
  lsum += __shfl_xor(lsum, 32);
#pragma unroll
  for (int r = 0; r < 4; ++r) {
    float lr = __shfl(lsum, grp * 4 + r, 16);
    float inv = 1.f / lr;
    int qrow = q0 + w * 16 + grp * 4 + r;
    size_t obase = ((size_t)b * NTOK + qrow) * CDIM + h * HD;
    ao16[obase + row16] = f2h(accd[0][r] * inv);
    ao16[obase + 16 + row16] = f2h(accd[1][r] * inv);
  }
}

// ---------------------------------------------------------------------------
// Output projection, single-fp16 MFMA, 128x128/BK=32 dbuf.
// ---------------------------------------------------------------------------
__global__ __launch_bounds__(512, 4) void gemm_out16(
    const unsigned short* __restrict__ a16, const unsigned short* __restrict__ wp16,
    const float* __restrict__ bp, float* __restrict__ out) {
  __shared__ __align__(16) unsigned short SM[16384];
  unsigned short* Xs = SM;
  unsigned short* Ws = SM + 8192;
  int tid = threadIdx.x;
  int w = tid >> 6, l = tid & 63;
  int row16 = l & 15, grp = l >> 4;
  int bid = blockIdx.x;
  int xcd = bid & 7, local = bid >> 3;
  int jb = local & 1, mb = xcd * 16 + (local >> 1);
  int j0 = jb * 128, m0 = mb * 128;
  int wm = w >> 1, wn = w & 1;

  auto stg = [&](int nb, int kt) {
    int k0s = kt * 32;
    int row = w * 16 + (l >> 2);
    int ge = (((l & 3) * 16) ^ ((row & 3) << 4)) >> 1;
    gl_lds16(a16 + (size_t)(m0 + row) * 256 + k0s + ge, Xs + nb * 4096 + w * 512);
    gl_lds16(wp16 + (size_t)(j0 + row) * 256 + k0s + ge, Ws + nb * 4096 + w * 512);
  };
  auto off16 = [&](int row, int g) {
    return row * 32 + ((((g * 16) ^ ((row & 3) << 4))) >> 1);
  };

  stg(0, 0);
  __syncthreads();

  f32x4 acc[2][4];
#pragma unroll
  for (int i = 0; i < 2; ++i)
#pragma unroll
    for (int c = 0; c < 4; ++c) acc[i][c] = (f32x4){0.f, 0.f, 0.f, 0.f};

  for (int kt = 0; kt < 8; ++kt) {
    int cur = kt & 1;
    if (kt < 7) stg(cur ^ 1, kt + 1);
    half8 a0 = ldh8(Xs + cur * 4096 + off16(wm * 32 + row16, grp));
    half8 a1 = ldh8(Xs + cur * 4096 + off16(wm * 32 + 16 + row16, grp));
#pragma unroll
    for (int c = 0; c < 4; ++c) {
      half8 bh = ldh8(Ws + cur * 4096 + off16(wn * 64 + c * 16 + row16, grp));
      acc[0][c] = __builtin_amdgcn_mfma_f32_16x16x32_f16(a0, bh, acc[0][c], 0, 0, 0);
      acc[1][c] = __builtin_amdgcn_mfma_f32_16x16x32_f16(a1, bh, acc[1][c], 0, 0, 0);
    }
    __syncthreads();
  }

#pragma unroll
  for (int i = 0; i < 2; ++i) {
    int ng = m0 + wm * 32 + i * 16 + grp * 4;
#pragma unroll
    for (int c = 0; c < 4; ++c) {
      int jg = j0 + wn * 64 + c * 16 + row16;
      float bias = bp[jg];
#pragma unroll
      for (int r = 0; r < 4; ++r) {
        out[(size_t)(ng + r) * CDIM + jg] = acc[i][c][r] + bias;
      }
    }
  }
}

// ---------------------------------------------------------------------------
extern "C" void kernel_launch(void* const* d_in, const int* in_sizes, int n_in,
                              void* d_out, int out_size, void* d_ws,
                              size_t ws_size, hipStream_t stream) {
  const float* x = (const float*)d_in[0];
  const float* mask = (const float*)d_in[1];
  const float* affine = (const float*)d_in[2];
  const float* Wq = (const float*)d_in[3];
  const float* bq = (const float*)d_in[4];
  const float* Wkv = (const float*)d_in[5];
  const float* bkv = (const float*)d_in[6];
  const float* Wp = (const float*)d_in[7];
  const float* bp = (const float*)d_in[8];
  const float* atab = (const float*)d_in[9];
  float* out = (float*)d_out;

  const size_t bhnd = (size_t)BB * HEADS * NTOK * HD;  // 4,194,304
  unsigned short* q16 = (unsigned short*)d_ws;
  unsigned short* k16 = q16 + bhnd;
  unsigned short* vt16 = k16 + bhnd;
  unsigned short* x16 = vt16 + bhnd;     // aliased as ao16 after qkv
  unsigned short* wt16 = x16 + bhnd;     // 768*256
  unsigned short* wp16 = wt16 + 768 * 256;
  float* bias = (float*)(wp16 + 256 * 256);
  float* mask2T = bias + (size_t)BB * HEADS * NTOK;

  cvt_x<<<2048, 256, 0, stream>>>(x, x16);
  cvt_w<<<1024, 256, 0, stream>>>(Wq, Wkv, Wp, wt16, wp16);
  bias_kernel<<<64, 256, 0, stream>>>(affine, atab, bias);
  mask_prepT<<<1024, 256, 0, stream>>>(mask, mask2T);
  gemm_qkv16<<<768, 512, 0, stream>>>(x16, wt16, bq, bkv, bias, q16, k16, vt16);
  attn16<<<1024, 512, 0, stream>>>(q16, k16, vt16, mask2T, x16);
  gemm_out16<<<256, 512, 0, stream>>>(x16, wp16, bp, out);
}

// Round 12
// 97.998 us; speedup vs baseline: 4.3639x; 1.1343x over previous
//
#include <hip/hip_runtime.h>
#include <hip/hip_bf16.h>
#include <math.h>

#define BB 16
#define NTOK 1024
#define CDIM 256
#define HEADS 8
#define HD 32
#define LOG2E 1.4426950408889634f
#define PSHIFT 18.0f

typedef __attribute__((ext_vector_type(8))) _Float16 half8;
typedef __attribute__((ext_vector_type(8))) unsigned short u16x8;
typedef __attribute__((ext_vector_type(4))) unsigned int u32x4;
typedef __attribute__((ext_vector_type(2))) unsigned int u32x2;
typedef __attribute__((ext_vector_type(4))) float f32x4;

__device__ __forceinline__ unsigned short f2h(float f) {
  _Float16 h = (_Float16)f;
  return __builtin_bit_cast(unsigned short, h);
}
__device__ __forceinline__ half8 ldh8(const unsigned short* p) {
  return *reinterpret_cast<const half8*>(p);
}
__device__ __forceinline__ void gl_lds16(const unsigned short* g,
                                         unsigned short* l) {
  __builtin_amdgcn_global_load_lds(
      (const __attribute__((address_space(1))) unsigned int*)g,
      (__attribute__((address_space(3))) unsigned int*)l, 16, 0, 0);
}

// ---------------------------------------------------------------------------
__global__ __launch_bounds__(256) void cvt_x(const float* __restrict__ X,
                                             unsigned short* __restrict__ x16) {
  size_t base = ((size_t)blockIdx.x * 256 + threadIdx.x) * 8;
  float4 a = *(const float4*)(X + base);
  float4 b = *(const float4*)(X + base + 4);
  u16x8 o = {f2h(a.x), f2h(a.y), f2h(a.z), f2h(a.w),
             f2h(b.x), f2h(b.y), f2h(b.z), f2h(b.w)};
  *(u16x8*)(x16 + base) = o;
}

// Transpose weights into (N,K) fp16.
__global__ __launch_bounds__(256) void cvt_w(
    const float* __restrict__ Wq, const float* __restrict__ Wkv,
    const float* __restrict__ Wp, unsigned short* __restrict__ wt16,
    unsigned short* __restrict__ wp16) {
  int idx = blockIdx.x * 256 + threadIdx.x;  // 0 .. 262143
  float val; size_t dst; bool isp = false;
  if (idx < 65536) {
    int k = idx >> 8, n = idx & 255;
    val = Wq[idx]; dst = (size_t)n * 256 + k;
  } else if (idx < 196608) {
    int i2 = idx - 65536;
    int k = i2 >> 9, n2 = i2 & 511;
    val = Wkv[i2]; dst = (size_t)(256 + n2) * 256 + k;
  } else {
    int i3 = idx - 196608;
    int k = i3 >> 8, n = i3 & 255;
    val = Wp[i3]; dst = (size_t)n * 256 + k; isp = true;
  }
  unsigned short h = f2h(val);
  if (isp) wp16[dst] = h; else wt16[dst] = h;
}

// ---------------------------------------------------------------------------
__global__ __launch_bounds__(256) void bias_kernel(
    const float* __restrict__ affine, const float* __restrict__ atab,
    float* __restrict__ bias) {
  int idx = blockIdx.x * 256 + threadIdx.x;
  if (idx >= BB * NTOK) return;
  int b = idx >> 10, n = idx & (NTOK - 1);
  float cx = (float)(n & 31);
  float cy = (float)(n >> 5);
  const float* A = affine + b * 6;
  float egx = fmaf(A[0], 16.f, fmaf(A[1], 16.f, A[2]));
  float egy = fmaf(A[3], 16.f, fmaf(A[4], 16.f, A[5]));
  float ang = atan2f(cy - egy, cx - egx);
  float t = (ang + 3.14159265358979323846f) *
            (1.f / (2.f * 3.14159265358979323846f)) * 4.f;
  int bin = (int)t;
  bin = bin < 0 ? 0 : (bin > 4 ? 4 : bin);
  for (int h = 0; h < HEADS; ++h) {
    float a = atab[bin * HEADS + h];
    float s = 1.f / (1.f + __expf(-a));
    bias[((size_t)b * HEADS + h) * NTOK + n] = 1.f + s;
  }
}

// ---------------------------------------------------------------------------
// maskF: mask * log2e - PSHIFT, laid out in MFMA C-fragment order:
//   maskF[((b4*16+kt)*4+f)*16384 + q*16 + (k&15)]
// so lane (q, grp) reads its f32x4 C-init at q*16 + grp*4.
// ---------------------------------------------------------------------------
__global__ __launch_bounds__(256) void mask_prepF(const float* __restrict__ m,
                                                  float* __restrict__ mF) {
  int idx = blockIdx.x * 256 + threadIdx.x;  // thread per float4; 1,048,576
  int b4 = idx >> 18;
  int rem = idx & 262143;
  int q = rem >> 8;
  int k = (rem & 255) * 4;
  float4 v = *(const float4*)(m + ((size_t)b4 * NTOK + q) * NTOK + k);
  float4 o = {fmaf(v.x, LOG2E, -PSHIFT), fmaf(v.y, LOG2E, -PSHIFT),
              fmaf(v.z, LOG2E, -PSHIFT), fmaf(v.w, LOG2E, -PSHIFT)};
  int kt = k >> 6, f = (k >> 4) & 3, ins = k & 15;
  size_t dst = ((size_t)((b4 * 16 + kt) * 4 + f)) * 16384 + q * 16 + ins;
  *(float4*)(mF + dst) = o;
}

// ---------------------------------------------------------------------------
// QKV projection, single-fp16 MFMA, 128x128/BK=32 dbuf, u16 LDS-bounce
// epilogue. q carries scale*bias*log2e; k fp16; v fp16 transposed.
// ---------------------------------------------------------------------------
__global__ __launch_bounds__(512, 4) void gemm_qkv16(
    const unsigned short* __restrict__ x16, const unsigned short* __restrict__ wt16,
    const float* __restrict__ bq, const float* __restrict__ bkv,
    const float* __restrict__ bias, unsigned short* __restrict__ q16,
    unsigned short* __restrict__ k16, unsigned short* __restrict__ vt16) {
  __shared__ __align__(16) unsigned short SM[16384];  // 32 KB multi-use
  unsigned short* Xs = SM;            // [2][4096]
  unsigned short* Ws = SM + 8192;     // [2][4096]
  int tid = threadIdx.x;
  int w = tid >> 6, l = tid & 63;
  int row16 = l & 15, grp = l >> 4;
  int bid = blockIdx.x;
  int xcd = bid & 7, local = bid >> 3;        // 0..95
  int jb = local % 6, mb = xcd * 16 + local / 6;
  int j0 = jb * 128, m0 = mb * 128;
  int wm = w >> 1, wn = w & 1;

  auto stg = [&](int nb, int kt) {  // 1KB chunk per operand per wave
    int k0s = kt * 32;
    int row = w * 16 + (l >> 2);
    int ge = (((l & 3) * 16) ^ ((row & 3) << 4)) >> 1;
    gl_lds16(x16 + (size_t)(m0 + row) * 256 + k0s + ge, Xs + nb * 4096 + w * 512);
    gl_lds16(wt16 + (size_t)(j0 + row) * 256 + k0s + ge, Ws + nb * 4096 + w * 512);
  };
  auto off16 = [&](int row, int g) {
    return row * 32 + ((((g * 16) ^ ((row & 3) << 4))) >> 1);
  };

  stg(0, 0);
  __syncthreads();

  f32x4 acc[2][4];
#pragma unroll
  for (int i = 0; i < 2; ++i)
#pragma unroll
    for (int c = 0; c < 4; ++c) acc[i][c] = (f32x4){0.f, 0.f, 0.f, 0.f};

  for (int kt = 0; kt < 8; ++kt) {
    int cur = kt & 1;
    if (kt < 7) stg(cur ^ 1, kt + 1);
    half8 a0 = ldh8(Xs + cur * 4096 + off16(wm * 32 + row16, grp));
    half8 a1 = ldh8(Xs + cur * 4096 + off16(wm * 32 + 16 + row16, grp));
#pragma unroll
    for (int c = 0; c < 4; ++c) {
      half8 bh = ldh8(Ws + cur * 4096 + off16(wn * 64 + c * 16 + row16, grp));
      acc[0][c] = __builtin_amdgcn_mfma_f32_16x16x32_f16(a0, bh, acc[0][c], 0, 0, 0);
      acc[1][c] = __builtin_amdgcn_mfma_f32_16x16x32_f16(a1, bh, acc[1][c], 0, 0, 0);
    }
    __syncthreads();
  }

  // epilogue: bounce through SM as u16 [64][136], two 64-row halves
  const float scaleq = 0.17677669529663687f * LOG2E;
  int half_mine = wm >> 1;
  for (int half = 0; half < 2; ++half) {
    if (half_mine == half) {
#pragma unroll
      for (int i = 0; i < 2; ++i) {
#pragma unroll
        for (int c = 0; c < 4; ++c) {
          int col = wn * 64 + c * 16 + row16;
          int jg = j0 + col;
#pragma unroll
          for (int r = 0; r < 4; ++r) {
            int rowl = (wm & 1) * 32 + i * 16 + grp * 4 + r;
            int m = m0 + half * 64 + rowl;
            int b = m >> 10, n = m & (NTOK - 1);
            float val = acc[i][c][r];
            unsigned short o;
            if (jb < 2)
              o = f2h((val + bq[jg]) * scaleq *
                      bias[((size_t)b * HEADS + (jg >> 5)) * NTOK + n]);
            else
              o = f2h(val + bkv[jg - CDIM]);
            SM[rowl * 136 + col] = o;
          }
        }
      }
    }
    __syncthreads();
    if (jb < 4) {
#pragma unroll
      for (int it = 0; it < 2; ++it) {
        int lin = it * 512 + tid;
        int rowb = lin >> 4, oct = lin & 15;
        u16x8 v = *(const u16x8*)&SM[rowb * 136 + oct * 8];
        int m = m0 + half * 64 + rowb;
        int b = m >> 10, n = m & (NTOK - 1);
        int jg = j0 + oct * 8;
        unsigned short* dst; int h, d;
        if (jb < 2) { h = jg >> 5; d = jg & 31; dst = q16; }
        else { int c2 = jg - CDIM; h = c2 >> 5; d = c2 & 31; dst = k16; }
        *(u16x8*)(dst + (((size_t)b * HEADS + h) * NTOK + n) * HD + d) = v;
      }
    } else {
#pragma unroll
      for (int it = 0; it < 2; ++it) {
        int lin = it * 512 + tid;
        int noct = lin >> 7, jl = lin & 127;
        u16x8 v;
#pragma unroll
        for (int e = 0; e < 8; ++e) v[e] = SM[(noct * 8 + e) * 136 + jl];
        int c3 = j0 + jl - 2 * CDIM;
        int h = c3 >> 5, d = c3 & 31;
        int n0 = m0 + half * 64 + noct * 8;
        int b = n0 >> 10, nn = n0 & (NTOK - 1);
        *(u16x8*)(vt16 + (((size_t)b * HEADS + h) * HD + d) * NTOK + nn) = v;
      }
    }
    __syncthreads();
  }
}

// ---------------------------------------------------------------------------
// Flash attention: fp16 Q/K/V/P, swapped QK^T, mask folded into MFMA
// C-operand (fragment-ordered maskF), p' = 2^(s - 18) in fp16 via cvt_pkrtz.
// ---------------------------------------------------------------------------
__global__ __launch_bounds__(512, 8) void attn16(
    const unsigned short* __restrict__ q16, const unsigned short* __restrict__ k16,
    const unsigned short* __restrict__ vt16, const float* __restrict__ maskF,
    unsigned short* __restrict__ ao16) {
  __shared__ __align__(16) unsigned short KT[2][64 * 32];  // fp16
  __shared__ __align__(16) unsigned short VT[2][32 * 64];  // fp16
  __shared__ __align__(16) unsigned Pp[8][16][20];         // pad-20 rows

  int tid = threadIdx.x;
  int w = tid >> 6, l = tid & 63;
  int row16 = l & 15, grp = l >> 4;
  int bid = blockIdx.x;
  int swz = (bid & 7) * 128 + (bid >> 3);
  int qt = swz & 7, h = (swz >> 3) & 7, b = swz >> 6;
  int q0 = qt * 128;
  int bh = b * HEADS + h;

  // Q as B-operand: col=q=row16, k-dim=d
  size_t qidx = (((size_t)bh * NTOK) + q0 + w * 16 + row16) * HD + grp * 8;
  half8 bq16 = ldh8(q16 + qidx);

  // per-lane C-fragment base: q*16 + grp*4 within each (kt,f) 16384-slab
  const float* mFb = maskF + (size_t)(b & 3) * 64 * 16384 +
                     (q0 + w * 16 + row16) * 16 + grp * 4;

  f32x4 accd[2];
  accd[0] = (f32x4){0.f, 0.f, 0.f, 0.f};
  accd[1] = (f32x4){0.f, 0.f, 0.f, 0.f};
  float lsum = 0.f;

  auto stage = [&](int nbuf, int kt2) {  // 8 x 1KB chunks, 1 per wave
    int k0n = kt2 * 64;
    if (w < 4) {  // K: [64k][32d] fp16
      int kl = w * 16 + (l >> 2);
      int gd = (((l & 3) * 16) ^ ((kl & 3) << 4)) >> 1;
      gl_lds16(k16 + (((size_t)bh * NTOK) + k0n + kl) * HD + gd,
               &KT[nbuf][w * 16 * 32]);
    } else {      // V^T: [32d][64k] fp16
      int sub = w - 4;
      int dl = sub * 8 + (l >> 3);
      int gk = (((l & 7) * 16) ^ ((dl & 7) << 4)) >> 1;
      gl_lds16(vt16 + ((size_t)bh * HD + dl) * NTOK + k0n + gk,
               &VT[nbuf][sub * 8 * 64]);
    }
  };

  stage(0, 0);
  __syncthreads();

  for (int kt = 0; kt < 16; ++kt) {
    int cur = kt & 1;
    if (kt < 15) stage(cur ^ 1, kt + 1);

    // mask C-fragments for this tile: 4 coalesced f32x4 loads
    f32x4 mC[4];
#pragma unroll
    for (int f = 0; f < 4; ++f)
      mC[f] = *(const f32x4*)(mFb + (size_t)(kt * 4 + f) * 16384);

#pragma unroll
    for (int hf = 0; hf < 2; ++hf) {
      f32x4 s[2];
#pragma unroll
      for (int fp = 0; fp < 2; ++fp) {
        int f = hf * 2 + fp;
        int kl = f * 16 + row16;
        int cb = (grp * 16) ^ ((kl & 3) << 4);
        half8 kf = ldh8(&KT[cur][kl * 32 + (cb >> 1)]);
        // S^T = K Q^T + mask (mask add free via C-operand)
        s[fp] = __builtin_amdgcn_mfma_f32_16x16x32_f16(kf, bq16, mC[f], 0, 0, 0);
      }
#pragma unroll
      for (int fp = 0; fp < 2; ++fp) {
        float p0 = __builtin_amdgcn_exp2f(s[fp][0]);
        float p1 = __builtin_amdgcn_exp2f(s[fp][1]);
        float p2 = __builtin_amdgcn_exp2f(s[fp][2]);
        float p3 = __builtin_amdgcn_exp2f(s[fp][3]);
        lsum += (p0 + p1) + (p2 + p3);
        unsigned pk01 =
            __builtin_bit_cast(unsigned, __builtin_amdgcn_cvt_pkrtz(p0, p1));
        unsigned pk23 =
            __builtin_bit_cast(unsigned, __builtin_amdgcn_cvt_pkrtz(p2, p3));
        *(u32x2*)&Pp[w][row16][fp * 8 + grp * 2] = (u32x2){pk01, pk23};
      }
      // read own q-row's A-frag: cols grp*4..+3 hold k = grp*8..grp*8+7
      half8 pa =
          __builtin_bit_cast(half8, *(const u32x4*)&Pp[w][row16][grp * 4]);
#pragma unroll
      for (int df = 0; df < 2; ++df) {
        int dl = df * 16 + row16;
        int cb = (hf * 64 + grp * 16) ^ ((dl & 7) << 4);
        half8 v = ldh8(&VT[cur][dl * 64 + (cb >> 1)]);
        accd[df] = __builtin_amdgcn_mfma_f32_16x16x32_f16(pa, v, accd[df], 0, 0, 0);
      }
    }
    __syncthreads();
  }

  // row-sum: reduce across the 4 grp slices for fixed row16
  lsum += __shfl_xor(lsum, 16);
  lsum += __shfl_xor(lsum, 32);
#pragma unroll
  for (int r = 0; r < 4; ++r) {
    float lr = __shfl(lsum, grp * 4 + r, 16);
    float inv = 1.f / lr;
    int qrow = q0 + w * 16 + grp * 4 + r;
    size_t obase = ((size_t)b * NTOK + qrow) * CDIM + h * HD;
    ao16[obase + row16] = f2h(accd[0][r] * inv);
    ao16[obase + 16 + row16] = f2h(accd[1][r] * inv);
  }
}

// ---------------------------------------------------------------------------
// Output projection, single-fp16 MFMA, 128x128/BK=32 dbuf.
// ---------------------------------------------------------------------------
__global__ __launch_bounds__(512, 4) void gemm_out16(
    const unsigned short* __restrict__ a16, const unsigned short* __restrict__ wp16,
    const float* __restrict__ bp, float* __restrict__ out) {
  __shared__ __align__(16) unsigned short SM[16384];
  unsigned short* Xs = SM;
  unsigned short* Ws = SM + 8192;
  int tid = threadIdx.x;
  int w = tid >> 6, l = tid & 63;
  int row16 = l & 15, grp = l >> 4;
  int bid = blockIdx.x;
  int xcd = bid & 7, local = bid >> 3;
  int jb = local & 1, mb = xcd * 16 + (local >> 1);
  int j0 = jb * 128, m0 = mb * 128;
  int wm = w >> 1, wn = w & 1;

  auto stg = [&](int nb, int kt) {
    int k0s = kt * 32;
    int row = w * 16 + (l >> 2);
    int ge = (((l & 3) * 16) ^ ((row & 3) << 4)) >> 1;
    gl_lds16(a16 + (size_t)(m0 + row) * 256 + k0s + ge, Xs + nb * 4096 + w * 512);
    gl_lds16(wp16 + (size_t)(j0 + row) * 256 + k0s + ge, Ws + nb * 4096 + w * 512);
  };
  auto off16 = [&](int row, int g) {
    return row * 32 + ((((g * 16) ^ ((row & 3) << 4))) >> 1);
  };

  stg(0, 0);
  __syncthreads();

  f32x4 acc[2][4];
#pragma unroll
  for (int i = 0; i < 2; ++i)
#pragma unroll
    for (int c = 0; c < 4; ++c) acc[i][c] = (f32x4){0.f, 0.f, 0.f, 0.f};

  for (int kt = 0; kt < 8; ++kt) {
    int cur = kt & 1;
    if (kt < 7) stg(cur ^ 1, kt + 1);
    half8 a0 = ldh8(Xs + cur * 4096 + off16(wm * 32 + row16, grp));
    half8 a1 = ldh8(Xs + cur * 4096 + off16(wm * 32 + 16 + row16, grp));
#pragma unroll
    for (int c = 0; c < 4; ++c) {
      half8 bh = ldh8(Ws + cur * 4096 + off16(wn * 64 + c * 16 + row16, grp));
      acc[0][c] = __builtin_amdgcn_mfma_f32_16x16x32_f16(a0, bh, acc[0][c], 0, 0, 0);
      acc[1][c] = __builtin_amdgcn_mfma_f32_16x16x32_f16(a1, bh, acc[1][c], 0, 0, 0);
    }
    __syncthreads();
  }

#pragma unroll
  for (int i = 0; i < 2; ++i) {
    int ng = m0 + wm * 32 + i * 16 + grp * 4;
#pragma unroll
    for (int c = 0; c < 4; ++c) {
      int jg = j0 + wn * 64 + c * 16 + row16;
      float bias = bp[jg];
#pragma unroll
      for (int r = 0; r < 4; ++r) {
        out[(size_t)(ng + r) * CDIM + jg] = acc[i][c][r] + bias;
      }
    }
  }
}

// ---------------------------------------------------------------------------
extern "C" void kernel_launch(void* const* d_in, const int* in_sizes, int n_in,
                              void* d_out, int out_size, void* d_ws,
                              size_t ws_size, hipStream_t stream) {
  const float* x = (const float*)d_in[0];
  const float* mask = (const float*)d_in[1];
  const float* affine = (const float*)d_in[2];
  const float* Wq = (const float*)d_in[3];
  const float* bq = (const float*)d_in[4];
  const float* Wkv = (const float*)d_in[5];
  const float* bkv = (const float*)d_in[6];
  const float* Wp = (const float*)d_in[7];
  const float* bp = (const float*)d_in[8];
  const float* atab = (const float*)d_in[9];
  float* out = (float*)d_out;

  const size_t bhnd = (size_t)BB * HEADS * NTOK * HD;  // 4,194,304
  unsigned short* q16 = (unsigned short*)d_ws;
  unsigned short* k16 = q16 + bhnd;
  unsigned short* vt16 = k16 + bhnd;
  unsigned short* x16 = vt16 + bhnd;     // aliased as ao16 after qkv
  unsigned short* wt16 = x16 + bhnd;     // 768*256
  unsigned short* wp16 = wt16 + 768 * 256;
  float* bias = (float*)(wp16 + 256 * 256);
  float* maskF = bias + (size_t)BB * HEADS * NTOK;

  cvt_x<<<2048, 256, 0, stream>>>(x, x16);
  cvt_w<<<1024, 256, 0, stream>>>(Wq, Wkv, Wp, wt16, wp16);
  bias_kernel<<<64, 256, 0, stream>>>(affine, atab, bias);
  mask_prepF<<<4096, 256, 0, stream>>>(mask, maskF);
  gemm_qkv16<<<768, 512, 0, stream>>>(x16, wt16, bq, bkv, bias, q16, k16, vt16);
  attn16<<<1024, 512, 0, stream>>>(q16, k16, vt16, maskF, x16);
  gemm_out16<<<256, 512, 0, stream>>>(x16, wp16, bp, out);
}